// Round 1
// baseline (2272.731 us; speedup 1.0000x reference)
//
#include <hip/hip_runtime.h>
#include <hip/hip_bf16.h>

// Problem constants (hard-coded; H/W inputs are 64/64)
// B=16, N=4096, C=384, M=16, NH=8, HD=48, H=W=64
#define SCALE 0.14433756729740643f  // 48^-0.5

__device__ inline float cvt_to_f(float v) { return v; }
__device__ inline float cvt_to_f(__hip_bfloat16 v) { return __bfloat162float(v); }
template <typename T> __device__ inline T cvt_from_f(float v);
template <> __device__ inline float cvt_from_f<float>(float v) { return v; }
template <> __device__ inline __hip_bfloat16 cvt_from_f<__hip_bfloat16>(float v) { return __float2bfloat16(v); }

// ---------------------------------------------------------------------------
// K1: saliency + x_sal (bf16). One wave per row (4 waves / block).
// ---------------------------------------------------------------------------
__global__ __launch_bounds__(256) void prep(const float* __restrict__ x,
                                            const float* __restrict__ wsal,
                                            const float* __restrict__ bsal,
                                            __hip_bfloat16* __restrict__ xsal) {
  int wave = threadIdx.x >> 6, lane = threadIdx.x & 63;
  size_t row = (size_t)blockIdx.x * 4 + wave;  // 65536 rows total
  const float* xr = x + row * 384;
  float xs[6];
  float part = 0.f;
#pragma unroll
  for (int j = 0; j < 6; j++) {
    int c = lane + 64 * j;
    xs[j] = xr[c];
    part += xs[j] * wsal[c];
  }
#pragma unroll
  for (int off = 32; off >= 1; off >>= 1) part += __shfl_xor(part, off);
  float s = part + bsal[0];
  float sal = 1.f / (1.f + __expf(-s));
#pragma unroll
  for (int j = 0; j < 6; j++) {
    int c = lane + 64 * j;
    xsal[row * 384 + c] = __float2bfloat16(xs[j] * sal);
  }
}

// ---------------------------------------------------------------------------
// Generic tiled GEMM: out[M,N] = A[M,K] @ B[K,N]; 64x64 tile, BK=16, fp32 VALU.
// Grid: (Ncols/64, Mrows/64), 256 threads, 4x4 micro-tile per thread.
// ---------------------------------------------------------------------------
template <typename AT, typename OT>
__global__ __launch_bounds__(256) void gemm64(const AT* __restrict__ A,
                                              const float* __restrict__ Bm,
                                              OT* __restrict__ out, int Ncols, int Kdim) {
  __shared__ float As[16][68];  // [k][row], pad keeps float4 alignment
  __shared__ float Bs[16][68];  // [k][col]
  int tid = threadIdx.x;
  int rowBase = blockIdx.y * 64;
  int colBase = blockIdx.x * 64;
  int ty = tid >> 4, tx = tid & 15;
  float acc[4][4] = {};
  for (int kk = 0; kk < Kdim; kk += 16) {
    {
      int r = tid >> 2;
      int kq = (tid & 3) << 2;
      const AT* Ap = A + (size_t)(rowBase + r) * Kdim + kk + kq;
#pragma unroll
      for (int i = 0; i < 4; i++) As[kq + i][r] = cvt_to_f(Ap[i]);
    }
    {
      int k = tid >> 4;
      int cq = (tid & 15) << 2;
      const float* Bp = Bm + (size_t)(kk + k) * Ncols + colBase + cq;
      float4 bv = *(const float4*)Bp;
      *(float4*)&Bs[k][cq] = bv;
    }
    __syncthreads();
#pragma unroll
    for (int k = 0; k < 16; k++) {
      float4 a4 = *(const float4*)&As[k][ty * 4];
      float4 b4 = *(const float4*)&Bs[k][tx * 4];
      float a[4] = {a4.x, a4.y, a4.z, a4.w};
      float b[4] = {b4.x, b4.y, b4.z, b4.w};
#pragma unroll
      for (int i = 0; i < 4; i++)
#pragma unroll
        for (int j = 0; j < 4; j++) acc[i][j] += a[i] * b[j];
    }
    __syncthreads();
  }
#pragma unroll
  for (int i = 0; i < 4; i++) {
    size_t ro = (size_t)(rowBase + ty * 4 + i) * Ncols + colBase + tx * 4;
#pragma unroll
    for (int j = 0; j < 4; j++) out[ro + j] = cvt_from_f<OT>(acc[i][j]);
  }
}

// ---------------------------------------------------------------------------
// q_seed[16,384] = anchor_seeds @ w_q_agg * SCALE (same for all batches).
// ---------------------------------------------------------------------------
__global__ void qseed_k(const float* __restrict__ seeds, const float* __restrict__ wq,
                        float* __restrict__ qseed) {
  int idx = blockIdx.x * 256 + threadIdx.x;  // 24 blocks * 256 = 6144
  int m = idx / 384, c = idx % 384;
  float acc = 0.f;
  for (int k = 0; k < 384; k++) acc += seeds[m * 384 + k] * wq[k * 384 + c];
  qseed[idx] = acc * SCALE;
}

// ---------------------------------------------------------------------------
// Agg attention partials: block = (s, h, b); keys [s*256, s*256+256).
// Online softmax over 4 sub-tiles of 64 keys; writes partial (out, m, l).
// ---------------------------------------------------------------------------
__global__ __launch_bounds__(256) void agg_attn_partial(
    const float* __restrict__ qseed, const __hip_bfloat16* __restrict__ kv,
    float* __restrict__ pOut, float* __restrict__ pM, float* __restrict__ pL) {
  int s = blockIdx.x, h = blockIdx.y, b = blockIdx.z;
  __shared__ float qs[16][48];
  __shared__ float kt[64][49];
  __shared__ float vt[64][49];
  __shared__ float lg[16][65];
  __shared__ float outb[16][48];
  __shared__ float mrow[16], lrow[16], rrow[16];
  int tid = threadIdx.x;
  for (int idx = tid; idx < 16 * 48; idx += 256)
    qs[idx / 48][idx % 48] = qseed[(idx / 48) * 384 + h * 48 + idx % 48];
  for (int idx = tid; idx < 16 * 48; idx += 256) outb[idx / 48][idx % 48] = 0.f;
  if (tid < 16) {
    mrow[tid] = -1e30f;
    lrow[tid] = 0.f;
  }
  __syncthreads();
  int k0 = s * 256;
  for (int t = 0; t < 4; t++) {
    int kb = k0 + t * 64;
    for (int idx = tid; idx < 64 * 48; idx += 256) {
      int kkk = idx / 48, d = idx % 48;
      size_t base = ((size_t)(b * 4096 + kb + kkk)) * 768 + h * 48 + d;
      kt[kkk][d] = __bfloat162float(kv[base]);
      vt[kkk][d] = __bfloat162float(kv[base + 384]);
    }
    __syncthreads();
    for (int idx = tid; idx < 16 * 64; idx += 256) {
      int m = idx >> 6, kkk = idx & 63;
      float acc = 0.f;
      for (int d = 0; d < 48; d++) acc += qs[m][d] * kt[kkk][d];
      lg[m][kkk] = acc;
    }
    __syncthreads();
    if (tid < 16) {
      int m = tid;
      float mx = mrow[m];
      for (int kkk = 0; kkk < 64; kkk++) mx = fmaxf(mx, lg[m][kkk]);
      float r = __expf(mrow[m] - mx);
      float sum = 0.f;
      for (int kkk = 0; kkk < 64; kkk++) {
        float p = __expf(lg[m][kkk] - mx);
        lg[m][kkk] = p;
        sum += p;
      }
      rrow[m] = r;
      lrow[m] = lrow[m] * r + sum;
      mrow[m] = mx;
    }
    __syncthreads();
    for (int idx = tid; idx < 16 * 48; idx += 256) {
      int m = idx / 48, d = idx % 48;
      float acc = outb[m][d] * rrow[m];
      for (int kkk = 0; kkk < 64; kkk++) acc += lg[m][kkk] * vt[kkk][d];
      outb[m][d] = acc;
    }
    __syncthreads();
  }
  int g = (b * 8 + h) * 16 + s;
  for (int idx = tid; idx < 16 * 48; idx += 256) pOut[(size_t)g * 768 + idx] = outb[idx / 48][idx % 48];
  if (tid < 16) {
    pM[g * 16 + tid] = mrow[tid];
    pL[g * 16 + tid] = lrow[tid];
  }
}

// ---------------------------------------------------------------------------
// Combine agg partials -> anchors1 = seeds + attn_out.  Block = (b,h).
// ---------------------------------------------------------------------------
__global__ void agg_combine(const float* __restrict__ pOut, const float* __restrict__ pM,
                            const float* __restrict__ pL, const float* __restrict__ seeds,
                            float* __restrict__ anch1) {
  int h = blockIdx.x & 7, b = blockIdx.x >> 3;
  int g = b * 8 + h;
  __shared__ float gm[16], glsum[16];
  int tid = threadIdx.x;
  if (tid < 16) {
    int m = tid;
    float mx = -1e30f;
    for (int s = 0; s < 16; s++) mx = fmaxf(mx, pM[(g * 16 + s) * 16 + m]);
    float l = 0.f;
    for (int s = 0; s < 16; s++) l += pL[(g * 16 + s) * 16 + m] * __expf(pM[(g * 16 + s) * 16 + m] - mx);
    gm[m] = mx;
    glsum[m] = l;
  }
  __syncthreads();
  for (int idx = tid; idx < 768; idx += 256) {
    int m = idx / 48, d = idx % 48;
    float acc = 0.f;
    for (int s = 0; s < 16; s++) {
      int p = g * 16 + s;
      acc += pOut[(size_t)p * 768 + idx] * __expf(pM[p * 16 + m] - gm[m]);
    }
    float o = acc / glsum[m];
    int c = h * 48 + d;
    anch1[(b * 16 + m) * 384 + c] = seeds[m * 384 + c] + o;
  }
}

// ---------------------------------------------------------------------------
// Anchor projection: out[b,16,cols] = A[b,16,384] @ W[384, wstride] slice.
// Grid: (chunks of 192 cols, B). col range = [col0, col0 + 192*gridDim.x)
// ---------------------------------------------------------------------------
__global__ void anchor_proj(const float* __restrict__ Aanch, const float* __restrict__ Wmat,
                            float* __restrict__ out, int wstride, int col0, float scale) {
  int cs = col0 + blockIdx.x * 192;
  int b = blockIdx.y;
  __shared__ float a1[16][384];
  int tid = threadIdx.x;
  for (int idx = tid; idx < 16 * 384; idx += 256) a1[idx / 384][idx % 384] = Aanch[b * 6144 + idx];
  __syncthreads();
  for (int o = tid; o < 16 * 192; o += 256) {
    int m = o / 192, cc = o % 192;
    float acc = 0.f;
    for (int k = 0; k < 384; k++) acc += a1[m][k] * Wmat[(size_t)k * wstride + cs + cc];
    out[((size_t)b * 16 + m) * wstride + cs + cc] = acc * scale;
  }
}

// ---------------------------------------------------------------------------
// Self attention on anchors (16x16, per (b,h)); anchors2 = anchors1 + out.
// ---------------------------------------------------------------------------
__global__ void self_attn(const float* __restrict__ qsf, const float* __restrict__ kvs,
                          const float* __restrict__ anch1, float* __restrict__ anch2) {
  int h = blockIdx.x & 7, b = blockIdx.x >> 3;
  __shared__ float qs[16][48], ks[16][48], vs[16][48], p[16][17];
  int tid = threadIdx.x;
  for (int idx = tid; idx < 768; idx += 256) {
    int m = idx / 48, d = idx % 48;
    qs[m][d] = qsf[(b * 16 + m) * 384 + h * 48 + d];
    ks[m][d] = kvs[(b * 16 + m) * 768 + h * 48 + d];
    vs[m][d] = kvs[(b * 16 + m) * 768 + 384 + h * 48 + d];
  }
  __syncthreads();
  {
    int mq = tid >> 4, mk = tid & 15;
    float acc = 0.f;
    for (int d = 0; d < 48; d++) acc += qs[mq][d] * ks[mk][d];
    p[mq][mk] = acc;
  }
  __syncthreads();
  if (tid < 16) {
    float mx = -1e30f;
    for (int mk = 0; mk < 16; mk++) mx = fmaxf(mx, p[tid][mk]);
    float sum = 0.f;
    for (int mk = 0; mk < 16; mk++) {
      float e = __expf(p[tid][mk] - mx);
      p[tid][mk] = e;
      sum += e;
    }
    float inv = 1.f / sum;
    for (int mk = 0; mk < 16; mk++) p[tid][mk] *= inv;
  }
  __syncthreads();
  for (int idx = tid; idx < 768; idx += 256) {
    int m = idx / 48, d = idx % 48;
    float acc = 0.f;
    for (int mk = 0; mk < 16; mk++) acc += p[m][mk] * vs[mk][d];
    int c = h * 48 + d;
    anch2[(b * 16 + m) * 384 + c] = anch1[(b * 16 + m) * 384 + c] + acc;
  }
}

// ---------------------------------------------------------------------------
// Depthwise 3x3 conv (SAME). Block = (c-chunk of 96, y, b). Writes gl = local.
// ---------------------------------------------------------------------------
__global__ __launch_bounds__(256) void dwconv(const float* __restrict__ x,
                                              const float* __restrict__ dwk,
                                              float* __restrict__ gl) {
  int cs = blockIdx.x * 96, y = blockIdx.y, b = blockIdx.z;
  __shared__ float xr[3][64][97];
  __shared__ float kw[96][9];
  int tid = threadIdx.x;
  for (int idx = tid; idx < 96 * 9; idx += 256) kw[idx / 9][idx % 9] = dwk[(cs + idx / 9) * 9 + idx % 9];
  for (int t = 0; t < 3; t++) {
    int yy = y + t - 1;
    for (int idx = tid; idx < 64 * 96; idx += 256) {
      int w = idx / 96, cc = idx % 96;
      float v = 0.f;
      if (yy >= 0 && yy < 64) v = x[((size_t)(b * 4096 + yy * 64 + w)) * 384 + cs + cc];
      xr[t][w][cc] = v;
    }
  }
  __syncthreads();
  for (int idx = tid; idx < 64 * 96; idx += 256) {
    int w = idx / 96, cc = idx % 96;
    float acc = 0.f;
#pragma unroll
    for (int dy = 0; dy < 3; dy++) {
#pragma unroll
      for (int dx = 0; dx < 3; dx++) {
        int wx = w + dx - 1;
        if (wx >= 0 && wx < 64) acc += xr[dy][wx][cc] * kw[cc][dy * 3 + dx];
      }
    }
    gl[((size_t)(b * 4096 + y * 64 + w)) * 384 + cs + cc] = acc;
  }
}

// ---------------------------------------------------------------------------
// Broadcast attention: one wave per row; softmax over M=16 anchors per head;
// gl += global_out.  Grid: (N/4, B), 256 threads (4 waves).
// ---------------------------------------------------------------------------
__global__ __launch_bounds__(256) void bcast_attn(const __hip_bfloat16* __restrict__ qb,
                                                  const float* __restrict__ kvb,
                                                  float* __restrict__ gl) {
  int b = blockIdx.y;
  __shared__ float kb[16][384], vb[16][384];
  __shared__ float qrow[4][384];
  __shared__ float pp[4][8][16];
  int tid = threadIdx.x;
  for (int idx = tid; idx < 16 * 384; idx += 256) {
    kb[idx / 384][idx % 384] = kvb[((size_t)b * 16 + idx / 384) * 768 + idx % 384];
    vb[idx / 384][idx % 384] = kvb[((size_t)b * 16 + idx / 384) * 768 + 384 + idx % 384];
  }
  __syncthreads();
  int wv = tid >> 6, lane = tid & 63;
  size_t row = (size_t)b * 4096 + blockIdx.x * 4 + wv;
#pragma unroll
  for (int j = 0; j < 6; j++) qrow[wv][lane + 64 * j] = __bfloat162float(qb[row * 384 + lane + 64 * j]);
  float lgv[2];
#pragma unroll
  for (int t = 0; t < 2; t++) {
    int idx = lane * 2 + t;  // = h*16 + m
    int h = idx >> 4, m = idx & 15;
    float acc = 0.f;
    for (int d = 0; d < 48; d++) acc += qrow[wv][h * 48 + d] * kb[m][h * 48 + d];
    lgv[t] = acc;
  }
#pragma unroll
  for (int t = 0; t < 2; t++) {
    int idx = lane * 2 + t;
    pp[wv][idx >> 4][idx & 15] = lgv[t];
  }
  __syncthreads();
  if (lane < 8) {
    int h = lane;
    float mx = -1e30f;
    for (int m2 = 0; m2 < 16; m2++) mx = fmaxf(mx, pp[wv][h][m2]);
    float sum = 0.f;
    for (int m2 = 0; m2 < 16; m2++) {
      float e = __expf(pp[wv][h][m2] - mx);
      pp[wv][h][m2] = e;
      sum += e;
    }
    float inv = 1.f / sum;
    for (int m2 = 0; m2 < 16; m2++) pp[wv][h][m2] *= inv;
  }
  __syncthreads();
#pragma unroll
  for (int j = 0; j < 6; j++) {
    int c = lane + 64 * j;
    int h = c / 48;
    float acc = 0.f;
    for (int m2 = 0; m2 < 16; m2++) acc += pp[wv][h][m2] * vb[m2][c];
    gl[row * 384 + c] += acc;
  }
}

// ---------------------------------------------------------------------------
extern "C" void kernel_launch(void* const* d_in, const int* in_sizes, int n_in,
                              void* d_out, int out_size, void* d_ws, size_t ws_size,
                              hipStream_t stream) {
  (void)in_sizes; (void)n_in; (void)out_size; (void)ws_size;
  const float* x = (const float*)d_in[0];
  const float* wsal = (const float*)d_in[3];
  const float* bsal = (const float*)d_in[4];
  const float* seeds = (const float*)d_in[5];
  const float* w_q_agg = (const float*)d_in[6];
  const float* w_kv_agg = (const float*)d_in[7];
  const float* w_q_self = (const float*)d_in[8];
  const float* w_kv_self = (const float*)d_in[9];
  const float* w_q_bcast = (const float*)d_in[10];
  const float* w_kv_bcast = (const float*)d_in[11];
  const float* dwk = (const float*)d_in[12];
  const float* w_proj = (const float*)d_in[13];
  float* out = (float*)d_out;

  char* ws = (char*)d_ws;
  size_t off = 0;
  auto take = [&](size_t bytes) -> void* {
    void* p = ws + off;
    off += (bytes + 255) & ~(size_t)255;
    return p;
  };
  __hip_bfloat16* xsal = (__hip_bfloat16*)take(50331648);     // [B*N, 384] bf16; reused as q_bcast
  __hip_bfloat16* kv_agg = (__hip_bfloat16*)take(100663296);  // [B*N, 768] bf16; reused as gl (f32)
  float* qseed = (float*)take(24576);
  float* pOut = (float*)take(6291456);
  float* pM = (float*)take(131072);
  float* pL = (float*)take(131072);
  float* anch1 = (float*)take(393216);
  float* anch2 = (float*)take(393216);
  float* q_self = (float*)take(393216);
  float* kv_self = (float*)take(786432);
  float* kv_b = (float*)take(786432);
  __hip_bfloat16* qb = xsal;   // alias: x_sal dead after kv_agg GEMM
  float* gl = (float*)kv_agg;  // alias: kv_agg dead after agg_attn_partial

  // 1) saliency + x_sal
  prep<<<16384, 256, 0, stream>>>(x, wsal, bsal, xsal);
  // 2) kv_agg = x_sal @ w_kv_agg   [65536x768]
  gemm64<__hip_bfloat16, __hip_bfloat16><<<dim3(12, 1024), 256, 0, stream>>>(xsal, w_kv_agg, kv_agg, 768, 384);
  // 3) q_seed (batch-independent), agg attention, combine -> anchors1
  qseed_k<<<24, 256, 0, stream>>>(seeds, w_q_agg, qseed);
  agg_attn_partial<<<dim3(16, 8, 16), 256, 0, stream>>>(qseed, kv_agg, pOut, pM, pL);
  agg_combine<<<128, 256, 0, stream>>>(pOut, pM, pL, seeds, anch1);
  // 4) anchor self-attention -> anchors2
  anchor_proj<<<dim3(2, 16), 256, 0, stream>>>(anch1, w_q_self, q_self, 384, 0, SCALE);
  anchor_proj<<<dim3(4, 16), 256, 0, stream>>>(anch1, w_kv_self, kv_self, 768, 0, 1.f);
  self_attn<<<128, 256, 0, stream>>>(q_self, kv_self, anch1, anch2);
  // 5) kv_bcast = anchors2 @ w_kv_bcast (scale folded into k half)
  anchor_proj<<<dim3(2, 16), 256, 0, stream>>>(anch2, w_kv_bcast, kv_b, 768, 0, SCALE);
  anchor_proj<<<dim3(2, 16), 256, 0, stream>>>(anch2, w_kv_bcast, kv_b, 768, 384, 1.f);
  // 6) q_bcast = x @ w_q_bcast (bf16 out, aliases x_sal region)
  gemm64<float, __hip_bfloat16><<<dim3(6, 1024), 256, 0, stream>>>(x, w_q_bcast, qb, 384, 384);
  // 7) depthwise conv -> gl = local (aliases kv_agg region)
  dwconv<<<dim3(4, 64, 16), 256, 0, stream>>>(x, dwk, gl);
  // 8) gl += global_out (bcast attention over 16 anchors)
  bcast_attn<<<dim3(1024, 16), 256, 0, stream>>>(qb, kv_b, gl);
  // 9) out = gl @ w_proj  (f32)
  gemm64<float, float><<<dim3(6, 1024), 256, 0, stream>>>(gl, w_proj, out, 384, 384);
}

// Round 2
// 1477.948 us; speedup vs baseline: 1.5378x; 1.5378x over previous
//
#include <hip/hip_runtime.h>
#include <hip/hip_bf16.h>

// Problem constants: B=16, N=4096, C=384, M=16, NH=8, HD=48, H=W=64
#define SCALE 0.14433756729740643f  // 48^-0.5

typedef __attribute__((ext_vector_type(8))) short bf16x8;
typedef __attribute__((ext_vector_type(4))) float f32x4;

template <typename T> __device__ inline T cvt_from_f(float v);
template <> __device__ inline float cvt_from_f<float>(float v) { return v; }
template <> __device__ inline __hip_bfloat16 cvt_from_f<__hip_bfloat16>(float v) { return __float2bfloat16(v); }

__device__ inline void gload16(const void* g, void* l) {
  __builtin_amdgcn_global_load_lds((const __attribute__((address_space(1))) void*)g,
                                   (__attribute__((address_space(3))) void*)l, 16, 0, 0);
}

// ---------------------------------------------------------------------------
// K1: saliency + x_sal (bf16). One wave per row (4 waves / block).
// ---------------------------------------------------------------------------
__global__ __launch_bounds__(256) void prep(const float* __restrict__ x,
                                            const float* __restrict__ wsal,
                                            const float* __restrict__ bsal,
                                            __hip_bfloat16* __restrict__ xsal) {
  int wave = threadIdx.x >> 6, lane = threadIdx.x & 63;
  size_t row = (size_t)blockIdx.x * 4 + wave;  // 65536 rows total
  const float* xr = x + row * 384;
  float xs[6];
  float part = 0.f;
#pragma unroll
  for (int j = 0; j < 6; j++) {
    int c = lane + 64 * j;
    xs[j] = xr[c];
    part += xs[j] * wsal[c];
  }
#pragma unroll
  for (int off = 32; off >= 1; off >>= 1) part += __shfl_xor(part, off);
  float s = part + bsal[0];
  float sal = 1.f / (1.f + __expf(-s));
#pragma unroll
  for (int j = 0; j < 6; j++) {
    int c = lane + 64 * j;
    xsal[row * 384 + c] = __float2bfloat16(xs[j] * sal);
  }
}

// ---------------------------------------------------------------------------
// xcast: x (f32) -> bf16, 8 elems/thread.
// ---------------------------------------------------------------------------
__global__ __launch_bounds__(256) void xcast(const float* __restrict__ x,
                                             __hip_bfloat16* __restrict__ xb) {
  size_t i = ((size_t)blockIdx.x * 256 + threadIdx.x) * 8;
  float4 v0 = *(const float4*)(x + i);
  float4 v1 = *(const float4*)(x + i + 4);
  float vv[8] = {v0.x, v0.y, v0.z, v0.w, v1.x, v1.y, v1.z, v1.w};
  __hip_bfloat16 tb[8];
#pragma unroll
  for (int j = 0; j < 8; j++) tb[j] = __float2bfloat16(vv[j]);
  *(ulonglong2*)(xb + i) = *(ulonglong2*)tb;
}

// ---------------------------------------------------------------------------
// Weight cast+transpose: wt[n*K+k] = bf16(w[k*N+n]).  (K=384 rows in source)
// ---------------------------------------------------------------------------
__global__ void wcast_t(const float* __restrict__ w, __hip_bfloat16* __restrict__ wt,
                        int K, int N) {
  int idx = blockIdx.x * 256 + threadIdx.x;
  if (idx >= K * N) return;
  int n = idx / K, k = idx % K;
  wt[idx] = __float2bfloat16(w[(size_t)k * N + n]);
}

// ---------------------------------------------------------------------------
// MFMA GEMM: out[M,Ncols] = A[M,384](bf16) @ BT[Ncols,384](bf16)^T.
// 128x128 tile, BK=32, 4 waves, m97 structure (global_load_lds w=16).
// Grid: (Ncols/128, M/128), 256 threads.
// ---------------------------------------------------------------------------
template <typename OT>
__global__ __launch_bounds__(256) void gemm_mfma(const __hip_bfloat16* __restrict__ A,
                                                 const __hip_bfloat16* __restrict__ BT,
                                                 OT* __restrict__ out, int Ncols) {
  constexpr int K = 384;
  __shared__ __align__(16) __hip_bfloat16 Asl[128][32];
  __shared__ __align__(16) __hip_bfloat16 Bsl[128][32];
  int tid = threadIdx.x;
  int lane = tid & 63;
  int w = tid >> 6;
  int wr = w >> 1, wc = w & 1;
  int fr = lane & 15, fq = lane >> 4;
  int rowBase = blockIdx.y * 128, colBase = blockIdx.x * 128;

  // staging chunk mapping: 512 chunks of 16B per tile; thread covers tid, tid+256
  int r1 = tid >> 2, kc1 = tid & 3;
  int r2 = (tid + 256) >> 2, kc2 = tid & 3;  // (tid+256)&3 == tid&3

  // wave-uniform LDS bases (HW adds lane*16)
  char* aB1 = (char*)Asl + (size_t)(w * 64) * 16;
  char* aB2 = (char*)Asl + (size_t)(256 + w * 64) * 16;
  char* bB1 = (char*)Bsl + (size_t)(w * 64) * 16;
  char* bB2 = (char*)Bsl + (size_t)(256 + w * 64) * 16;

  const __hip_bfloat16* a1 = A + (size_t)(rowBase + r1) * K + kc1 * 8;
  const __hip_bfloat16* a2 = A + (size_t)(rowBase + r2) * K + kc2 * 8;
  const __hip_bfloat16* b1 = BT + (size_t)(colBase + r1) * K + kc1 * 8;
  const __hip_bfloat16* b2 = BT + (size_t)(colBase + r2) * K + kc2 * 8;

  f32x4 acc[4][4] = {};

  for (int kk = 0; kk < K; kk += 32) {
    gload16(a1 + kk, aB1);
    gload16(a2 + kk, aB2);
    gload16(b1 + kk, bB1);
    gload16(b2 + kk, bB2);
    __syncthreads();  // drains vmcnt before barrier
    bf16x8 af[4], bfv[4];
#pragma unroll
    for (int m = 0; m < 4; m++) af[m] = *(const bf16x8*)&Asl[wr * 64 + m * 16 + fr][fq * 8];
#pragma unroll
    for (int n = 0; n < 4; n++) bfv[n] = *(const bf16x8*)&Bsl[wc * 64 + n * 16 + fr][fq * 8];
#pragma unroll
    for (int m = 0; m < 4; m++)
#pragma unroll
      for (int n = 0; n < 4; n++)
        acc[m][n] = __builtin_amdgcn_mfma_f32_16x16x32_bf16(af[m], bfv[n], acc[m][n], 0, 0, 0);
    __syncthreads();
  }

#pragma unroll
  for (int m = 0; m < 4; m++) {
    int row0 = rowBase + wr * 64 + m * 16 + fq * 4;
#pragma unroll
    for (int n = 0; n < 4; n++) {
      int col = colBase + wc * 64 + n * 16 + fr;
      f32x4 v = acc[m][n];
#pragma unroll
      for (int r = 0; r < 4; r++) out[(size_t)(row0 + r) * Ncols + col] = cvt_from_f<OT>(v[r]);
    }
  }
}

// ---------------------------------------------------------------------------
// q_seed[16,384] = anchor_seeds @ w_q_agg * SCALE (same for all batches).
// ---------------------------------------------------------------------------
__global__ void qseed_k(const float* __restrict__ seeds, const float* __restrict__ wq,
                        float* __restrict__ qseed) {
  int idx = blockIdx.x * 256 + threadIdx.x;  // 24 blocks * 256 = 6144
  int m = idx / 384, c = idx % 384;
  float acc = 0.f;
  for (int k = 0; k < 384; k++) acc += seeds[m * 384 + k] * wq[k * 384 + c];
  qseed[idx] = acc * SCALE;
}

// ---------------------------------------------------------------------------
// Agg attention partials: block = (s, h, b); keys [s*256, s*256+256).
// ---------------------------------------------------------------------------
__global__ __launch_bounds__(256) void agg_attn_partial(
    const float* __restrict__ qseed, const __hip_bfloat16* __restrict__ kv,
    float* __restrict__ pOut, float* __restrict__ pM, float* __restrict__ pL) {
  int s = blockIdx.x, h = blockIdx.y, b = blockIdx.z;
  __shared__ float qs[16][48];
  __shared__ float kt[64][49];
  __shared__ float vt[64][49];
  __shared__ float lg[16][65];
  __shared__ float outb[16][48];
  __shared__ float mrow[16], lrow[16], rrow[16];
  int tid = threadIdx.x;
  for (int idx = tid; idx < 16 * 48; idx += 256)
    qs[idx / 48][idx % 48] = qseed[(idx / 48) * 384 + h * 48 + idx % 48];
  for (int idx = tid; idx < 16 * 48; idx += 256) outb[idx / 48][idx % 48] = 0.f;
  if (tid < 16) {
    mrow[tid] = -1e30f;
    lrow[tid] = 0.f;
  }
  __syncthreads();
  int k0 = s * 256;
  for (int t = 0; t < 4; t++) {
    int kb = k0 + t * 64;
    for (int idx = tid; idx < 64 * 48; idx += 256) {
      int kkk = idx / 48, d = idx % 48;
      size_t base = ((size_t)(b * 4096 + kb + kkk)) * 768 + h * 48 + d;
      kt[kkk][d] = __bfloat162float(kv[base]);
      vt[kkk][d] = __bfloat162float(kv[base + 384]);
    }
    __syncthreads();
    for (int idx = tid; idx < 16 * 64; idx += 256) {
      int m = idx >> 6, kkk = idx & 63;
      float acc = 0.f;
      for (int d = 0; d < 48; d++) acc += qs[m][d] * kt[kkk][d];
      lg[m][kkk] = acc;
    }
    __syncthreads();
    if (tid < 16) {
      int m = tid;
      float mx = mrow[m];
      for (int kkk = 0; kkk < 64; kkk++) mx = fmaxf(mx, lg[m][kkk]);
      float r = __expf(mrow[m] - mx);
      float sum = 0.f;
      for (int kkk = 0; kkk < 64; kkk++) {
        float p = __expf(lg[m][kkk] - mx);
        lg[m][kkk] = p;
        sum += p;
      }
      rrow[m] = r;
      lrow[m] = lrow[m] * r + sum;
      mrow[m] = mx;
    }
    __syncthreads();
    for (int idx = tid; idx < 16 * 48; idx += 256) {
      int m = idx / 48, d = idx % 48;
      float acc = outb[m][d] * rrow[m];
      for (int kkk = 0; kkk < 64; kkk++) acc += lg[m][kkk] * vt[kkk][d];
      outb[m][d] = acc;
    }
    __syncthreads();
  }
  int g = (b * 8 + h) * 16 + s;
  for (int idx = tid; idx < 16 * 48; idx += 256) pOut[(size_t)g * 768 + idx] = outb[idx / 48][idx % 48];
  if (tid < 16) {
    pM[g * 16 + tid] = mrow[tid];
    pL[g * 16 + tid] = lrow[tid];
  }
}

// ---------------------------------------------------------------------------
// Combine agg partials -> anchors1 = seeds + attn_out.  Block = (b,h).
// ---------------------------------------------------------------------------
__global__ void agg_combine(const float* __restrict__ pOut, const float* __restrict__ pM,
                            const float* __restrict__ pL, const float* __restrict__ seeds,
                            float* __restrict__ anch1) {
  int h = blockIdx.x & 7, b = blockIdx.x >> 3;
  int g = b * 8 + h;
  __shared__ float gm[16], glsum[16];
  int tid = threadIdx.x;
  if (tid < 16) {
    int m = tid;
    float mx = -1e30f;
    for (int s = 0; s < 16; s++) mx = fmaxf(mx, pM[(g * 16 + s) * 16 + m]);
    float l = 0.f;
    for (int s = 0; s < 16; s++) l += pL[(g * 16 + s) * 16 + m] * __expf(pM[(g * 16 + s) * 16 + m] - mx);
    gm[m] = mx;
    glsum[m] = l;
  }
  __syncthreads();
  for (int idx = tid; idx < 768; idx += 256) {
    int m = idx / 48, d = idx % 48;
    float acc = 0.f;
    for (int s = 0; s < 16; s++) {
      int p = g * 16 + s;
      acc += pOut[(size_t)p * 768 + idx] * __expf(pM[p * 16 + m] - gm[m]);
    }
    float o = acc / glsum[m];
    int c = h * 48 + d;
    anch1[(b * 16 + m) * 384 + c] = seeds[m * 384 + c] + o;
  }
}

// ---------------------------------------------------------------------------
// Anchor projection: out[b,16,cols] = A[b,16,384] @ W[384, wstride] slice.
// ---------------------------------------------------------------------------
__global__ void anchor_proj(const float* __restrict__ Aanch, const float* __restrict__ Wmat,
                            float* __restrict__ out, int wstride, int col0, float scale) {
  int cs = col0 + blockIdx.x * 192;
  int b = blockIdx.y;
  __shared__ float a1[16][384];
  int tid = threadIdx.x;
  for (int idx = tid; idx < 16 * 384; idx += 256) a1[idx / 384][idx % 384] = Aanch[b * 6144 + idx];
  __syncthreads();
  for (int o = tid; o < 16 * 192; o += 256) {
    int m = o / 192, cc = o % 192;
    float acc = 0.f;
    for (int k = 0; k < 384; k++) acc += a1[m][k] * Wmat[(size_t)k * wstride + cs + cc];
    out[((size_t)b * 16 + m) * wstride + cs + cc] = acc * scale;
  }
}

// ---------------------------------------------------------------------------
// Self attention on anchors (16x16, per (b,h)); anchors2 = anchors1 + out.
// ---------------------------------------------------------------------------
__global__ void self_attn(const float* __restrict__ qsf, const float* __restrict__ kvs,
                          const float* __restrict__ anch1, float* __restrict__ anch2) {
  int h = blockIdx.x & 7, b = blockIdx.x >> 3;
  __shared__ float qs[16][48], ks[16][48], vs[16][48], p[16][17];
  int tid = threadIdx.x;
  for (int idx = tid; idx < 768; idx += 256) {
    int m = idx / 48, d = idx % 48;
    qs[m][d] = qsf[(b * 16 + m) * 384 + h * 48 + d];
    ks[m][d] = kvs[(b * 16 + m) * 768 + h * 48 + d];
    vs[m][d] = kvs[(b * 16 + m) * 768 + 384 + h * 48 + d];
  }
  __syncthreads();
  {
    int mq = tid >> 4, mk = tid & 15;
    float acc = 0.f;
    for (int d = 0; d < 48; d++) acc += qs[mq][d] * ks[mk][d];
    p[mq][mk] = acc;
  }
  __syncthreads();
  if (tid < 16) {
    float mx = -1e30f;
    for (int mk = 0; mk < 16; mk++) mx = fmaxf(mx, p[tid][mk]);
    float sum = 0.f;
    for (int mk = 0; mk < 16; mk++) {
      float e = __expf(p[tid][mk] - mx);
      p[tid][mk] = e;
      sum += e;
    }
    float inv = 1.f / sum;
    for (int mk = 0; mk < 16; mk++) p[tid][mk] *= inv;
  }
  __syncthreads();
  for (int idx = tid; idx < 768; idx += 256) {
    int m = idx / 48, d = idx % 48;
    float acc = 0.f;
    for (int mk = 0; mk < 16; mk++) acc += p[m][mk] * vs[mk][d];
    int c = h * 48 + d;
    anch2[(b * 16 + m) * 384 + c] = anch1[(b * 16 + m) * 384 + c] + acc;
  }
}

// ---------------------------------------------------------------------------
// Depthwise 3x3 conv (SAME). Block = (c-chunk of 96, y, b). Writes gl (bf16).
// ---------------------------------------------------------------------------
__global__ __launch_bounds__(256) void dwconv(const float* __restrict__ x,
                                              const float* __restrict__ dwk,
                                              __hip_bfloat16* __restrict__ gl) {
  int cs = blockIdx.x * 96, y = blockIdx.y, b = blockIdx.z;
  __shared__ float xr[3][64][97];
  __shared__ float kw[96][9];
  int tid = threadIdx.x;
  for (int idx = tid; idx < 96 * 9; idx += 256) kw[idx / 9][idx % 9] = dwk[(cs + idx / 9) * 9 + idx % 9];
  for (int t = 0; t < 3; t++) {
    int yy = y + t - 1;
    for (int idx = tid; idx < 64 * 96; idx += 256) {
      int w = idx / 96, cc = idx % 96;
      float v = 0.f;
      if (yy >= 0 && yy < 64) v = x[((size_t)(b * 4096 + yy * 64 + w)) * 384 + cs + cc];
      xr[t][w][cc] = v;
    }
  }
  __syncthreads();
  for (int idx = tid; idx < 64 * 96; idx += 256) {
    int w = idx / 96, cc = idx % 96;
    float acc = 0.f;
#pragma unroll
    for (int dy = 0; dy < 3; dy++) {
#pragma unroll
      for (int dx = 0; dx < 3; dx++) {
        int wx = w + dx - 1;
        if (wx >= 0 && wx < 64) acc += xr[dy][wx][cc] * kw[cc][dy * 3 + dx];
      }
    }
    gl[((size_t)(b * 4096 + y * 64 + w)) * 384 + cs + cc] = __float2bfloat16(acc);
  }
}

// ---------------------------------------------------------------------------
// Broadcast attention: one wave per row; softmax over M=16 anchors per head;
// gl += global_out (bf16 RMW).  Grid: (N/4, B), 256 threads (4 waves).
// ---------------------------------------------------------------------------
__global__ __launch_bounds__(256) void bcast_attn(const __hip_bfloat16* __restrict__ qb,
                                                  const float* __restrict__ kvb,
                                                  __hip_bfloat16* __restrict__ gl) {
  int b = blockIdx.y;
  __shared__ float kb[16][384], vb[16][384];
  __shared__ float qrow[4][384];
  __shared__ float pp[4][8][16];
  int tid = threadIdx.x;
  for (int idx = tid; idx < 16 * 384; idx += 256) {
    kb[idx / 384][idx % 384] = kvb[((size_t)b * 16 + idx / 384) * 768 + idx % 384];
    vb[idx / 384][idx % 384] = kvb[((size_t)b * 16 + idx / 384) * 768 + 384 + idx % 384];
  }
  __syncthreads();
  int wv = tid >> 6, lane = tid & 63;
  size_t row = (size_t)b * 4096 + blockIdx.x * 4 + wv;
#pragma unroll
  for (int j = 0; j < 6; j++) qrow[wv][lane + 64 * j] = __bfloat162float(qb[row * 384 + lane + 64 * j]);
  float lgv[2];
#pragma unroll
  for (int t = 0; t < 2; t++) {
    int idx = lane * 2 + t;  // = h*16 + m
    int h = idx >> 4, m = idx & 15;
    float acc = 0.f;
    for (int d = 0; d < 48; d++) acc += qrow[wv][h * 48 + d] * kb[m][h * 48 + d];
    lgv[t] = acc;
  }
#pragma unroll
  for (int t = 0; t < 2; t++) {
    int idx = lane * 2 + t;
    pp[wv][idx >> 4][idx & 15] = lgv[t];
  }
  __syncthreads();
  if (lane < 8) {
    int h = lane;
    float mx = -1e30f;
    for (int m2 = 0; m2 < 16; m2++) mx = fmaxf(mx, pp[wv][h][m2]);
    float sum = 0.f;
    for (int m2 = 0; m2 < 16; m2++) {
      float e = __expf(pp[wv][h][m2] - mx);
      pp[wv][h][m2] = e;
      sum += e;
    }
    float inv = 1.f / sum;
    for (int m2 = 0; m2 < 16; m2++) pp[wv][h][m2] *= inv;
  }
  __syncthreads();
#pragma unroll
  for (int j = 0; j < 6; j++) {
    int c = lane + 64 * j;
    int h = c / 48;
    float acc = 0.f;
    for (int m2 = 0; m2 < 16; m2++) acc += pp[wv][h][m2] * vb[m2][c];
    size_t o = row * 384 + c;
    gl[o] = __float2bfloat16(__bfloat162float(gl[o]) + acc);
  }
}

// ---------------------------------------------------------------------------
extern "C" void kernel_launch(void* const* d_in, const int* in_sizes, int n_in,
                              void* d_out, int out_size, void* d_ws, size_t ws_size,
                              hipStream_t stream) {
  (void)in_sizes; (void)n_in; (void)out_size; (void)ws_size;
  const float* x = (const float*)d_in[0];
  const float* wsal = (const float*)d_in[3];
  const float* bsal = (const float*)d_in[4];
  const float* seeds = (const float*)d_in[5];
  const float* w_q_agg = (const float*)d_in[6];
  const float* w_kv_agg = (const float*)d_in[7];
  const float* w_q_self = (const float*)d_in[8];
  const float* w_kv_self = (const float*)d_in[9];
  const float* w_q_bcast = (const float*)d_in[10];
  const float* w_kv_bcast = (const float*)d_in[11];
  const float* dwk = (const float*)d_in[12];
  const float* w_proj = (const float*)d_in[13];
  float* out = (float*)d_out;

  char* ws = (char*)d_ws;
  size_t off = 0;
  auto take = [&](size_t bytes) -> void* {
    void* p = ws + off;
    off += (bytes + 255) & ~(size_t)255;
    return p;
  };
  __hip_bfloat16* xsal = (__hip_bfloat16*)take(50331648);  // R1: xsal, later xb
  __hip_bfloat16* kv = (__hip_bfloat16*)take(100663296);   // R3: kv; later qb + gl
  float* qseed = (float*)take(24576);
  float* pOut = (float*)take(6291456);
  float* pM = (float*)take(131072);
  float* pL = (float*)take(131072);
  float* anch1 = (float*)take(393216);
  float* anch2 = (float*)take(393216);
  float* q_self = (float*)take(393216);
  float* kv_self = (float*)take(786432);
  float* kv_b = (float*)take(786432);
  __hip_bfloat16* wkvT = (__hip_bfloat16*)take(589824);  // [768][384] bf16
  __hip_bfloat16* wqbT = (__hip_bfloat16*)take(294912);  // [384][384] bf16
  __hip_bfloat16* wprT = (__hip_bfloat16*)take(294912);  // [384][384] bf16
  __hip_bfloat16* xb = xsal;                         // alias: xsal dead after kv GEMM
  __hip_bfloat16* qb = kv;                           // alias: kv dead after agg_attn
  __hip_bfloat16* gl = kv + 25165824;                // alias: second half of R3

  // 0) weight transpose+cast (tiny)
  wcast_t<<<1152, 256, 0, stream>>>(w_kv_agg, wkvT, 384, 768);
  wcast_t<<<576, 256, 0, stream>>>(w_q_bcast, wqbT, 384, 384);
  wcast_t<<<576, 256, 0, stream>>>(w_proj, wprT, 384, 384);
  // 1) saliency + x_sal
  prep<<<16384, 256, 0, stream>>>(x, wsal, bsal, xsal);
  // 2) kv = x_sal @ w_kv_agg   [65536x768] bf16 (MFMA)
  gemm_mfma<__hip_bfloat16><<<dim3(6, 512), 256, 0, stream>>>(xsal, wkvT, kv, 768);
  // 3) agg attention -> anchors1
  qseed_k<<<24, 256, 0, stream>>>(seeds, w_q_agg, qseed);
  agg_attn_partial<<<dim3(16, 8, 16), 256, 0, stream>>>(qseed, kv, pOut, pM, pL);
  agg_combine<<<128, 256, 0, stream>>>(pOut, pM, pL, seeds, anch1);
  // 4) anchor self-attention -> anchors2
  anchor_proj<<<dim3(2, 16), 256, 0, stream>>>(anch1, w_q_self, q_self, 384, 0, SCALE);
  anchor_proj<<<dim3(4, 16), 256, 0, stream>>>(anch1, w_kv_self, kv_self, 768, 0, 1.f);
  self_attn<<<128, 256, 0, stream>>>(q_self, kv_self, anch1, anch2);
  // 5) kv_bcast = anchors2 @ w_kv_bcast (SCALE folded into k half)
  anchor_proj<<<dim3(2, 16), 256, 0, stream>>>(anch2, w_kv_bcast, kv_b, 768, 0, SCALE);
  anchor_proj<<<dim3(2, 16), 256, 0, stream>>>(anch2, w_kv_bcast, kv_b, 768, 384, 1.f);
  // 6) xb = bf16(x) over dead xsal; qb = xb @ w_q_bcast (MFMA) into dead kv
  xcast<<<12288, 256, 0, stream>>>(x, xb);
  gemm_mfma<__hip_bfloat16><<<dim3(3, 512), 256, 0, stream>>>(xb, wqbT, qb, 384);
  // 7) depthwise conv -> gl (bf16)
  dwconv<<<dim3(4, 64, 16), 256, 0, stream>>>(x, dwk, gl);
  // 8) gl += global_out (bcast attention over 16 anchors)
  bcast_attn<<<dim3(1024, 16), 256, 0, stream>>>(qb, kv_b, gl);
  // 9) out = gl @ w_proj (MFMA, f32 out)
  gemm_mfma<float><<<dim3(3, 512), 256, 0, stream>>>(gl, wprT, out, 384);
}

// Round 3
// 1235.730 us; speedup vs baseline: 1.8392x; 1.1960x over previous
//
#include <hip/hip_runtime.h>
#include <hip/hip_bf16.h>

// Problem constants: B=16, N=4096, C=384, M=16, NH=8, HD=48, H=W=64
#define SCALE 0.14433756729740643f  // 48^-0.5

typedef __attribute__((ext_vector_type(8))) short bf16x8;
typedef __attribute__((ext_vector_type(4))) float f32x4;

__device__ inline float b2f(short s) {
  union { unsigned int u; float f; } c;
  c.u = ((unsigned int)(unsigned short)s) << 16;
  return c.f;
}

template <typename T> __device__ inline T cvt_from_f(float v);
template <> __device__ inline float cvt_from_f<float>(float v) { return v; }
template <> __device__ inline __hip_bfloat16 cvt_from_f<__hip_bfloat16>(float v) { return __float2bfloat16(v); }

__device__ inline void gload16(const void* g, void* l) {
  __builtin_amdgcn_global_load_lds((const __attribute__((address_space(1))) void*)g,
                                   (__attribute__((address_space(3))) void*)l, 16, 0, 0);
}

// ---------------------------------------------------------------------------
// prep: xb = bf16(x); sal[row] = sigmoid(x·wsal + b). One wave per row.
// ---------------------------------------------------------------------------
__global__ __launch_bounds__(256) void prep(const float* __restrict__ x,
                                            const float* __restrict__ wsal,
                                            const float* __restrict__ bsal,
                                            __hip_bfloat16* __restrict__ xb,
                                            float* __restrict__ sal) {
  int wave = threadIdx.x >> 6, lane = threadIdx.x & 63;
  size_t row = (size_t)blockIdx.x * 4 + wave;
  const float* xr = x + row * 384;
  float xs[6];
  float part = 0.f;
#pragma unroll
  for (int j = 0; j < 6; j++) {
    int c = lane + 64 * j;
    xs[j] = xr[c];
    part += xs[j] * wsal[c];
  }
#pragma unroll
  for (int off = 32; off >= 1; off >>= 1) part += __shfl_xor(part, off);
  float s = 1.f / (1.f + __expf(-(part + bsal[0])));
#pragma unroll
  for (int j = 0; j < 6; j++) {
    int c = lane + 64 * j;
    xb[row * 384 + c] = __float2bfloat16(xs[j]);
  }
  if (lane == 0) sal[row] = s;
}

// ---------------------------------------------------------------------------
// Weight cast+transpose: wt[n*K+k] = bf16(w[k*N+n]).
// ---------------------------------------------------------------------------
__global__ void wcast_t(const float* __restrict__ w, __hip_bfloat16* __restrict__ wt,
                        int K, int N) {
  int idx = blockIdx.x * 256 + threadIdx.x;
  if (idx >= K * N) return;
  int n = idx / K, k = idx % K;
  wt[idx] = __float2bfloat16(w[(size_t)k * N + n]);
}

// dwk [384][9] -> kwp[c8][ki][j]  (j = c&7)
__global__ void kwpack(const float* __restrict__ dwk, float* __restrict__ kwp) {
  int idx = blockIdx.x * 256 + threadIdx.x;
  if (idx >= 3456) return;
  int c = idx / 9, ki = idx % 9;
  kwp[(c >> 3) * 72 + ki * 8 + (c & 7)] = dwk[idx];
}

// ---------------------------------------------------------------------------
// MFMA GEMM: out[M,Ncols] = A[M,384](bf16) @ BT[Ncols,384]^T, optional row scale.
// 128x128 tile, BK=32, 4 waves, m97 structure.
// ---------------------------------------------------------------------------
template <typename OT, bool RS>
__global__ __launch_bounds__(256) void gemm_mfma(const __hip_bfloat16* __restrict__ A,
                                                 const __hip_bfloat16* __restrict__ BT,
                                                 OT* __restrict__ out, int Ncols,
                                                 const float* __restrict__ rowScale) {
  constexpr int K = 384;
  __shared__ __align__(16) __hip_bfloat16 Asl[128][32];
  __shared__ __align__(16) __hip_bfloat16 Bsl[128][32];
  int tid = threadIdx.x;
  int lane = tid & 63;
  int w = tid >> 6;
  int wr = w >> 1, wc = w & 1;
  int fr = lane & 15, fq = lane >> 4;
  int rowBase = blockIdx.y * 128, colBase = blockIdx.x * 128;

  int r1 = tid >> 2, kc1 = tid & 3;
  int r2 = (tid + 256) >> 2;

  char* aB1 = (char*)Asl + (size_t)(w * 64) * 16;
  char* aB2 = (char*)Asl + (size_t)(256 + w * 64) * 16;
  char* bB1 = (char*)Bsl + (size_t)(w * 64) * 16;
  char* bB2 = (char*)Bsl + (size_t)(256 + w * 64) * 16;

  const __hip_bfloat16* a1 = A + (size_t)(rowBase + r1) * K + kc1 * 8;
  const __hip_bfloat16* a2 = A + (size_t)(rowBase + r2) * K + kc1 * 8;
  const __hip_bfloat16* b1 = BT + (size_t)(colBase + r1) * K + kc1 * 8;
  const __hip_bfloat16* b2 = BT + (size_t)(colBase + r2) * K + kc1 * 8;

  f32x4 acc[4][4] = {};

  for (int kk = 0; kk < K; kk += 32) {
    gload16(a1 + kk, aB1);
    gload16(a2 + kk, aB2);
    gload16(b1 + kk, bB1);
    gload16(b2 + kk, bB2);
    __syncthreads();
    bf16x8 af[4], bfv[4];
#pragma unroll
    for (int m = 0; m < 4; m++) af[m] = *(const bf16x8*)&Asl[wr * 64 + m * 16 + fr][fq * 8];
#pragma unroll
    for (int n = 0; n < 4; n++) bfv[n] = *(const bf16x8*)&Bsl[wc * 64 + n * 16 + fr][fq * 8];
#pragma unroll
    for (int m = 0; m < 4; m++)
#pragma unroll
      for (int n = 0; n < 4; n++)
        acc[m][n] = __builtin_amdgcn_mfma_f32_16x16x32_bf16(af[m], bfv[n], acc[m][n], 0, 0, 0);
    __syncthreads();
  }

  if constexpr (RS) {
    float sv[4][4];
#pragma unroll
    for (int m = 0; m < 4; m++)
#pragma unroll
      for (int r = 0; r < 4; r++)
        sv[m][r] = rowScale[rowBase + wr * 64 + m * 16 + fq * 4 + r];
#pragma unroll
    for (int m = 0; m < 4; m++)
#pragma unroll
      for (int n = 0; n < 4; n++)
#pragma unroll
        for (int r = 0; r < 4; r++) acc[m][n][r] *= sv[m][r];
  }

#pragma unroll
  for (int m = 0; m < 4; m++) {
    int row0 = rowBase + wr * 64 + m * 16 + fq * 4;
#pragma unroll
    for (int n = 0; n < 4; n++) {
      int col = colBase + wc * 64 + n * 16 + fr;
      f32x4 v = acc[m][n];
#pragma unroll
      for (int r = 0; r < 4; r++) out[(size_t)(row0 + r) * Ncols + col] = cvt_from_f<OT>(v[r]);
    }
  }
}

// ---------------------------------------------------------------------------
// q_seed[16,384] = anchor_seeds @ w_q_agg * SCALE.
// ---------------------------------------------------------------------------
__global__ void qseed_k(const float* __restrict__ seeds, const float* __restrict__ wq,
                        float* __restrict__ qseed) {
  int idx = blockIdx.x * 256 + threadIdx.x;
  int m = idx / 384, c = idx % 384;
  float acc = 0.f;
  for (int k = 0; k < 384; k++) acc += seeds[m * 384 + k] * wq[k * 384 + c];
  qseed[idx] = acc * SCALE;
}

// ---------------------------------------------------------------------------
// Agg attention partials: block = (s, h, b); keys [s*256, s*256+256).
// ---------------------------------------------------------------------------
__global__ __launch_bounds__(256) void agg_attn_partial(
    const float* __restrict__ qseed, const __hip_bfloat16* __restrict__ kv,
    float* __restrict__ pOut, float* __restrict__ pM, float* __restrict__ pL) {
  int s = blockIdx.x, h = blockIdx.y, b = blockIdx.z;
  __shared__ float qs[16][48];
  __shared__ float kt[64][49];
  __shared__ float vt[64][49];
  __shared__ float lg[16][65];
  __shared__ float outb[16][48];
  __shared__ float mrow[16], lrow[16], rrow[16];
  int tid = threadIdx.x;
  for (int idx = tid; idx < 16 * 48; idx += 256)
    qs[idx / 48][idx % 48] = qseed[(idx / 48) * 384 + h * 48 + idx % 48];
  for (int idx = tid; idx < 16 * 48; idx += 256) outb[idx / 48][idx % 48] = 0.f;
  if (tid < 16) {
    mrow[tid] = -1e30f;
    lrow[tid] = 0.f;
  }
  __syncthreads();
  int k0 = s * 256;
  for (int t = 0; t < 4; t++) {
    int kb = k0 + t * 64;
    // stage 64 rows of k and v: 768 16B chunks, vectorized
#pragma unroll
    for (int i = 0; i < 3; i++) {
      int idx = tid + i * 256;          // 0..767
      int mat = idx / 384;              // 0:k 1:v (wave-uniform)
      int id2 = idx - mat * 384;
      int r = id2 / 6, oc = id2 - r * 6;
      bf16x8 v = *(const bf16x8*)(kv + ((size_t)(b * 4096 + kb + r)) * 768 + mat * 384 + h * 48 + oc * 8);
      float* dst = mat ? &vt[r][oc * 8] : &kt[r][oc * 8];
#pragma unroll
      for (int j = 0; j < 8; j++) dst[j] = b2f(v[j]);
    }
    __syncthreads();
    for (int idx = tid; idx < 16 * 64; idx += 256) {
      int m = idx >> 6, kkk = idx & 63;
      float acc = 0.f;
      for (int d = 0; d < 48; d++) acc += qs[m][d] * kt[kkk][d];
      lg[m][kkk] = acc;
    }
    __syncthreads();
    if (tid < 64) {  // wave-parallel softmax: lane = m*4+q, each handles 16 keys
      int m = tid >> 2, q = tid & 3;
      float mx = mrow[m];
      for (int i = 0; i < 16; i++) mx = fmaxf(mx, lg[m][q * 16 + i]);
      mx = fmaxf(mx, __shfl_xor(mx, 1));
      mx = fmaxf(mx, __shfl_xor(mx, 2));
      float r = __expf(mrow[m] - mx);
      float sum = 0.f;
      for (int i = 0; i < 16; i++) {
        float e = __expf(lg[m][q * 16 + i] - mx);
        lg[m][q * 16 + i] = e;
        sum += e;
      }
      sum += __shfl_xor(sum, 1);
      sum += __shfl_xor(sum, 2);
      if (q == 0) {
        rrow[m] = r;
        lrow[m] = lrow[m] * r + sum;
        mrow[m] = mx;
      }
    }
    __syncthreads();
    for (int idx = tid; idx < 16 * 48; idx += 256) {
      int m = idx / 48, d = idx % 48;
      float acc = outb[m][d] * rrow[m];
      for (int kkk = 0; kkk < 64; kkk++) acc += lg[m][kkk] * vt[kkk][d];
      outb[m][d] = acc;
    }
    __syncthreads();
  }
  int g = (b * 8 + h) * 16 + s;
  for (int idx = tid; idx < 16 * 48; idx += 256) pOut[(size_t)g * 768 + idx] = outb[idx / 48][idx % 48];
  if (tid < 16) {
    pM[g * 16 + tid] = mrow[tid];
    pL[g * 16 + tid] = lrow[tid];
  }
}

// ---------------------------------------------------------------------------
// Combine agg partials -> anchors1 = seeds + attn_out.
// ---------------------------------------------------------------------------
__global__ void agg_combine(const float* __restrict__ pOut, const float* __restrict__ pM,
                            const float* __restrict__ pL, const float* __restrict__ seeds,
                            float* __restrict__ anch1) {
  int h = blockIdx.x & 7, b = blockIdx.x >> 3;
  int g = b * 8 + h;
  __shared__ float gm[16], glsum[16];
  int tid = threadIdx.x;
  if (tid < 16) {
    int m = tid;
    float mx = -1e30f;
    for (int s = 0; s < 16; s++) mx = fmaxf(mx, pM[(g * 16 + s) * 16 + m]);
    float l = 0.f;
    for (int s = 0; s < 16; s++) l += pL[(g * 16 + s) * 16 + m] * __expf(pM[(g * 16 + s) * 16 + m] - mx);
    gm[m] = mx;
    glsum[m] = l;
  }
  __syncthreads();
  for (int idx = tid; idx < 768; idx += 256) {
    int m = idx / 48, d = idx % 48;
    float acc = 0.f;
    for (int s = 0; s < 16; s++) {
      int p = g * 16 + s;
      acc += pOut[(size_t)p * 768 + idx] * __expf(pM[p * 16 + m] - gm[m]);
    }
    float o = acc / glsum[m];
    int c = h * 48 + d;
    anch1[(b * 16 + m) * 384 + c] = seeds[m * 384 + c] + o;
  }
}

// ---------------------------------------------------------------------------
// Anchor projection: out[b,16,cols] = A[b,16,384] @ W[384, wstride] slice.
// ---------------------------------------------------------------------------
__global__ void anchor_proj(const float* __restrict__ Aanch, const float* __restrict__ Wmat,
                            float* __restrict__ out, int wstride, int col0, float scale) {
  int cs = col0 + blockIdx.x * 192;
  int b = blockIdx.y;
  __shared__ float a1[16][384];
  int tid = threadIdx.x;
  for (int idx = tid; idx < 16 * 384; idx += 256) a1[idx / 384][idx % 384] = Aanch[b * 6144 + idx];
  __syncthreads();
  for (int o = tid; o < 16 * 192; o += 256) {
    int m = o / 192, cc = o % 192;
    float acc = 0.f;
    for (int k = 0; k < 384; k++) acc += a1[m][k] * Wmat[(size_t)k * wstride + cs + cc];
    out[((size_t)b * 16 + m) * wstride + cs + cc] = acc * scale;
  }
}

// ---------------------------------------------------------------------------
// Self attention on anchors (16x16, per (b,h)); anchors2 = anchors1 + out.
// ---------------------------------------------------------------------------
__global__ void self_attn(const float* __restrict__ qsf, const float* __restrict__ kvs,
                          const float* __restrict__ anch1, float* __restrict__ anch2) {
  int h = blockIdx.x & 7, b = blockIdx.x >> 3;
  __shared__ float qs[16][48], ks[16][48], vs[16][48], p[16][17];
  int tid = threadIdx.x;
  for (int idx = tid; idx < 768; idx += 256) {
    int m = idx / 48, d = idx % 48;
    qs[m][d] = qsf[(b * 16 + m) * 384 + h * 48 + d];
    ks[m][d] = kvs[(b * 16 + m) * 768 + h * 48 + d];
    vs[m][d] = kvs[(b * 16 + m) * 768 + 384 + h * 48 + d];
  }
  __syncthreads();
  {
    int mq = tid >> 4, mk = tid & 15;
    float acc = 0.f;
    for (int d = 0; d < 48; d++) acc += qs[mq][d] * ks[mk][d];
    p[mq][mk] = acc;
  }
  __syncthreads();
  if (tid < 16) {
    float mx = -1e30f;
    for (int mk = 0; mk < 16; mk++) mx = fmaxf(mx, p[tid][mk]);
    float sum = 0.f;
    for (int mk = 0; mk < 16; mk++) {
      float e = __expf(p[tid][mk] - mx);
      p[tid][mk] = e;
      sum += e;
    }
    float inv = 1.f / sum;
    for (int mk = 0; mk < 16; mk++) p[tid][mk] *= inv;
  }
  __syncthreads();
  for (int idx = tid; idx < 768; idx += 256) {
    int m = idx / 48, d = idx % 48;
    float acc = 0.f;
    for (int mk = 0; mk < 16; mk++) acc += p[m][mk] * vs[mk][d];
    int c = h * 48 + d;
    anch2[(b * 16 + m) * 384 + c] = anch1[(b * 16 + m) * 384 + c] + acc;
  }
}

// ---------------------------------------------------------------------------
// Depthwise 3x3 conv (SAME), no LDS. Grid (48 c8, 16 ygrp, 16 b), 256 thr.
// lane = w, tid>>6 = y sub-row. Reads xb (bf16), uniform packed weights.
// ---------------------------------------------------------------------------
__global__ __launch_bounds__(256) void dwconv(const __hip_bfloat16* __restrict__ xb,
                                              const float* __restrict__ kwp,
                                              __hip_bfloat16* __restrict__ gl) {
  int c8 = blockIdx.x, b = blockIdx.z;
  int y = blockIdx.y * 4 + (threadIdx.x >> 6);
  int w = threadIdx.x & 63;
  float acc[8] = {};
  const float* kwb = kwp + c8 * 72;
#pragma unroll
  for (int dy = -1; dy <= 1; dy++) {
    int yy = y + dy;
    if (yy < 0 || yy >= 64) continue;  // wave-uniform
#pragma unroll
    for (int dx = -1; dx <= 1; dx++) {
      int ww = w + dx;
      int ki = (dy + 1) * 3 + (dx + 1);
      float4 k0 = *(const float4*)(kwb + ki * 8);
      float4 k1 = *(const float4*)(kwb + ki * 8 + 4);
      float kk[8] = {k0.x, k0.y, k0.z, k0.w, k1.x, k1.y, k1.z, k1.w};
      if (ww >= 0 && ww < 64) {
        bf16x8 v = *(const bf16x8*)(xb + ((size_t)(b * 4096 + yy * 64 + ww)) * 384 + c8 * 8);
#pragma unroll
        for (int j = 0; j < 8; j++) acc[j] += b2f(v[j]) * kk[j];
      }
    }
  }
  __hip_bfloat16 tb[8];
#pragma unroll
  for (int j = 0; j < 8; j++) tb[j] = __float2bfloat16(acc[j]);
  *(ulonglong2*)(gl + ((size_t)(b * 4096 + y * 64 + w)) * 384 + c8 * 8) = *(ulonglong2*)tb;
}

// ---------------------------------------------------------------------------
// Broadcast attention: block = 128 rows of one batch; wave = 32 rows.
// K as khm[h*16+m][49] f32 (2-way max on reads), V bf16, softmax in-register.
// ---------------------------------------------------------------------------
__global__ __launch_bounds__(256) void bcast_attn(const __hip_bfloat16* __restrict__ qb,
                                                  const float* __restrict__ kvb,
                                                  __hip_bfloat16* __restrict__ gl) {
  int b = blockIdx.y;
  __shared__ float khm[128][49];
  __shared__ __hip_bfloat16 vbs[16][384];
  __shared__ float qrow[4][8][49];
  __shared__ float pp[4][8][17];
  int tid = threadIdx.x;
  const float* kvB = kvb + (size_t)b * 16 * 768;
  for (int idx = tid; idx < 6144; idx += 256) {
    int hm = idx / 48, d = idx - hm * 48;
    int m = hm & 15, h = hm >> 4;
    khm[hm][d] = kvB[m * 768 + h * 48 + d];
  }
  for (int idx = tid; idx < 6144; idx += 256) {
    int m = idx / 384, c = idx - m * 384;
    vbs[m][c] = __float2bfloat16(kvB[m * 768 + 384 + c]);
  }
  __syncthreads();
  int wv = tid >> 6, lane = tid & 63;
  int h0 = lane >> 4, m0 = lane & 15;
  for (int it = 0; it < 32; it++) {
    size_t row = (size_t)b * 4096 + (size_t)blockIdx.x * 128 + wv * 32 + it;
    // load q row, broadcast via padded LDS
#pragma unroll
    for (int j = 0; j < 6; j++) {
      int c = lane + 64 * j;
      float qv = __bfloat162float(qb[row * 384 + c]);
      qrow[wv][c / 48][c % 48] = qv;
    }
    __syncthreads();
    // logits: lane covers (h0,m0) and (h0+4,m0)
    float p0 = 0.f, p1 = 0.f;
    for (int d = 0; d < 48; d++) {
      float q0 = qrow[wv][h0][d];
      float q1 = qrow[wv][h0 + 4][d];
      p0 += q0 * khm[lane][d];
      p1 += q1 * khm[lane + 64][d];
    }
    // softmax over m within each 16-lane group, in registers
    float mx0 = p0, mx1 = p1;
#pragma unroll
    for (int off = 1; off < 16; off <<= 1) {
      mx0 = fmaxf(mx0, __shfl_xor(mx0, off));
      mx1 = fmaxf(mx1, __shfl_xor(mx1, off));
    }
    p0 = __expf(p0 - mx0);
    p1 = __expf(p1 - mx1);
    float s0 = p0, s1 = p1;
#pragma unroll
    for (int off = 1; off < 16; off <<= 1) {
      s0 += __shfl_xor(s0, off);
      s1 += __shfl_xor(s1, off);
    }
    pp[wv][h0][m0] = p0 / s0;
    pp[wv][h0 + 4][m0] = p1 / s1;
    __syncthreads();
    // PV + gl RMW
#pragma unroll
    for (int j = 0; j < 6; j++) {
      int c = lane + 64 * j;
      int h = c / 48;
      float acc = 0.f;
#pragma unroll
      for (int m = 0; m < 16; m++) acc += pp[wv][h][m] * __bfloat162float(vbs[m][c]);
      size_t o = row * 384 + c;
      gl[o] = __float2bfloat16(__bfloat162float(gl[o]) + acc);
    }
  }
}

// ---------------------------------------------------------------------------
extern "C" void kernel_launch(void* const* d_in, const int* in_sizes, int n_in,
                              void* d_out, int out_size, void* d_ws, size_t ws_size,
                              hipStream_t stream) {
  (void)in_sizes; (void)n_in; (void)out_size; (void)ws_size;
  const float* x = (const float*)d_in[0];
  const float* wsal = (const float*)d_in[3];
  const float* bsal = (const float*)d_in[4];
  const float* seeds = (const float*)d_in[5];
  const float* w_q_agg = (const float*)d_in[6];
  const float* w_kv_agg = (const float*)d_in[7];
  const float* w_q_self = (const float*)d_in[8];
  const float* w_kv_self = (const float*)d_in[9];
  const float* w_q_bcast = (const float*)d_in[10];
  const float* w_kv_bcast = (const float*)d_in[11];
  const float* dwk = (const float*)d_in[12];
  const float* w_proj = (const float*)d_in[13];
  float* out = (float*)d_out;

  char* ws = (char*)d_ws;
  size_t off = 0;
  auto take = [&](size_t bytes) -> void* {
    void* p = ws + off;
    off += (bytes + 255) & ~(size_t)255;
    return p;
  };
  __hip_bfloat16* xb = (__hip_bfloat16*)take(50331648);  // bf16(x); live to dwconv/qb-gemm
  __hip_bfloat16* kv = (__hip_bfloat16*)take(100663296); // kv; later qb (1st half) + gl (2nd)
  float* qseed = (float*)take(24576);
  float* pOut = (float*)take(6291456);
  float* pM = (float*)take(131072);
  float* pL = (float*)take(131072);
  float* anch1 = (float*)take(393216);
  float* anch2 = (float*)take(393216);
  float* q_self = (float*)take(393216);
  float* kv_self = (float*)take(786432);
  float* kv_b = (float*)take(786432);
  __hip_bfloat16* wkvT = (__hip_bfloat16*)take(589824);  // [768][384] bf16
  __hip_bfloat16* wqbT = (__hip_bfloat16*)take(294912);  // [384][384] bf16
  __hip_bfloat16* wprT = (__hip_bfloat16*)take(294912);  // [384][384] bf16
  float* kwp = (float*)take(13824);                      // [48][9][8]
  float* sal = pOut;            // alias: sal dead before pOut written
  __hip_bfloat16* qb = kv;      // alias: kv dead after agg_attn
  __hip_bfloat16* gl = kv + 25165824;  // second half

  // 0) weight prep (tiny)
  wcast_t<<<1152, 256, 0, stream>>>(w_kv_agg, wkvT, 384, 768);
  wcast_t<<<576, 256, 0, stream>>>(w_q_bcast, wqbT, 384, 384);
  wcast_t<<<576, 256, 0, stream>>>(w_proj, wprT, 384, 384);
  kwpack<<<14, 256, 0, stream>>>(dwk, kwp);
  // 1) xb + saliency
  prep<<<16384, 256, 0, stream>>>(x, wsal, bsal, xb, sal);
  // 2) kv = diag(sal) * (xb @ w_kv_agg)   [65536x768] bf16 MFMA, row-scale epilogue
  gemm_mfma<__hip_bfloat16, true><<<dim3(6, 512), 256, 0, stream>>>(xb, wkvT, kv, 768, sal);
  // 3) agg attention -> anchors1
  qseed_k<<<24, 256, 0, stream>>>(seeds, w_q_agg, qseed);
  agg_attn_partial<<<dim3(16, 8, 16), 256, 0, stream>>>(qseed, kv, pOut, pM, pL);
  agg_combine<<<128, 256, 0, stream>>>(pOut, pM, pL, seeds, anch1);
  // 4) anchor self-attention -> anchors2
  anchor_proj<<<dim3(2, 16), 256, 0, stream>>>(anch1, w_q_self, q_self, 384, 0, SCALE);
  anchor_proj<<<dim3(4, 16), 256, 0, stream>>>(anch1, w_kv_self, kv_self, 768, 0, 1.f);
  self_attn<<<128, 256, 0, stream>>>(q_self, kv_self, anch1, anch2);
  // 5) kv_bcast = anchors2 @ w_kv_bcast (SCALE folded into k half)
  anchor_proj<<<dim3(2, 16), 256, 0, stream>>>(anch2, w_kv_bcast, kv_b, 768, 0, SCALE);
  anchor_proj<<<dim3(2, 16), 256, 0, stream>>>(anch2, w_kv_bcast, kv_b, 768, 384, 1.f);
  // 6) qb = xb @ w_q_bcast (into dead kv region)
  gemm_mfma<__hip_bfloat16, false><<<dim3(3, 512), 256, 0, stream>>>(xb, wqbT, qb, 384, nullptr);
  // 7) depthwise conv -> gl
  dwconv<<<dim3(48, 16, 16), 256, 0, stream>>>(xb, kwp, gl);
  // 8) gl += broadcast attention
  bcast_attn<<<dim3(32, 16), 256, 0, stream>>>(qb, kv_b, gl);
  // 9) out = gl @ w_proj (f32)
  gemm_mfma<float, false><<<dim3(3, 512), 256, 0, stream>>>(gl, wprT, out, 384, nullptr);
}

// Round 4
// 994.027 us; speedup vs baseline: 2.2864x; 1.2432x over previous
//
#include <hip/hip_runtime.h>
#include <hip/hip_bf16.h>

// Problem constants: B=16, N=4096, C=384, M=16, NH=8, HD=48, H=W=64
#define SCALE 0.14433756729740643f  // 48^-0.5

typedef __attribute__((ext_vector_type(8))) short bf16x8;
typedef __attribute__((ext_vector_type(4))) float f32x4;

__device__ inline float b2f(short s) {
  union { unsigned int u; float f; } c;
  c.u = ((unsigned int)(unsigned short)s) << 16;
  return c.f;
}

template <typename T> __device__ inline T cvt_from_f(float v);
template <> __device__ inline float cvt_from_f<float>(float v) { return v; }
template <> __device__ inline __hip_bfloat16 cvt_from_f<__hip_bfloat16>(float v) { return __float2bfloat16(v); }

__device__ inline void gload16(const void* g, void* l) {
  __builtin_amdgcn_global_load_lds((const __attribute__((address_space(1))) void*)g,
                                   (__attribute__((address_space(3))) void*)l, 16, 0, 0);
}

// ---------------------------------------------------------------------------
// prep: xb = bf16(x); sal[row] = sigmoid(x·wsal + b). One wave per row.
// ---------------------------------------------------------------------------
__global__ __launch_bounds__(256) void prep(const float* __restrict__ x,
                                            const float* __restrict__ wsal,
                                            const float* __restrict__ bsal,
                                            __hip_bfloat16* __restrict__ xb,
                                            float* __restrict__ sal) {
  int wave = threadIdx.x >> 6, lane = threadIdx.x & 63;
  size_t row = (size_t)blockIdx.x * 4 + wave;
  const float* xr = x + row * 384;
  float xs[6];
  float part = 0.f;
#pragma unroll
  for (int j = 0; j < 6; j++) {
    int c = lane + 64 * j;
    xs[j] = xr[c];
    part += xs[j] * wsal[c];
  }
#pragma unroll
  for (int off = 32; off >= 1; off >>= 1) part += __shfl_xor(part, off);
  float s = 1.f / (1.f + __expf(-(part + bsal[0])));
#pragma unroll
  for (int j = 0; j < 6; j++) {
    int c = lane + 64 * j;
    xb[row * 384 + c] = __float2bfloat16(xs[j]);
  }
  if (lane == 0) sal[row] = s;
}

// ---------------------------------------------------------------------------
// Weight cast+transpose: wt[n*K+k] = bf16(w[k*N+n]).
// ---------------------------------------------------------------------------
__global__ void wcast_t(const float* __restrict__ w, __hip_bfloat16* __restrict__ wt,
                        int K, int N) {
  int idx = blockIdx.x * 256 + threadIdx.x;
  if (idx >= K * N) return;
  int n = idx / K, k = idx % K;
  wt[idx] = __float2bfloat16(w[(size_t)k * N + n]);
}

// ---------------------------------------------------------------------------
// MFMA GEMM: out[M,Ncols] = A[M,384](bf16) @ BT[Ncols,384]^T, optional row scale.
// 128x128 tile, BK=32, 4 waves, m97 structure.
// ---------------------------------------------------------------------------
template <typename OT, bool RS>
__global__ __launch_bounds__(256) void gemm_mfma(const __hip_bfloat16* __restrict__ A,
                                                 const __hip_bfloat16* __restrict__ BT,
                                                 OT* __restrict__ out, int Ncols,
                                                 const float* __restrict__ rowScale) {
  constexpr int K = 384;
  __shared__ __align__(16) __hip_bfloat16 Asl[128][32];
  __shared__ __align__(16) __hip_bfloat16 Bsl[128][32];
  int tid = threadIdx.x;
  int lane = tid & 63;
  int w = tid >> 6;
  int wr = w >> 1, wc = w & 1;
  int fr = lane & 15, fq = lane >> 4;
  int rowBase = blockIdx.y * 128, colBase = blockIdx.x * 128;

  int r1 = tid >> 2, kc1 = tid & 3;
  int r2 = (tid + 256) >> 2;

  char* aB1 = (char*)Asl + (size_t)(w * 64) * 16;
  char* aB2 = (char*)Asl + (size_t)(256 + w * 64) * 16;
  char* bB1 = (char*)Bsl + (size_t)(w * 64) * 16;
  char* bB2 = (char*)Bsl + (size_t)(256 + w * 64) * 16;

  const __hip_bfloat16* a1 = A + (size_t)(rowBase + r1) * K + kc1 * 8;
  const __hip_bfloat16* a2 = A + (size_t)(rowBase + r2) * K + kc1 * 8;
  const __hip_bfloat16* b1 = BT + (size_t)(colBase + r1) * K + kc1 * 8;
  const __hip_bfloat16* b2 = BT + (size_t)(colBase + r2) * K + kc1 * 8;

  f32x4 acc[4][4] = {};

  for (int kk = 0; kk < K; kk += 32) {
    gload16(a1 + kk, aB1);
    gload16(a2 + kk, aB2);
    gload16(b1 + kk, bB1);
    gload16(b2 + kk, bB2);
    __syncthreads();
    bf16x8 af[4], bfv[4];
#pragma unroll
    for (int m = 0; m < 4; m++) af[m] = *(const bf16x8*)&Asl[wr * 64 + m * 16 + fr][fq * 8];
#pragma unroll
    for (int n = 0; n < 4; n++) bfv[n] = *(const bf16x8*)&Bsl[wc * 64 + n * 16 + fr][fq * 8];
#pragma unroll
    for (int m = 0; m < 4; m++)
#pragma unroll
      for (int n = 0; n < 4; n++)
        acc[m][n] = __builtin_amdgcn_mfma_f32_16x16x32_bf16(af[m], bfv[n], acc[m][n], 0, 0, 0);
    __syncthreads();
  }

  if constexpr (RS) {
    float sv[4][4];
#pragma unroll
    for (int m = 0; m < 4; m++)
#pragma unroll
      for (int r = 0; r < 4; r++)
        sv[m][r] = rowScale[rowBase + wr * 64 + m * 16 + fq * 4 + r];
#pragma unroll
    for (int m = 0; m < 4; m++)
#pragma unroll
      for (int n = 0; n < 4; n++)
#pragma unroll
        for (int r = 0; r < 4; r++) acc[m][n][r] *= sv[m][r];
  }

#pragma unroll
  for (int m = 0; m < 4; m++) {
    int row0 = rowBase + wr * 64 + m * 16 + fq * 4;
#pragma unroll
    for (int n = 0; n < 4; n++) {
      int col = colBase + wc * 64 + n * 16 + fr;
      f32x4 v = acc[m][n];
#pragma unroll
      for (int r = 0; r < 4; r++) out[(size_t)(row0 + r) * Ncols + col] = cvt_from_f<OT>(v[r]);
    }
  }
}

// ---------------------------------------------------------------------------
// q_seed[16,384] = anchor_seeds @ w_q_agg * SCALE.
// ---------------------------------------------------------------------------
__global__ void qseed_k(const float* __restrict__ seeds, const float* __restrict__ wq,
                        float* __restrict__ qseed) {
  int idx = blockIdx.x * 256 + threadIdx.x;
  int m = idx / 384, c = idx % 384;
  float acc = 0.f;
  for (int k = 0; k < 384; k++) acc += seeds[m * 384 + k] * wq[k * 384 + c];
  qseed[idx] = acc * SCALE;
}

// ---------------------------------------------------------------------------
// Agg attention partials: block = (s, h, b); keys [s*256, s*256+256).
// ---------------------------------------------------------------------------
__global__ __launch_bounds__(256) void agg_attn_partial(
    const float* __restrict__ qseed, const __hip_bfloat16* __restrict__ kv,
    float* __restrict__ pOut, float* __restrict__ pM, float* __restrict__ pL) {
  int s = blockIdx.x, h = blockIdx.y, b = blockIdx.z;
  __shared__ float qs[16][48];
  __shared__ float kt[64][49];
  __shared__ float vt[64][49];
  __shared__ float lg[16][65];
  __shared__ float outb[16][48];
  __shared__ float mrow[16], lrow[16], rrow[16];
  int tid = threadIdx.x;
  for (int idx = tid; idx < 16 * 48; idx += 256)
    qs[idx / 48][idx % 48] = qseed[(idx / 48) * 384 + h * 48 + idx % 48];
  for (int idx = tid; idx < 16 * 48; idx += 256) outb[idx / 48][idx % 48] = 0.f;
  if (tid < 16) {
    mrow[tid] = -1e30f;
    lrow[tid] = 0.f;
  }
  __syncthreads();
  int k0 = s * 256;
  for (int t = 0; t < 4; t++) {
    int kb = k0 + t * 64;
#pragma unroll
    for (int i = 0; i < 3; i++) {
      int idx = tid + i * 256;
      int mat = idx / 384;
      int id2 = idx - mat * 384;
      int r = id2 / 6, oc = id2 - r * 6;
      bf16x8 v = *(const bf16x8*)(kv + ((size_t)(b * 4096 + kb + r)) * 768 + mat * 384 + h * 48 + oc * 8);
      float* dst = mat ? &vt[r][oc * 8] : &kt[r][oc * 8];
#pragma unroll
      for (int j = 0; j < 8; j++) dst[j] = b2f(v[j]);
    }
    __syncthreads();
    for (int idx = tid; idx < 16 * 64; idx += 256) {
      int m = idx >> 6, kkk = idx & 63;
      float acc = 0.f;
      for (int d = 0; d < 48; d++) acc += qs[m][d] * kt[kkk][d];
      lg[m][kkk] = acc;
    }
    __syncthreads();
    if (tid < 64) {
      int m = tid >> 2, q = tid & 3;
      float mx = mrow[m];
      for (int i = 0; i < 16; i++) mx = fmaxf(mx, lg[m][q * 16 + i]);
      mx = fmaxf(mx, __shfl_xor(mx, 1));
      mx = fmaxf(mx, __shfl_xor(mx, 2));
      float r = __expf(mrow[m] - mx);
      float sum = 0.f;
      for (int i = 0; i < 16; i++) {
        float e = __expf(lg[m][q * 16 + i] - mx);
        lg[m][q * 16 + i] = e;
        sum += e;
      }
      sum += __shfl_xor(sum, 1);
      sum += __shfl_xor(sum, 2);
      if (q == 0) {
        rrow[m] = r;
        lrow[m] = lrow[m] * r + sum;
        mrow[m] = mx;
      }
    }
    __syncthreads();
    for (int idx = tid; idx < 16 * 48; idx += 256) {
      int m = idx / 48, d = idx % 48;
      float acc = outb[m][d] * rrow[m];
      for (int kkk = 0; kkk < 64; kkk++) acc += lg[m][kkk] * vt[kkk][d];
      outb[m][d] = acc;
    }
    __syncthreads();
  }
  int g = (b * 8 + h) * 16 + s;
  for (int idx = tid; idx < 16 * 48; idx += 256) pOut[(size_t)g * 768 + idx] = outb[idx / 48][idx % 48];
  if (tid < 16) {
    pM[g * 16 + tid] = mrow[tid];
    pL[g * 16 + tid] = lrow[tid];
  }
}

// ---------------------------------------------------------------------------
// Combine agg partials -> anchors1 = seeds + attn_out.
// ---------------------------------------------------------------------------
__global__ void agg_combine(const float* __restrict__ pOut, const float* __restrict__ pM,
                            const float* __restrict__ pL, const float* __restrict__ seeds,
                            float* __restrict__ anch1) {
  int h = blockIdx.x & 7, b = blockIdx.x >> 3;
  int g = b * 8 + h;
  __shared__ float gm[16], glsum[16];
  int tid = threadIdx.x;
  if (tid < 16) {
    int m = tid;
    float mx = -1e30f;
    for (int s = 0; s < 16; s++) mx = fmaxf(mx, pM[(g * 16 + s) * 16 + m]);
    float l = 0.f;
    for (int s = 0; s < 16; s++) l += pL[(g * 16 + s) * 16 + m] * __expf(pM[(g * 16 + s) * 16 + m] - mx);
    gm[m] = mx;
    glsum[m] = l;
  }
  __syncthreads();
  for (int idx = tid; idx < 768; idx += 256) {
    int m = idx / 48, d = idx % 48;
    float acc = 0.f;
    for (int s = 0; s < 16; s++) {
      int p = g * 16 + s;
      acc += pOut[(size_t)p * 768 + idx] * __expf(pM[p * 16 + m] - gm[m]);
    }
    float o = acc / glsum[m];
    int c = h * 48 + d;
    anch1[(b * 16 + m) * 384 + c] = seeds[m * 384 + c] + o;
  }
}

// ---------------------------------------------------------------------------
// Anchor projection: out[b,16,cols] = A[b,16,384] @ W[384, wstride] slice.
// ---------------------------------------------------------------------------
__global__ void anchor_proj(const float* __restrict__ Aanch, const float* __restrict__ Wmat,
                            float* __restrict__ out, int wstride, int col0, float scale) {
  int cs = col0 + blockIdx.x * 192;
  int b = blockIdx.y;
  __shared__ float a1[16][384];
  int tid = threadIdx.x;
  for (int idx = tid; idx < 16 * 384; idx += 256) a1[idx / 384][idx % 384] = Aanch[b * 6144 + idx];
  __syncthreads();
  for (int o = tid; o < 16 * 192; o += 256) {
    int m = o / 192, cc = o % 192;
    float acc = 0.f;
    for (int k = 0; k < 384; k++) acc += a1[m][k] * Wmat[(size_t)k * wstride + cs + cc];
    out[((size_t)b * 16 + m) * wstride + cs + cc] = acc * scale;
  }
}

// ---------------------------------------------------------------------------
// Self attention on anchors (16x16, per (b,h)); anchors2 = anchors1 + out.
// ---------------------------------------------------------------------------
__global__ void self_attn(const float* __restrict__ qsf, const float* __restrict__ kvs,
                          const float* __restrict__ anch1, float* __restrict__ anch2) {
  int h = blockIdx.x & 7, b = blockIdx.x >> 3;
  __shared__ float qs[16][48], ks[16][48], vs[16][48], p[16][17];
  int tid = threadIdx.x;
  for (int idx = tid; idx < 768; idx += 256) {
    int m = idx / 48, d = idx % 48;
    qs[m][d] = qsf[(b * 16 + m) * 384 + h * 48 + d];
    ks[m][d] = kvs[(b * 16 + m) * 768 + h * 48 + d];
    vs[m][d] = kvs[(b * 16 + m) * 768 + 384 + h * 48 + d];
  }
  __syncthreads();
  {
    int mq = tid >> 4, mk = tid & 15;
    float acc = 0.f;
    for (int d = 0; d < 48; d++) acc += qs[mq][d] * ks[mk][d];
    p[mq][mk] = acc;
  }
  __syncthreads();
  if (tid < 16) {
    float mx = -1e30f;
    for (int mk = 0; mk < 16; mk++) mx = fmaxf(mx, p[tid][mk]);
    float sum = 0.f;
    for (int mk = 0; mk < 16; mk++) {
      float e = __expf(p[tid][mk] - mx);
      p[tid][mk] = e;
      sum += e;
    }
    float inv = 1.f / sum;
    for (int mk = 0; mk < 16; mk++) p[tid][mk] *= inv;
  }
  __syncthreads();
  for (int idx = tid; idx < 768; idx += 256) {
    int m = idx / 48, d = idx % 48;
    float acc = 0.f;
    for (int mk = 0; mk < 16; mk++) acc += p[m][mk] * vs[mk][d];
    int c = h * 48 + d;
    anch2[(b * 16 + m) * 384 + c] = anch1[(b * 16 + m) * 384 + c] + acc;
  }
}

// ---------------------------------------------------------------------------
// Fused depthwise conv + broadcast attention: gl = conv(x) + attn(qb; kv_b).
// Block = 16 positions of one batch (4 waves x 4 iters); wave = one position.
// Lane owns 6 CONTIGUOUS channels (c = lane*6..+5) -> coalesced tap reads.
// ---------------------------------------------------------------------------
__global__ __launch_bounds__(256) void local_bcast(const __hip_bfloat16* __restrict__ xb,
                                                   const float* __restrict__ dwk,
                                                   const __hip_bfloat16* __restrict__ qb,
                                                   const float* __restrict__ kvb,
                                                   __hip_bfloat16* __restrict__ gl) {
  int b = blockIdx.y;
  __shared__ float khm[128][49];
  __shared__ __hip_bfloat16 vbs[16][384];
  __shared__ float qrow[4][8][49];
  __shared__ float pp[4][8][17];
  int tid = threadIdx.x;
  const float* kvB = kvb + (size_t)b * 16 * 768;
  for (int idx = tid; idx < 6144; idx += 256) {
    int hm = idx / 48, d = idx - hm * 48;
    khm[hm][d] = kvB[(hm & 15) * 768 + (hm >> 4) * 48 + d];
  }
  for (int idx = tid; idx < 6144; idx += 256) {
    int m = idx / 384, c = idx - m * 384;
    vbs[m][c] = __float2bfloat16(kvB[m * 768 + 384 + c]);
  }
  int wv = tid >> 6, lane = tid & 63;
  int h0 = lane >> 4, m0 = lane & 15;
  int hl = lane >> 3;   // head of this lane's 6 contiguous channels
  int c0 = lane * 6;
  // conv weights in registers (once per kernel)
  float kw[6][9];
#pragma unroll
  for (int i = 0; i < 6; i++)
#pragma unroll
    for (int ki = 0; ki < 9; ki++) kw[i][ki] = dwk[(c0 + i) * 9 + ki];
  __syncthreads();
  for (int it = 0; it < 4; it++) {
    int p = blockIdx.x * 16 + wv * 4 + it;
    int y = p >> 6, w = p & 63;
    size_t prow = (size_t)b * 4096 + p;
    // q row -> LDS broadcast (d' = (lane&7)*6 + i)
    {
      const __hip_bfloat16* qp = qb + prow * 384 + c0;
      int dbase = (lane & 7) * 6;
#pragma unroll
      for (int i = 0; i < 6; i++) qrow[wv][hl][dbase + i] = __bfloat162float(qp[i]);
    }
    __syncthreads();
    // logits for (h0,m0) and (h0+4,m0)
    float pl0 = 0.f, pl1 = 0.f;
#pragma unroll
    for (int d = 0; d < 48; d++) {
      pl0 += qrow[wv][h0][d] * khm[lane][d];
      pl1 += qrow[wv][h0 + 4][d] * khm[lane + 64][d];
    }
    float mx0 = pl0, mx1 = pl1;
#pragma unroll
    for (int offm = 1; offm < 16; offm <<= 1) {
      mx0 = fmaxf(mx0, __shfl_xor(mx0, offm));
      mx1 = fmaxf(mx1, __shfl_xor(mx1, offm));
    }
    pl0 = __expf(pl0 - mx0);
    pl1 = __expf(pl1 - mx1);
    float s0 = pl0, s1 = pl1;
#pragma unroll
    for (int offm = 1; offm < 16; offm <<= 1) {
      s0 += __shfl_xor(s0, offm);
      s1 += __shfl_xor(s1, offm);
    }
    pp[wv][h0][m0] = pl0 / s0;
    pp[wv][h0 + 4][m0] = pl1 / s1;
    __syncthreads();
    // attention PV
    float acc[6];
#pragma unroll
    for (int i = 0; i < 6; i++) {
      float a = 0.f;
#pragma unroll
      for (int m = 0; m < 16; m++) a += pp[wv][hl][m] * __bfloat162float(vbs[m][c0 + i]);
      acc[i] = a;
    }
    // depthwise 3x3 conv, coalesced taps
#pragma unroll
    for (int dy = -1; dy <= 1; dy++) {
      int yy = y + dy;
      if (yy < 0 || yy >= 64) continue;
#pragma unroll
      for (int dx = -1; dx <= 1; dx++) {
        int ww = w + dx;
        if (ww < 0 || ww >= 64) continue;
        int ki = (dy + 1) * 3 + (dx + 1);
        const __hip_bfloat16* xp = xb + ((size_t)(b * 4096 + yy * 64 + ww)) * 384 + c0;
#pragma unroll
        for (int i = 0; i < 6; i++) acc[i] += __bfloat162float(xp[i]) * kw[i][ki];
      }
    }
    __hip_bfloat16 tb[6];
#pragma unroll
    for (int i = 0; i < 6; i++) tb[i] = __float2bfloat16(acc[i]);
    __hip_bfloat16* gp = gl + prow * 384 + c0;
    *(unsigned int*)(gp) = *(unsigned int*)(tb);
    *(unsigned int*)(gp + 2) = *(unsigned int*)(tb + 2);
    *(unsigned int*)(gp + 4) = *(unsigned int*)(tb + 4);
  }
}

// ---------------------------------------------------------------------------
extern "C" void kernel_launch(void* const* d_in, const int* in_sizes, int n_in,
                              void* d_out, int out_size, void* d_ws, size_t ws_size,
                              hipStream_t stream) {
  (void)in_sizes; (void)n_in; (void)out_size; (void)ws_size;
  const float* x = (const float*)d_in[0];
  const float* wsal = (const float*)d_in[3];
  const float* bsal = (const float*)d_in[4];
  const float* seeds = (const float*)d_in[5];
  const float* w_q_agg = (const float*)d_in[6];
  const float* w_kv_agg = (const float*)d_in[7];
  const float* w_q_self = (const float*)d_in[8];
  const float* w_kv_self = (const float*)d_in[9];
  const float* w_q_bcast = (const float*)d_in[10];
  const float* w_kv_bcast = (const float*)d_in[11];
  const float* dwk = (const float*)d_in[12];
  const float* w_proj = (const float*)d_in[13];
  float* out = (float*)d_out;

  char* ws = (char*)d_ws;
  size_t off = 0;
  auto take = [&](size_t bytes) -> void* {
    void* p = ws + off;
    off += (bytes + 255) & ~(size_t)255;
    return p;
  };
  __hip_bfloat16* xb = (__hip_bfloat16*)take(50331648);  // bf16(x)
  __hip_bfloat16* kv = (__hip_bfloat16*)take(100663296); // kv; later qb (1st half) + gl (2nd)
  float* qseed = (float*)take(24576);
  float* pOut = (float*)take(6291456);
  float* pM = (float*)take(131072);
  float* pL = (float*)take(131072);
  float* anch1 = (float*)take(393216);
  float* anch2 = (float*)take(393216);
  float* q_self = (float*)take(393216);
  float* kv_self = (float*)take(786432);
  float* kv_b = (float*)take(786432);
  __hip_bfloat16* wkvT = (__hip_bfloat16*)take(589824);  // [768][384] bf16
  __hip_bfloat16* wqbT = (__hip_bfloat16*)take(294912);  // [384][384] bf16
  __hip_bfloat16* wprT = (__hip_bfloat16*)take(294912);  // [384][384] bf16
  float* sal = pOut;                   // alias: sal dead before pOut written
  __hip_bfloat16* qb = kv;             // alias: kv dead after agg_attn
  __hip_bfloat16* gl = kv + 25165824;  // second half

  // 0) weight prep (tiny)
  wcast_t<<<1152, 256, 0, stream>>>(w_kv_agg, wkvT, 384, 768);
  wcast_t<<<576, 256, 0, stream>>>(w_q_bcast, wqbT, 384, 384);
  wcast_t<<<576, 256, 0, stream>>>(w_proj, wprT, 384, 384);
  // 1) xb + saliency
  prep<<<16384, 256, 0, stream>>>(x, wsal, bsal, xb, sal);
  // 2) kv = diag(sal) * (xb @ w_kv_agg)   [65536x768] bf16 MFMA, row-scale epilogue
  gemm_mfma<__hip_bfloat16, true><<<dim3(6, 512), 256, 0, stream>>>(xb, wkvT, kv, 768, sal);
  // 3) agg attention -> anchors1
  qseed_k<<<24, 256, 0, stream>>>(seeds, w_q_agg, qseed);
  agg_attn_partial<<<dim3(16, 8, 16), 256, 0, stream>>>(qseed, kv, pOut, pM, pL);
  agg_combine<<<128, 256, 0, stream>>>(pOut, pM, pL, seeds, anch1);
  // 4) anchor self-attention -> anchors2
  anchor_proj<<<dim3(2, 16), 256, 0, stream>>>(anch1, w_q_self, q_self, 384, 0, SCALE);
  anchor_proj<<<dim3(4, 16), 256, 0, stream>>>(anch1, w_kv_self, kv_self, 768, 0, 1.f);
  self_attn<<<128, 256, 0, stream>>>(q_self, kv_self, anch1, anch2);
  // 5) kv_bcast = anchors2 @ w_kv_bcast (SCALE folded into k half)
  anchor_proj<<<dim3(2, 16), 256, 0, stream>>>(anch2, w_kv_bcast, kv_b, 768, 0, SCALE);
  anchor_proj<<<dim3(2, 16), 256, 0, stream>>>(anch2, w_kv_bcast, kv_b, 768, 384, 1.f);
  // 6) qb = xb @ w_q_bcast (into dead kv region)
  gemm_mfma<__hip_bfloat16, false><<<dim3(3, 512), 256, 0, stream>>>(xb, wqbT, qb, 384, nullptr);
  // 7+8) gl = dwconv(x) + bcast attention (fused, single write)
  local_bcast<<<dim3(256, 16), 256, 0, stream>>>(xb, dwk, qb, kv_b, gl);
  // 9) out = gl @ w_proj (f32)
  gemm_mfma<float, false><<<dim3(3, 512), 256, 0, stream>>>(gl, wprT, out, 384, nullptr);
}

// Round 5
// 942.829 us; speedup vs baseline: 2.4105x; 1.0543x over previous
//
#include <hip/hip_runtime.h>
#include <hip/hip_bf16.h>

// Problem constants: B=16, N=4096, C=384, M=16, NH=8, HD=48, H=W=64
#define SCALE 0.14433756729740643f  // 48^-0.5

typedef __attribute__((ext_vector_type(8))) short bf16x8;
typedef __attribute__((ext_vector_type(4))) float f32x4;

__device__ inline float b2f(short s) {
  union { unsigned int u; float f; } c;
  c.u = ((unsigned int)(unsigned short)s) << 16;
  return c.f;
}

template <typename T> __device__ inline T cvt_from_f(float v);
template <> __device__ inline float cvt_from_f<float>(float v) { return v; }
template <> __device__ inline __hip_bfloat16 cvt_from_f<__hip_bfloat16>(float v) { return __float2bfloat16(v); }

__device__ inline void gload16(const void* g, void* l) {
  __builtin_amdgcn_global_load_lds((const __attribute__((address_space(1))) void*)g,
                                   (__attribute__((address_space(3))) void*)l, 16, 0, 0);
}

// ---------------------------------------------------------------------------
// prep: xb = bf16(x); sal[row] = sigmoid(x·wsal + b). One wave per row.
// ---------------------------------------------------------------------------
__global__ __launch_bounds__(256) void prep(const float* __restrict__ x,
                                            const float* __restrict__ wsal,
                                            const float* __restrict__ bsal,
                                            __hip_bfloat16* __restrict__ xb,
                                            float* __restrict__ sal) {
  int wave = threadIdx.x >> 6, lane = threadIdx.x & 63;
  size_t row = (size_t)blockIdx.x * 4 + wave;
  const float* xr = x + row * 384;
  float xs[6];
  float part = 0.f;
#pragma unroll
  for (int j = 0; j < 6; j++) {
    int c = lane + 64 * j;
    xs[j] = xr[c];
    part += xs[j] * wsal[c];
  }
#pragma unroll
  for (int off = 32; off >= 1; off >>= 1) part += __shfl_xor(part, off);
  float s = 1.f / (1.f + __expf(-(part + bsal[0])));
#pragma unroll
  for (int j = 0; j < 6; j++) {
    int c = lane + 64 * j;
    xb[row * 384 + c] = __float2bfloat16(xs[j]);
  }
  if (lane == 0) sal[row] = s;
}

// ---------------------------------------------------------------------------
// Weight cast+transpose: wt[n*K+k] = bf16(w[k*N+n]).
// ---------------------------------------------------------------------------
__global__ void wcast_t(const float* __restrict__ w, __hip_bfloat16* __restrict__ wt,
                        int K, int N) {
  int idx = blockIdx.x * 256 + threadIdx.x;
  if (idx >= K * N) return;
  int n = idx / K, k = idx % K;
  wt[idx] = __float2bfloat16(w[(size_t)k * N + n]);
}

// ---------------------------------------------------------------------------
// MFMA GEMM: out[M,Ncols] = A[M,K](bf16) @ BT[Ncols,K]^T, optional row scale,
// optional per-batch BT (batch = rowBase/4096). 128x128 tile, BK=32, 4 waves.
// ---------------------------------------------------------------------------
template <int K, typename OT, bool RS>
__global__ __launch_bounds__(256) void gemm_mfma(const __hip_bfloat16* __restrict__ A,
                                                 const __hip_bfloat16* __restrict__ BT,
                                                 OT* __restrict__ out, int Ncols,
                                                 const float* __restrict__ rowScale,
                                                 size_t btBatchStride) {
  __shared__ __align__(16) __hip_bfloat16 Asl[128][32];
  __shared__ __align__(16) __hip_bfloat16 Bsl[128][32];
  int tid = threadIdx.x;
  int lane = tid & 63;
  int w = tid >> 6;
  int wr = w >> 1, wc = w & 1;
  int fr = lane & 15, fq = lane >> 4;
  int rowBase = blockIdx.y * 128, colBase = blockIdx.x * 128;
  const __hip_bfloat16* BTb = BT + (size_t)(rowBase >> 12) * btBatchStride;

  int r1 = tid >> 2, kc1 = tid & 3;
  int r2 = (tid + 256) >> 2;

  char* aB1 = (char*)Asl + (size_t)(w * 64) * 16;
  char* aB2 = (char*)Asl + (size_t)(256 + w * 64) * 16;
  char* bB1 = (char*)Bsl + (size_t)(w * 64) * 16;
  char* bB2 = (char*)Bsl + (size_t)(256 + w * 64) * 16;

  const __hip_bfloat16* a1 = A + (size_t)(rowBase + r1) * K + kc1 * 8;
  const __hip_bfloat16* a2 = A + (size_t)(rowBase + r2) * K + kc1 * 8;
  const __hip_bfloat16* b1 = BTb + (size_t)(colBase + r1) * K + kc1 * 8;
  const __hip_bfloat16* b2 = BTb + (size_t)(colBase + r2) * K + kc1 * 8;

  f32x4 acc[4][4] = {};

  for (int kk = 0; kk < K; kk += 32) {
    gload16(a1 + kk, aB1);
    gload16(a2 + kk, aB2);
    gload16(b1 + kk, bB1);
    gload16(b2 + kk, bB2);
    __syncthreads();
    bf16x8 af[4], bfv[4];
#pragma unroll
    for (int m = 0; m < 4; m++) af[m] = *(const bf16x8*)&Asl[wr * 64 + m * 16 + fr][fq * 8];
#pragma unroll
    for (int n = 0; n < 4; n++) bfv[n] = *(const bf16x8*)&Bsl[wc * 64 + n * 16 + fr][fq * 8];
#pragma unroll
    for (int m = 0; m < 4; m++)
#pragma unroll
      for (int n = 0; n < 4; n++)
        acc[m][n] = __builtin_amdgcn_mfma_f32_16x16x32_bf16(af[m], bfv[n], acc[m][n], 0, 0, 0);
    __syncthreads();
  }

  if constexpr (RS) {
    float sv[4][4];
#pragma unroll
    for (int m = 0; m < 4; m++)
#pragma unroll
      for (int r = 0; r < 4; r++)
        sv[m][r] = rowScale[rowBase + wr * 64 + m * 16 + fq * 4 + r];
#pragma unroll
    for (int m = 0; m < 4; m++)
#pragma unroll
      for (int n = 0; n < 4; n++)
#pragma unroll
        for (int r = 0; r < 4; r++) acc[m][n][r] *= sv[m][r];
  }

#pragma unroll
  for (int m = 0; m < 4; m++) {
    int row0 = rowBase + wr * 64 + m * 16 + fq * 4;
#pragma unroll
    for (int n = 0; n < 4; n++) {
      int col = colBase + wc * 64 + n * 16 + fr;
      f32x4 v = acc[m][n];
#pragma unroll
      for (int r = 0; r < 4; r++) out[(size_t)(row0 + r) * Ncols + col] = cvt_from_f<OT>(v[r]);
    }
  }
}

// ---------------------------------------------------------------------------
// pgemm: P = softmax_per_head(xb @ W_pbT_b^T), written bf16 to A2[:,384+hm].
// N=128 (all heads in one tile); softmax across the 16-lane fr group.
// Grid: (1, 512).
// ---------------------------------------------------------------------------
__global__ __launch_bounds__(256) void pgemm(const __hip_bfloat16* __restrict__ A,
                                             const __hip_bfloat16* __restrict__ wpbT,
                                             __hip_bfloat16* __restrict__ A2) {
  constexpr int K = 384;
  __shared__ __align__(16) __hip_bfloat16 Asl[128][32];
  __shared__ __align__(16) __hip_bfloat16 Bsl[128][32];
  int tid = threadIdx.x;
  int lane = tid & 63;
  int w = tid >> 6;
  int wr = w >> 1, wc = w & 1;
  int fr = lane & 15, fq = lane >> 4;
  int rowBase = blockIdx.y * 128;
  const __hip_bfloat16* BTb = wpbT + (size_t)(rowBase >> 12) * (128 * 384);

  int r1 = tid >> 2, kc1 = tid & 3;
  int r2 = (tid + 256) >> 2;

  char* aB1 = (char*)Asl + (size_t)(w * 64) * 16;
  char* aB2 = (char*)Asl + (size_t)(256 + w * 64) * 16;
  char* bB1 = (char*)Bsl + (size_t)(w * 64) * 16;
  char* bB2 = (char*)Bsl + (size_t)(256 + w * 64) * 16;

  const __hip_bfloat16* a1 = A + (size_t)(rowBase + r1) * K + kc1 * 8;
  const __hip_bfloat16* a2 = A + (size_t)(rowBase + r2) * K + kc1 * 8;
  const __hip_bfloat16* b1 = BTb + (size_t)r1 * K + kc1 * 8;
  const __hip_bfloat16* b2 = BTb + (size_t)r2 * K + kc1 * 8;

  f32x4 acc[4][4] = {};

  for (int kk = 0; kk < K; kk += 32) {
    gload16(a1 + kk, aB1);
    gload16(a2 + kk, aB2);
    gload16(b1 + kk, bB1);
    gload16(b2 + kk, bB2);
    __syncthreads();
    bf16x8 af[4], bfv[4];
#pragma unroll
    for (int m = 0; m < 4; m++) af[m] = *(const bf16x8*)&Asl[wr * 64 + m * 16 + fr][fq * 8];
#pragma unroll
    for (int n = 0; n < 4; n++) bfv[n] = *(const bf16x8*)&Bsl[wc * 64 + n * 16 + fr][fq * 8];
#pragma unroll
    for (int m = 0; m < 4; m++)
#pragma unroll
      for (int n = 0; n < 4; n++)
        acc[m][n] = __builtin_amdgcn_mfma_f32_16x16x32_bf16(af[m], bfv[n], acc[m][n], 0, 0, 0);
    __syncthreads();
  }

  // epilogue: per (row, head) softmax over the 16-lane fr group.
  // col = wc*64 + n*16 + fr -> head h = wc*4+n, member m-index = fr.
#pragma unroll
  for (int m = 0; m < 4; m++) {
    int row0 = rowBase + wr * 64 + m * 16 + fq * 4;
#pragma unroll
    for (int n = 0; n < 4; n++) {
      int col = wc * 64 + n * 16 + fr;
      f32x4 v = acc[m][n];
      f32x4 mx = v;
#pragma unroll
      for (int off = 1; off < 16; off <<= 1)
#pragma unroll
        for (int r = 0; r < 4; r++) mx[r] = fmaxf(mx[r], __shfl_xor(mx[r], off));
      f32x4 e;
#pragma unroll
      for (int r = 0; r < 4; r++) e[r] = __expf(v[r] - mx[r]);
      f32x4 s = e;
#pragma unroll
      for (int off = 1; off < 16; off <<= 1)
#pragma unroll
        for (int r = 0; r < 4; r++) s[r] += __shfl_xor(s[r], off);
#pragma unroll
      for (int r = 0; r < 4; r++)
        A2[(size_t)(row0 + r) * 512 + 384 + col] = __float2bfloat16(e[r] / s[r]);
    }
  }
}

// ---------------------------------------------------------------------------
// q_seed[16,384] = anchor_seeds @ w_q_agg * SCALE.
// ---------------------------------------------------------------------------
__global__ void qseed_k(const float* __restrict__ seeds, const float* __restrict__ wq,
                        float* __restrict__ qseed) {
  int idx = blockIdx.x * 256 + threadIdx.x;
  int m = idx / 384, c = idx % 384;
  float acc = 0.f;
  for (int k = 0; k < 384; k++) acc += seeds[m * 384 + k] * wq[k * 384 + c];
  qseed[idx] = acc * SCALE;
}

// ---------------------------------------------------------------------------
// Agg attention partials: block = (s, h, b); keys [s*256, s*256+256).
// ---------------------------------------------------------------------------
__global__ __launch_bounds__(256) void agg_attn_partial(
    const float* __restrict__ qseed, const __hip_bfloat16* __restrict__ kv,
    float* __restrict__ pOut, float* __restrict__ pM, float* __restrict__ pL) {
  int s = blockIdx.x, h = blockIdx.y, b = blockIdx.z;
  __shared__ float qs[16][48];
  __shared__ float kt[64][49];
  __shared__ float vt[64][49];
  __shared__ float lg[16][65];
  __shared__ float outb[16][48];
  __shared__ float mrow[16], lrow[16], rrow[16];
  int tid = threadIdx.x;
  for (int idx = tid; idx < 16 * 48; idx += 256)
    qs[idx / 48][idx % 48] = qseed[(idx / 48) * 384 + h * 48 + idx % 48];
  for (int idx = tid; idx < 16 * 48; idx += 256) outb[idx / 48][idx % 48] = 0.f;
  if (tid < 16) {
    mrow[tid] = -1e30f;
    lrow[tid] = 0.f;
  }
  __syncthreads();
  int k0 = s * 256;
  for (int t = 0; t < 4; t++) {
    int kb = k0 + t * 64;
#pragma unroll
    for (int i = 0; i < 3; i++) {
      int idx = tid + i * 256;
      int mat = idx / 384;
      int id2 = idx - mat * 384;
      int r = id2 / 6, oc = id2 - r * 6;
      bf16x8 v = *(const bf16x8*)(kv + ((size_t)(b * 4096 + kb + r)) * 768 + mat * 384 + h * 48 + oc * 8);
      float* dst = mat ? &vt[r][oc * 8] : &kt[r][oc * 8];
#pragma unroll
      for (int j = 0; j < 8; j++) dst[j] = b2f(v[j]);
    }
    __syncthreads();
    for (int idx = tid; idx < 16 * 64; idx += 256) {
      int m = idx >> 6, kkk = idx & 63;
      float acc = 0.f;
      for (int d = 0; d < 48; d++) acc += qs[m][d] * kt[kkk][d];
      lg[m][kkk] = acc;
    }
    __syncthreads();
    if (tid < 64) {
      int m = tid >> 2, q = tid & 3;
      float mx = mrow[m];
      for (int i = 0; i < 16; i++) mx = fmaxf(mx, lg[m][q * 16 + i]);
      mx = fmaxf(mx, __shfl_xor(mx, 1));
      mx = fmaxf(mx, __shfl_xor(mx, 2));
      float r = __expf(mrow[m] - mx);
      float sum = 0.f;
      for (int i = 0; i < 16; i++) {
        float e = __expf(lg[m][q * 16 + i] - mx);
        lg[m][q * 16 + i] = e;
        sum += e;
      }
      sum += __shfl_xor(sum, 1);
      sum += __shfl_xor(sum, 2);
      if (q == 0) {
        rrow[m] = r;
        lrow[m] = lrow[m] * r + sum;
        mrow[m] = mx;
      }
    }
    __syncthreads();
    for (int idx = tid; idx < 16 * 48; idx += 256) {
      int m = idx / 48, d = idx % 48;
      float acc = outb[m][d] * rrow[m];
      for (int kkk = 0; kkk < 64; kkk++) acc += lg[m][kkk] * vt[kkk][d];
      outb[m][d] = acc;
    }
    __syncthreads();
  }
  int g = (b * 8 + h) * 16 + s;
  for (int idx = tid; idx < 16 * 48; idx += 256) pOut[(size_t)g * 768 + idx] = outb[idx / 48][idx % 48];
  if (tid < 16) {
    pM[g * 16 + tid] = mrow[tid];
    pL[g * 16 + tid] = lrow[tid];
  }
}

// ---------------------------------------------------------------------------
// Combine agg partials -> anchors1 = seeds + attn_out.
// ---------------------------------------------------------------------------
__global__ void agg_combine(const float* __restrict__ pOut, const float* __restrict__ pM,
                            const float* __restrict__ pL, const float* __restrict__ seeds,
                            float* __restrict__ anch1) {
  int h = blockIdx.x & 7, b = blockIdx.x >> 3;
  int g = b * 8 + h;
  __shared__ float gm[16], glsum[16];
  int tid = threadIdx.x;
  if (tid < 16) {
    int m = tid;
    float mx = -1e30f;
    for (int s = 0; s < 16; s++) mx = fmaxf(mx, pM[(g * 16 + s) * 16 + m]);
    float l = 0.f;
    for (int s = 0; s < 16; s++) l += pL[(g * 16 + s) * 16 + m] * __expf(pM[(g * 16 + s) * 16 + m] - mx);
    gm[m] = mx;
    glsum[m] = l;
  }
  __syncthreads();
  for (int idx = tid; idx < 768; idx += 256) {
    int m = idx / 48, d = idx % 48;
    float acc = 0.f;
    for (int s = 0; s < 16; s++) {
      int p = g * 16 + s;
      acc += pOut[(size_t)p * 768 + idx] * __expf(pM[p * 16 + m] - gm[m]);
    }
    float o = acc / glsum[m];
    int c = h * 48 + d;
    anch1[(b * 16 + m) * 384 + c] = seeds[m * 384 + c] + o;
  }
}

// ---------------------------------------------------------------------------
// Anchor projection: out[b,16,cols] = A[b,16,384] @ W[384, wstride] slice.
// ---------------------------------------------------------------------------
__global__ void anchor_proj(const float* __restrict__ Aanch, const float* __restrict__ Wmat,
                            float* __restrict__ out, int wstride, int col0, float scale) {
  int cs = col0 + blockIdx.x * 192;
  int b = blockIdx.y;
  __shared__ float a1[16][384];
  int tid = threadIdx.x;
  for (int idx = tid; idx < 16 * 384; idx += 256) a1[idx / 384][idx % 384] = Aanch[b * 6144 + idx];
  __syncthreads();
  for (int o = tid; o < 16 * 192; o += 256) {
    int m = o / 192, cc = o % 192;
    float acc = 0.f;
    for (int k = 0; k < 384; k++) acc += a1[m][k] * Wmat[(size_t)k * wstride + cs + cc];
    out[((size_t)b * 16 + m) * wstride + cs + cc] = acc * scale;
  }
}

// ---------------------------------------------------------------------------
// Self attention on anchors (16x16, per (b,h)); anchors2 = anchors1 + out.
// ---------------------------------------------------------------------------
__global__ void self_attn(const float* __restrict__ qsf, const float* __restrict__ kvs,
                          const float* __restrict__ anch1, float* __restrict__ anch2) {
  int h = blockIdx.x & 7, b = blockIdx.x >> 3;
  __shared__ float qs[16][48], ks[16][48], vs[16][48], p[16][17];
  int tid = threadIdx.x;
  for (int idx = tid; idx < 768; idx += 256) {
    int m = idx / 48, d = idx % 48;
    qs[m][d] = qsf[(b * 16 + m) * 384 + h * 48 + d];
    ks[m][d] = kvs[(b * 16 + m) * 768 + h * 48 + d];
    vs[m][d] = kvs[(b * 16 + m) * 768 + 384 + h * 48 + d];
  }
  __syncthreads();
  {
    int mq = tid >> 4, mk = tid & 15;
    float acc = 0.f;
    for (int d = 0; d < 48; d++) acc += qs[mq][d] * ks[mk][d];
    p[mq][mk] = acc;
  }
  __syncthreads();
  if (tid < 16) {
    float mx = -1e30f;
    for (int mk = 0; mk < 16; mk++) mx = fmaxf(mx, p[tid][mk]);
    float sum = 0.f;
    for (int mk = 0; mk < 16; mk++) {
      float e = __expf(p[tid][mk] - mx);
      p[tid][mk] = e;
      sum += e;
    }
    float inv = 1.f / sum;
    for (int mk = 0; mk < 16; mk++) p[tid][mk] *= inv;
  }
  __syncthreads();
  for (int idx = tid; idx < 768; idx += 256) {
    int m = idx / 48, d = idx % 48;
    float acc = 0.f;
    for (int mk = 0; mk < 16; mk++) acc += p[m][mk] * vs[mk][d];
    int c = h * 48 + d;
    anch2[(b * 16 + m) * 384 + c] = anch1[(b * 16 + m) * 384 + c] + acc;
  }
}

// ---------------------------------------------------------------------------
// fill_wpb: W_pbT[b][hm][k] = sum_d w_q_bcast[k][h*48+d] * k_b[b][m][h*48+d].
// (SCALE already folded into kv_b's k half.)
// ---------------------------------------------------------------------------
__global__ void fill_wpb(const float* __restrict__ wq, const float* __restrict__ kvb,
                         __hip_bfloat16* __restrict__ wpbT) {
  int idx = blockIdx.x * 256 + threadIdx.x;  // 16*128*384 = 786432
  int b = idx / 49152;
  int rem = idx - b * 49152;
  int hm = rem / 384, k = rem - hm * 384;
  int h = hm >> 4, m = hm & 15;
  const float* kp = kvb + ((size_t)(b * 16 + m)) * 768 + h * 48;
  const float* wp = wq + (size_t)k * 384 + h * 48;
  float acc = 0.f;
#pragma unroll
  for (int d = 0; d < 48; d++) acc += wp[d] * kp[d];
  wpbT[idx] = __float2bfloat16(acc);
}

// ---------------------------------------------------------------------------
// fill_bt2: BT2[b][cp][k2]:  k2<384 -> w_proj[k2][cp]
//                            k2>=384 -> sum_d v_b[b][m][h*48+d]*w_proj[h*48+d][cp]
// ---------------------------------------------------------------------------
__global__ void fill_bt2(const float* __restrict__ wproj, const float* __restrict__ kvb,
                         __hip_bfloat16* __restrict__ bt2) {
  int idx = blockIdx.x * 256 + threadIdx.x;  // 16*384*512 = 3145728
  int b = idx / 196608;
  int rem = idx - b * 196608;
  int cp = rem / 512, k2 = rem - cp * 512;
  float v;
  if (k2 < 384) {
    v = wproj[(size_t)k2 * 384 + cp];
  } else {
    int hm = k2 - 384, h = hm >> 4, m = hm & 15;
    const float* vp = kvb + ((size_t)(b * 16 + m)) * 768 + 384 + h * 48;
    const float* wp2 = wproj + (size_t)(h * 48) * 384 + cp;
    v = 0.f;
#pragma unroll
    for (int d = 0; d < 48; d++) v += vp[d] * wp2[(size_t)d * 384];
  }
  bt2[idx] = __float2bfloat16(v);
}

// ---------------------------------------------------------------------------
// dwconv2: depthwise 3x3 conv, no LDS/no syncs. Writes A2[:,0:384] (stride 512).
// Lane owns 6 contiguous channels; wave = one position per iteration.
// Grid (128, 16): 4 waves x 8 positions.
// ---------------------------------------------------------------------------
__global__ __launch_bounds__(256) void dwconv2(const __hip_bfloat16* __restrict__ xb,
                                               const float* __restrict__ dwk,
                                               __hip_bfloat16* __restrict__ A2) {
  int b = blockIdx.y;
  int wv = threadIdx.x >> 6, lane = threadIdx.x & 63;
  int c0 = lane * 6;
  float kw[6][9];
#pragma unroll
  for (int i = 0; i < 6; i++)
#pragma unroll
    for (int ki = 0; ki < 9; ki++) kw[i][ki] = dwk[(c0 + i) * 9 + ki];
  for (int it = 0; it < 8; it++) {
    int p = blockIdx.x * 32 + wv * 8 + it;
    int y = p >> 6, w = p & 63;
    size_t prow = (size_t)b * 4096 + p;
    float acc[6] = {};
#pragma unroll
    for (int dy = -1; dy <= 1; dy++) {
      int yy = y + dy;
      if (yy < 0 || yy >= 64) continue;  // wave-uniform
#pragma unroll
      for (int dx = -1; dx <= 1; dx++) {
        int ww = w + dx;
        if (ww < 0 || ww >= 64) continue;
        int ki = (dy + 1) * 3 + (dx + 1);
        const __hip_bfloat16* xp = xb + ((size_t)(b * 4096 + yy * 64 + ww)) * 384 + c0;
#pragma unroll
        for (int i = 0; i < 6; i++) acc[i] += __bfloat162float(xp[i]) * kw[i][ki];
      }
    }
    __hip_bfloat16 tb[6];
#pragma unroll
    for (int i = 0; i < 6; i++) tb[i] = __float2bfloat16(acc[i]);
    __hip_bfloat16* gp = A2 + prow * 512 + c0;
    *(unsigned int*)(gp) = *(unsigned int*)(tb);
    *(unsigned int*)(gp + 2) = *(unsigned int*)(tb + 2);
    *(unsigned int*)(gp + 4) = *(unsigned int*)(tb + 4);
  }
}

// ---------------------------------------------------------------------------
extern "C" void kernel_launch(void* const* d_in, const int* in_sizes, int n_in,
                              void* d_out, int out_size, void* d_ws, size_t ws_size,
                              hipStream_t stream) {
  (void)in_sizes; (void)n_in; (void)out_size; (void)ws_size;
  const float* x = (const float*)d_in[0];
  const float* wsal = (const float*)d_in[3];
  const float* bsal = (const float*)d_in[4];
  const float* seeds = (const float*)d_in[5];
  const float* w_q_agg = (const float*)d_in[6];
  const float* w_kv_agg = (const float*)d_in[7];
  const float* w_q_self = (const float*)d_in[8];
  const float* w_kv_self = (const float*)d_in[9];
  const float* w_q_bcast = (const float*)d_in[10];
  const float* w_kv_bcast = (const float*)d_in[11];
  const float* dwk = (const float*)d_in[12];
  const float* w_proj = (const float*)d_in[13];
  float* out = (float*)d_out;

  char* ws = (char*)d_ws;
  size_t off = 0;
  auto take = [&](size_t bytes) -> void* {
    void* p = ws + off;
    off += (bytes + 255) & ~(size_t)255;
    return p;
  };
  __hip_bfloat16* xb = (__hip_bfloat16*)take(50331648);  // bf16(x)
  __hip_bfloat16* kv = (__hip_bfloat16*)take(100663296); // kv; later A2 [65536][512] bf16
  float* qseed = (float*)take(24576);
  float* pOut = (float*)take(6291456);
  float* pM = (float*)take(131072);
  float* pL = (float*)take(131072);
  float* anch1 = (float*)take(393216);
  float* anch2 = (float*)take(393216);
  float* q_self = (float*)take(393216);
  float* kv_self = (float*)take(786432);
  float* kv_b = (float*)take(786432);
  __hip_bfloat16* wkvT = (__hip_bfloat16*)take(589824);   // [768][384] bf16
  __hip_bfloat16* wpbT = (__hip_bfloat16*)take(1572864);  // [16][128][384] bf16
  __hip_bfloat16* bt2 = (__hip_bfloat16*)take(6291456);   // [16][384][512] bf16
  float* sal = pOut;                 // alias: sal dead before pOut written
  __hip_bfloat16* A2 = kv;           // alias: kv dead after agg_attn (64 MB of 96)

  // 0) weight prep (tiny)
  wcast_t<<<1152, 256, 0, stream>>>(w_kv_agg, wkvT, 384, 768);
  // 1) xb + saliency
  prep<<<16384, 256, 0, stream>>>(x, wsal, bsal, xb, sal);
  // 2) kv = diag(sal) * (xb @ w_kv_agg)   [65536x768] bf16 MFMA
  gemm_mfma<384, __hip_bfloat16, true><<<dim3(6, 512), 256, 0, stream>>>(xb, wkvT, kv, 768, sal, 0);
  // 3) agg attention -> anchors1
  qseed_k<<<24, 256, 0, stream>>>(seeds, w_q_agg, qseed);
  agg_attn_partial<<<dim3(16, 8, 16), 256, 0, stream>>>(qseed, kv, pOut, pM, pL);
  agg_combine<<<128, 256, 0, stream>>>(pOut, pM, pL, seeds, anch1);
  // 4) anchor self-attention -> anchors2
  anchor_proj<<<dim3(2, 16), 256, 0, stream>>>(anch1, w_q_self, q_self, 384, 0, SCALE);
  anchor_proj<<<dim3(4, 16), 256, 0, stream>>>(anch1, w_kv_self, kv_self, 768, 0, 1.f);
  self_attn<<<128, 256, 0, stream>>>(q_self, kv_self, anch1, anch2);
  // 5) kv_bcast = anchors2 @ w_kv_bcast (SCALE folded into k half)
  anchor_proj<<<dim3(2, 16), 256, 0, stream>>>(anch2, w_kv_bcast, kv_b, 768, 0, SCALE);
  anchor_proj<<<dim3(2, 16), 256, 0, stream>>>(anch2, w_kv_bcast, kv_b, 768, 384, 1.f);
  // 6) per-batch folded weights: W_pb = w_q_bcast @ Kblk_b ; BT2 = [w_projT | Wv'_bT]
  fill_wpb<<<3072, 256, 0, stream>>>(w_q_bcast, kv_b, wpbT);
  fill_bt2<<<12288, 256, 0, stream>>>(w_proj, kv_b, bt2);
  // 7) A2[:,0:384] = dwconv(xb)   (kv region dead -> A2)
  dwconv2<<<dim3(128, 16), 256, 0, stream>>>(xb, dwk, A2);
  // 8) A2[:,384:512] = P = softmax(xb @ W_pbT_b)
  pgemm<<<dim3(1, 512), 256, 0, stream>>>(xb, wpbT, A2);
  // 9) out = A2 @ BT2_b   (K=512, f32 out)
  gemm_mfma<512, float, false><<<dim3(3, 512), 256, 0, stream>>>(A2, bt2, out, 384, nullptr, (size_t)384 * 512);
}

// Round 6
// 493.425 us; speedup vs baseline: 4.6060x; 1.9108x over previous
//
#include <hip/hip_runtime.h>
#include <hip/hip_bf16.h>

// Problem constants: B=16, N=4096, C=384, M=16, NH=8, HD=48, H=W=64
#define SCALE 0.14433756729740643f  // 48^-0.5

typedef __attribute__((ext_vector_type(8))) short bf16x8;
typedef __attribute__((ext_vector_type(4))) float f32x4;

__device__ inline float b2f(short s) {
  union { unsigned int u; float f; } c;
  c.u = ((unsigned int)(unsigned short)s) << 16;
  return c.f;
}

template <typename T> __device__ inline T cvt_from_f(float v);
template <> __device__ inline float cvt_from_f<float>(float v) { return v; }
template <> __device__ inline __hip_bfloat16 cvt_from_f<__hip_bfloat16>(float v) { return __float2bfloat16(v); }

__device__ inline void gload16(const void* g, void* l) {
  __builtin_amdgcn_global_load_lds((const __attribute__((address_space(1))) void*)g,
                                   (__attribute__((address_space(3))) void*)l, 16, 0, 0);
}

// ---------------------------------------------------------------------------
// prep: xb = bf16(x); sal[row] = sigmoid(x·wsal + b). One wave per row.
// ---------------------------------------------------------------------------
__global__ __launch_bounds__(256) void prep(const float* __restrict__ x,
                                            const float* __restrict__ wsal,
                                            const float* __restrict__ bsal,
                                            __hip_bfloat16* __restrict__ xb,
                                            float* __restrict__ sal) {
  int wave = threadIdx.x >> 6, lane = threadIdx.x & 63;
  size_t row = (size_t)blockIdx.x * 4 + wave;
  const float* xr = x + row * 384;
  float xs[6];
  float part = 0.f;
#pragma unroll
  for (int j = 0; j < 6; j++) {
    int c = lane + 64 * j;
    xs[j] = xr[c];
    part += xs[j] * wsal[c];
  }
#pragma unroll
  for (int off = 32; off >= 1; off >>= 1) part += __shfl_xor(part, off);
  float s = 1.f / (1.f + __expf(-(part + bsal[0])));
#pragma unroll
  for (int j = 0; j < 6; j++) {
    int c = lane + 64 * j;
    xb[row * 384 + c] = __float2bfloat16(xs[j]);
  }
  if (lane == 0) sal[row] = s;
}

// ---------------------------------------------------------------------------
// Weight cast+transpose: wt[n*K+k] = bf16(w[k*N+n]).
// ---------------------------------------------------------------------------
__global__ void wcast_t(const float* __restrict__ w, __hip_bfloat16* __restrict__ wt,
                        int K, int N) {
  int idx = blockIdx.x * 256 + threadIdx.x;
  if (idx >= K * N) return;
  int n = idx / K, k = idx % K;
  wt[idx] = __float2bfloat16(w[(size_t)k * N + n]);
}

// ---------------------------------------------------------------------------
// MFMA GEMM: out[M,Ncols] = A[M,K](bf16) @ BT[Ncols,K]^T, optional row scale,
// optional per-batch BT (batch = rowBase/4096). 128x128 tile, BK=32, 4 waves.
// ---------------------------------------------------------------------------
template <int K, typename OT, bool RS>
__global__ __launch_bounds__(256) void gemm_mfma(const __hip_bfloat16* __restrict__ A,
                                                 const __hip_bfloat16* __restrict__ BT,
                                                 OT* __restrict__ out, int Ncols,
                                                 const float* __restrict__ rowScale,
                                                 size_t btBatchStride) {
  __shared__ __align__(16) __hip_bfloat16 Asl[128][32];
  __shared__ __align__(16) __hip_bfloat16 Bsl[128][32];
  int tid = threadIdx.x;
  int lane = tid & 63;
  int w = tid >> 6;
  int wr = w >> 1, wc = w & 1;
  int fr = lane & 15, fq = lane >> 4;
  int rowBase = blockIdx.y * 128, colBase = blockIdx.x * 128;
  const __hip_bfloat16* BTb = BT + (size_t)(rowBase >> 12) * btBatchStride;

  int r1 = tid >> 2, kc1 = tid & 3;
  int r2 = (tid + 256) >> 2;

  char* aB1 = (char*)Asl + (size_t)(w * 64) * 16;
  char* aB2 = (char*)Asl + (size_t)(256 + w * 64) * 16;
  char* bB1 = (char*)Bsl + (size_t)(w * 64) * 16;
  char* bB2 = (char*)Bsl + (size_t)(256 + w * 64) * 16;

  const __hip_bfloat16* a1 = A + (size_t)(rowBase + r1) * K + kc1 * 8;
  const __hip_bfloat16* a2 = A + (size_t)(rowBase + r2) * K + kc1 * 8;
  const __hip_bfloat16* b1 = BTb + (size_t)(colBase + r1) * K + kc1 * 8;
  const __hip_bfloat16* b2 = BTb + (size_t)(colBase + r2) * K + kc1 * 8;

  f32x4 acc[4][4] = {};

  for (int kk = 0; kk < K; kk += 32) {
    gload16(a1 + kk, aB1);
    gload16(a2 + kk, aB2);
    gload16(b1 + kk, bB1);
    gload16(b2 + kk, bB2);
    __syncthreads();
    bf16x8 af[4], bfv[4];
#pragma unroll
    for (int m = 0; m < 4; m++) af[m] = *(const bf16x8*)&Asl[wr * 64 + m * 16 + fr][fq * 8];
#pragma unroll
    for (int n = 0; n < 4; n++) bfv[n] = *(const bf16x8*)&Bsl[wc * 64 + n * 16 + fr][fq * 8];
#pragma unroll
    for (int m = 0; m < 4; m++)
#pragma unroll
      for (int n = 0; n < 4; n++)
        acc[m][n] = __builtin_amdgcn_mfma_f32_16x16x32_bf16(af[m], bfv[n], acc[m][n], 0, 0, 0);
    __syncthreads();
  }

  if constexpr (RS) {
    float sv[4][4];
#pragma unroll
    for (int m = 0; m < 4; m++)
#pragma unroll
      for (int r = 0; r < 4; r++)
        sv[m][r] = rowScale[rowBase + wr * 64 + m * 16 + fq * 4 + r];
#pragma unroll
    for (int m = 0; m < 4; m++)
#pragma unroll
      for (int n = 0; n < 4; n++)
#pragma unroll
        for (int r = 0; r < 4; r++) acc[m][n][r] *= sv[m][r];
  }

#pragma unroll
  for (int m = 0; m < 4; m++) {
    int row0 = rowBase + wr * 64 + m * 16 + fq * 4;
#pragma unroll
    for (int n = 0; n < 4; n++) {
      int col = colBase + wc * 64 + n * 16 + fr;
      f32x4 v = acc[m][n];
#pragma unroll
      for (int r = 0; r < 4; r++) out[(size_t)(row0 + r) * Ncols + col] = cvt_from_f<OT>(v[r]);
    }
  }
}

// ---------------------------------------------------------------------------
// pgemm: P = softmax_per_head(xb @ W_pbT_b^T), written bf16 to A2[:,384+hm].
// N=128 (all heads in one tile); softmax across the 16-lane fr group.
// Grid: (1, 512).
// ---------------------------------------------------------------------------
__global__ __launch_bounds__(256) void pgemm(const __hip_bfloat16* __restrict__ A,
                                             const __hip_bfloat16* __restrict__ wpbT,
                                             __hip_bfloat16* __restrict__ A2) {
  constexpr int K = 384;
  __shared__ __align__(16) __hip_bfloat16 Asl[128][32];
  __shared__ __align__(16) __hip_bfloat16 Bsl[128][32];
  int tid = threadIdx.x;
  int lane = tid & 63;
  int w = tid >> 6;
  int wr = w >> 1, wc = w & 1;
  int fr = lane & 15, fq = lane >> 4;
  int rowBase = blockIdx.y * 128;
  const __hip_bfloat16* BTb = wpbT + (size_t)(rowBase >> 12) * (128 * 384);

  int r1 = tid >> 2, kc1 = tid & 3;
  int r2 = (tid + 256) >> 2;

  char* aB1 = (char*)Asl + (size_t)(w * 64) * 16;
  char* aB2 = (char*)Asl + (size_t)(256 + w * 64) * 16;
  char* bB1 = (char*)Bsl + (size_t)(w * 64) * 16;
  char* bB2 = (char*)Bsl + (size_t)(256 + w * 64) * 16;

  const __hip_bfloat16* a1 = A + (size_t)(rowBase + r1) * K + kc1 * 8;
  const __hip_bfloat16* a2 = A + (size_t)(rowBase + r2) * K + kc1 * 8;
  const __hip_bfloat16* b1 = BTb + (size_t)r1 * K + kc1 * 8;
  const __hip_bfloat16* b2 = BTb + (size_t)r2 * K + kc1 * 8;

  f32x4 acc[4][4] = {};

  for (int kk = 0; kk < K; kk += 32) {
    gload16(a1 + kk, aB1);
    gload16(a2 + kk, aB2);
    gload16(b1 + kk, bB1);
    gload16(b2 + kk, bB2);
    __syncthreads();
    bf16x8 af[4], bfv[4];
#pragma unroll
    for (int m = 0; m < 4; m++) af[m] = *(const bf16x8*)&Asl[wr * 64 + m * 16 + fr][fq * 8];
#pragma unroll
    for (int n = 0; n < 4; n++) bfv[n] = *(const bf16x8*)&Bsl[wc * 64 + n * 16 + fr][fq * 8];
#pragma unroll
    for (int m = 0; m < 4; m++)
#pragma unroll
      for (int n = 0; n < 4; n++)
        acc[m][n] = __builtin_amdgcn_mfma_f32_16x16x32_bf16(af[m], bfv[n], acc[m][n], 0, 0, 0);
    __syncthreads();
  }

  // epilogue: per (row, head) softmax over the 16-lane fr group.
#pragma unroll
  for (int m = 0; m < 4; m++) {
    int row0 = rowBase + wr * 64 + m * 16 + fq * 4;
#pragma unroll
    for (int n = 0; n < 4; n++) {
      int col = wc * 64 + n * 16 + fr;
      f32x4 v = acc[m][n];
      f32x4 mx = v;
#pragma unroll
      for (int off = 1; off < 16; off <<= 1)
#pragma unroll
        for (int r = 0; r < 4; r++) mx[r] = fmaxf(mx[r], __shfl_xor(mx[r], off));
      f32x4 e;
#pragma unroll
      for (int r = 0; r < 4; r++) e[r] = __expf(v[r] - mx[r]);
      f32x4 s = e;
#pragma unroll
      for (int off = 1; off < 16; off <<= 1)
#pragma unroll
        for (int r = 0; r < 4; r++) s[r] += __shfl_xor(s[r], off);
#pragma unroll
      for (int r = 0; r < 4; r++)
        A2[(size_t)(row0 + r) * 512 + 384 + col] = __float2bfloat16(e[r] / s[r]);
    }
  }
}

// ---------------------------------------------------------------------------
// Agg attention partials: block = (s, h, b); keys [s*256, s*256+256).
// ---------------------------------------------------------------------------
__global__ __launch_bounds__(256) void agg_attn_partial(
    const float* __restrict__ qseed, const __hip_bfloat16* __restrict__ kv,
    float* __restrict__ pOut, float* __restrict__ pM, float* __restrict__ pL) {
  int s = blockIdx.x, h = blockIdx.y, b = blockIdx.z;
  __shared__ float qs[16][48];
  __shared__ float kt[64][49];
  __shared__ float vt[64][49];
  __shared__ float lg[16][65];
  __shared__ float outb[16][48];
  __shared__ float mrow[16], lrow[16], rrow[16];
  int tid = threadIdx.x;
  for (int idx = tid; idx < 16 * 48; idx += 256)
    qs[idx / 48][idx % 48] = qseed[(idx / 48) * 384 + h * 48 + idx % 48];
  for (int idx = tid; idx < 16 * 48; idx += 256) outb[idx / 48][idx % 48] = 0.f;
  if (tid < 16) {
    mrow[tid] = -1e30f;
    lrow[tid] = 0.f;
  }
  __syncthreads();
  int k0 = s * 256;
  for (int t = 0; t < 4; t++) {
    int kb = k0 + t * 64;
#pragma unroll
    for (int i = 0; i < 3; i++) {
      int idx = tid + i * 256;
      int mat = idx / 384;
      int id2 = idx - mat * 384;
      int r = id2 / 6, oc = id2 - r * 6;
      bf16x8 v = *(const bf16x8*)(kv + ((size_t)(b * 4096 + kb + r)) * 768 + mat * 384 + h * 48 + oc * 8);
      float* dst = mat ? &vt[r][oc * 8] : &kt[r][oc * 8];
#pragma unroll
      for (int j = 0; j < 8; j++) dst[j] = b2f(v[j]);
    }
    __syncthreads();
    for (int idx = tid; idx < 16 * 64; idx += 256) {
      int m = idx >> 6, kkk = idx & 63;
      float acc = 0.f;
      for (int d = 0; d < 48; d++) acc += qs[m][d] * kt[kkk][d];
      lg[m][kkk] = acc;
    }
    __syncthreads();
    if (tid < 64) {
      int m = tid >> 2, q = tid & 3;
      float mx = mrow[m];
      for (int i = 0; i < 16; i++) mx = fmaxf(mx, lg[m][q * 16 + i]);
      mx = fmaxf(mx, __shfl_xor(mx, 1));
      mx = fmaxf(mx, __shfl_xor(mx, 2));
      float r = __expf(mrow[m] - mx);
      float sum = 0.f;
      for (int i = 0; i < 16; i++) {
        float e = __expf(lg[m][q * 16 + i] - mx);
        lg[m][q * 16 + i] = e;
        sum += e;
      }
      sum += __shfl_xor(sum, 1);
      sum += __shfl_xor(sum, 2);
      if (q == 0) {
        rrow[m] = r;
        lrow[m] = lrow[m] * r + sum;
        mrow[m] = mx;
      }
    }
    __syncthreads();
    for (int idx = tid; idx < 16 * 48; idx += 256) {
      int m = idx / 48, d = idx % 48;
      float acc = outb[m][d] * rrow[m];
      for (int kkk = 0; kkk < 64; kkk++) acc += lg[m][kkk] * vt[kkk][d];
      outb[m][d] = acc;
    }
    __syncthreads();
  }
  int g = (b * 8 + h) * 16 + s;
  for (int idx = tid; idx < 16 * 48; idx += 256) pOut[(size_t)g * 768 + idx] = outb[idx / 48][idx % 48];
  if (tid < 16) {
    pM[g * 16 + tid] = mrow[tid];
    pL[g * 16 + tid] = lrow[tid];
  }
}

// ---------------------------------------------------------------------------
// Combine agg partials -> anchors1 = seeds + attn_out.
// ---------------------------------------------------------------------------
__global__ void agg_combine(const float* __restrict__ pOut, const float* __restrict__ pM,
                            const float* __restrict__ pL, const float* __restrict__ seeds,
                            float* __restrict__ anch1) {
  int h = blockIdx.x & 7, b = blockIdx.x >> 3;
  int g = b * 8 + h;
  __shared__ float gm[16], glsum[16];
  int tid = threadIdx.x;
  if (tid < 16) {
    int m = tid;
    float mx = -1e30f;
    for (int s = 0; s < 16; s++) mx = fmaxf(mx, pM[(g * 16 + s) * 16 + m]);
    float l = 0.f;
    for (int s = 0; s < 16; s++) l += pL[(g * 16 + s) * 16 + m] * __expf(pM[(g * 16 + s) * 16 + m] - mx);
    gm[m] = mx;
    glsum[m] = l;
  }
  __syncthreads();
  for (int idx = tid; idx < 768; idx += 256) {
    int m = idx / 48, d = idx % 48;
    float acc = 0.f;
    for (int s = 0; s < 16; s++) {
      int p = g * 16 + s;
      acc += pOut[(size_t)p * 768 + idx] * __expf(pM[p * 16 + m] - gm[m]);
    }
    float o = acc / glsum[m];
    int c = h * 48 + d;
    anch1[(b * 16 + m) * 384 + c] = seeds[m * 384 + c] + o;
  }
}

// ---------------------------------------------------------------------------
// anchor_proj2: out[b,16,wstride] = A[b,16,384] @ W[384,wstride], scaled by
// SCALE on cols < scaleCols. Block = 16m x 16col tile; grid (wstride/16, B).
// A staged in padded LDS; k-loop split into 4 independent accumulators.
// ---------------------------------------------------------------------------
__global__ __launch_bounds__(256) void anchor_proj2(const float* __restrict__ A,
                                                    const float* __restrict__ W,
                                                    float* __restrict__ out, int wstride,
                                                    int scaleCols) {
  int cs = blockIdx.x * 16;
  int b = blockIdx.y;
  __shared__ float a1[16][385];
  int tid = threadIdx.x;
  for (int idx = tid; idx < 6144; idx += 256) a1[idx / 384][idx % 384] = A[b * 6144 + idx];
  __syncthreads();
  int m = tid >> 4, cc = tid & 15;
  int col = cs + cc;
  const float* wp = W + col;
  float acc0 = 0.f, acc1 = 0.f, acc2 = 0.f, acc3 = 0.f;
#pragma unroll 4
  for (int k = 0; k < 384; k += 4) {
    acc0 += a1[m][k] * wp[(size_t)k * wstride];
    acc1 += a1[m][k + 1] * wp[(size_t)(k + 1) * wstride];
    acc2 += a1[m][k + 2] * wp[(size_t)(k + 2) * wstride];
    acc3 += a1[m][k + 3] * wp[(size_t)(k + 3) * wstride];
  }
  float acc = (acc0 + acc1) + (acc2 + acc3);
  if (col < scaleCols) acc *= SCALE;
  out[((size_t)b * 16 + m) * wstride + col] = acc;
}

// ---------------------------------------------------------------------------
// Self attention on anchors (16x16, per (b,h)); anchors2 = anchors1 + out.
// ---------------------------------------------------------------------------
__global__ void self_attn(const float* __restrict__ qsf, const float* __restrict__ kvs,
                          const float* __restrict__ anch1, float* __restrict__ anch2) {
  int h = blockIdx.x & 7, b = blockIdx.x >> 3;
  __shared__ float qs[16][48], ks[16][48], vs[16][48], p[16][17];
  int tid = threadIdx.x;
  for (int idx = tid; idx < 768; idx += 256) {
    int m = idx / 48, d = idx % 48;
    qs[m][d] = qsf[(b * 16 + m) * 384 + h * 48 + d];
    ks[m][d] = kvs[(b * 16 + m) * 768 + h * 48 + d];
    vs[m][d] = kvs[(b * 16 + m) * 768 + 384 + h * 48 + d];
  }
  __syncthreads();
  {
    int mq = tid >> 4, mk = tid & 15;
    float acc = 0.f;
    for (int d = 0; d < 48; d++) acc += qs[mq][d] * ks[mk][d];
    p[mq][mk] = acc;
  }
  __syncthreads();
  if (tid < 16) {
    float mx = -1e30f;
    for (int mk = 0; mk < 16; mk++) mx = fmaxf(mx, p[tid][mk]);
    float sum = 0.f;
    for (int mk = 0; mk < 16; mk++) {
      float e = __expf(p[tid][mk] - mx);
      p[tid][mk] = e;
      sum += e;
    }
    float inv = 1.f / sum;
    for (int mk = 0; mk < 16; mk++) p[tid][mk] *= inv;
  }
  __syncthreads();
  for (int idx = tid; idx < 768; idx += 256) {
    int m = idx / 48, d = idx % 48;
    float acc = 0.f;
    for (int mk = 0; mk < 16; mk++) acc += p[m][mk] * vs[mk][d];
    int c = h * 48 + d;
    anch2[(b * 16 + m) * 384 + c] = anch1[(b * 16 + m) * 384 + c] + acc;
  }
}

// ---------------------------------------------------------------------------
// fill_wpb: W_pbT[b][hm][k] = sum_d w_q_bcast[k][h*48+d] * k_b[b][m][h*48+d].
// ---------------------------------------------------------------------------
__global__ void fill_wpb(const float* __restrict__ wq, const float* __restrict__ kvb,
                         __hip_bfloat16* __restrict__ wpbT) {
  int idx = blockIdx.x * 256 + threadIdx.x;  // 16*128*384 = 786432
  int b = idx / 49152;
  int rem = idx - b * 49152;
  int hm = rem / 384, k = rem - hm * 384;
  int h = hm >> 4, m = hm & 15;
  const float* kp = kvb + ((size_t)(b * 16 + m)) * 768 + h * 48;
  const float* wp = wq + (size_t)k * 384 + h * 48;
  float acc = 0.f;
#pragma unroll
  for (int d = 0; d < 48; d++) acc += wp[d] * kp[d];
  wpbT[idx] = __float2bfloat16(acc);
}

// ---------------------------------------------------------------------------
// fill_bt2: BT2[b][cp][k2]:  k2<384 -> w_proj[k2][cp]
//                            k2>=384 -> sum_d v_b[b][m][h*48+d]*w_proj[h*48+d][cp]
// ---------------------------------------------------------------------------
__global__ void fill_bt2(const float* __restrict__ wproj, const float* __restrict__ kvb,
                         __hip_bfloat16* __restrict__ bt2) {
  int idx = blockIdx.x * 256 + threadIdx.x;  // 16*384*512 = 3145728
  int b = idx / 196608;
  int rem = idx - b * 196608;
  int cp = rem / 512, k2 = rem - cp * 512;
  float v;
  if (k2 < 384) {
    v = wproj[(size_t)k2 * 384 + cp];
  } else {
    int hm = k2 - 384, h = hm >> 4, m = hm & 15;
    const float* vp = kvb + ((size_t)(b * 16 + m)) * 768 + 384 + h * 48;
    const float* wp2 = wproj + (size_t)(h * 48) * 384 + cp;
    v = 0.f;
#pragma unroll
    for (int d = 0; d < 48; d++) v += vp[d] * wp2[(size_t)d * 384];
  }
  bt2[idx] = __float2bfloat16(v);
}

// ---------------------------------------------------------------------------
// dwconv2: depthwise 3x3 conv, no LDS/no syncs. Writes A2[:,0:384] (stride 512).
// ---------------------------------------------------------------------------
__global__ __launch_bounds__(256) void dwconv2(const __hip_bfloat16* __restrict__ xb,
                                               const float* __restrict__ dwk,
                                               __hip_bfloat16* __restrict__ A2) {
  int b = blockIdx.y;
  int wv = threadIdx.x >> 6, lane = threadIdx.x & 63;
  int c0 = lane * 6;
  float kw[6][9];
#pragma unroll
  for (int i = 0; i < 6; i++)
#pragma unroll
    for (int ki = 0; ki < 9; ki++) kw[i][ki] = dwk[(c0 + i) * 9 + ki];
  for (int it = 0; it < 8; it++) {
    int p = blockIdx.x * 32 + wv * 8 + it;
    int y = p >> 6, w = p & 63;
    size_t prow = (size_t)b * 4096 + p;
    float acc[6] = {};
#pragma unroll
    for (int dy = -1; dy <= 1; dy++) {
      int yy = y + dy;
      if (yy < 0 || yy >= 64) continue;  // wave-uniform
#pragma unroll
      for (int dx = -1; dx <= 1; dx++) {
        int ww = w + dx;
        if (ww < 0 || ww >= 64) continue;
        int ki = (dy + 1) * 3 + (dx + 1);
        const __hip_bfloat16* xp = xb + ((size_t)(b * 4096 + yy * 64 + ww)) * 384 + c0;
#pragma unroll
        for (int i = 0; i < 6; i++) acc[i] += __bfloat162float(xp[i]) * kw[i][ki];
      }
    }
    __hip_bfloat16 tb[6];
#pragma unroll
    for (int i = 0; i < 6; i++) tb[i] = __float2bfloat16(acc[i]);
    __hip_bfloat16* gp = A2 + prow * 512 + c0;
    *(unsigned int*)(gp) = *(unsigned int*)(tb);
    *(unsigned int*)(gp + 2) = *(unsigned int*)(tb + 2);
    *(unsigned int*)(gp + 4) = *(unsigned int*)(tb + 4);
  }
}

// ---------------------------------------------------------------------------
extern "C" void kernel_launch(void* const* d_in, const int* in_sizes, int n_in,
                              void* d_out, int out_size, void* d_ws, size_t ws_size,
                              hipStream_t stream) {
  (void)in_sizes; (void)n_in; (void)out_size; (void)ws_size;
  const float* x = (const float*)d_in[0];
  const float* wsal = (const float*)d_in[3];
  const float* bsal = (const float*)d_in[4];
  const float* seeds = (const float*)d_in[5];
  const float* w_q_agg = (const float*)d_in[6];
  const float* w_kv_agg = (const float*)d_in[7];
  const float* w_q_self = (const float*)d_in[8];
  const float* w_kv_self = (const float*)d_in[9];
  const float* w_q_bcast = (const float*)d_in[10];
  const float* w_kv_bcast = (const float*)d_in[11];
  const float* dwk = (const float*)d_in[12];
  const float* w_proj = (const float*)d_in[13];
  float* out = (float*)d_out;

  char* ws = (char*)d_ws;
  size_t off = 0;
  auto take = [&](size_t bytes) -> void* {
    void* p = ws + off;
    off += (bytes + 255) & ~(size_t)255;
    return p;
  };
  __hip_bfloat16* xb = (__hip_bfloat16*)take(50331648);  // bf16(x)
  __hip_bfloat16* kv = (__hip_bfloat16*)take(100663296); // kv; later A2 [65536][512] bf16
  float* qseed = (float*)take(24576);
  float* pOut = (float*)take(6291456);
  float* pM = (float*)take(131072);
  float* pL = (float*)take(131072);
  float* anch1 = (float*)take(393216);
  float* anch2 = (float*)take(393216);
  float* q_self = (float*)take(393216);
  float* kv_self = (float*)take(786432);
  float* kv_b = (float*)take(786432);
  __hip_bfloat16* wkvT = (__hip_bfloat16*)take(589824);   // [768][384] bf16
  __hip_bfloat16* wpbT = (__hip_bfloat16*)take(1572864);  // [16][128][384] bf16
  __hip_bfloat16* bt2 = (__hip_bfloat16*)take(6291456);   // [16][384][512] bf16
  float* sal = pOut;                 // alias: sal dead before pOut written
  __hip_bfloat16* A2 = kv;           // alias: kv dead after agg_attn (64 MB of 96)

  // 0) weight prep (tiny)
  wcast_t<<<1152, 256, 0, stream>>>(w_kv_agg, wkvT, 384, 768);
  // 1) xb + saliency
  prep<<<16384, 256, 0, stream>>>(x, wsal, bsal, xb, sal);
  // 2) kv = diag(sal) * (xb @ w_kv_agg)   [65536x768] bf16 MFMA
  gemm_mfma<384, __hip_bfloat16, true><<<dim3(6, 512), 256, 0, stream>>>(xb, wkvT, kv, 768, sal, 0);
  // 3) agg attention -> anchors1
  anchor_proj2<<<dim3(24, 1), 256, 0, stream>>>(seeds, w_q_agg, qseed, 384, 384);
  agg_attn_partial<<<dim3(16, 8, 16), 256, 0, stream>>>(qseed, kv, pOut, pM, pL);
  agg_combine<<<128, 256, 0, stream>>>(pOut, pM, pL, seeds, anch1);
  // 4) anchor self-attention -> anchors2
  anchor_proj2<<<dim3(24, 16), 256, 0, stream>>>(anch1, w_q_self, q_self, 384, 384);
  anchor_proj2<<<dim3(48, 16), 256, 0, stream>>>(anch1, w_kv_self, kv_self, 768, 0);
  self_attn<<<128, 256, 0, stream>>>(q_self, kv_self, anch1, anch2);
  // 5) kv_bcast = anchors2 @ w_kv_bcast (SCALE on k half, cols<384)
  anchor_proj2<<<dim3(48, 16), 256, 0, stream>>>(anch2, w_kv_bcast, kv_b, 768, 384);
  // 6) per-batch folded weights: W_pb = w_q_bcast @ Kblk_b ; BT2 = [w_projT | Wv'_bT]
  fill_wpb<<<3072, 256, 0, stream>>>(w_q_bcast, kv_b, wpbT);
  fill_bt2<<<12288, 256, 0, stream>>>(w_proj, kv_b, bt2);
  // 7) A2[:,0:384] = dwconv(xb)   (kv region dead -> A2)
  dwconv2<<<dim3(128, 16), 256, 0, stream>>>(xb, dwk, A2);
  // 8) A2[:,384:512] = P = softmax(xb @ W_pbT_b)
  pgemm<<<dim3(1, 512), 256, 0, stream>>>(xb, wpbT, A2);
  // 9) out = A2 @ BT2_b   (K=512, f32 out)
  gemm_mfma<512, float, false><<<dim3(3, 512), 256, 0, stream>>>(A2, bt2, out, 384, nullptr, (size_t)384 * 512);
}

// Round 7
// 479.098 us; speedup vs baseline: 4.7438x; 1.0299x over previous
//
#include <hip/hip_runtime.h>
#include <hip/hip_bf16.h>

// Problem constants: B=16, N=4096, C=384, M=16, NH=8, HD=48, H=W=64
#define SCALE 0.14433756729740643f  // 48^-0.5

typedef __attribute__((ext_vector_type(8))) short bf16x8;
typedef __attribute__((ext_vector_type(4))) float f32x4;

template <typename T> __device__ inline T cvt_from_f(float v);
template <> __device__ inline float cvt_from_f<float>(float v) { return v; }
template <> __device__ inline __hip_bfloat16 cvt_from_f<__hip_bfloat16>(float v) { return __float2bfloat16(v); }

__device__ inline void gload16(const void* g, void* l) {
  __builtin_amdgcn_global_load_lds((const __attribute__((address_space(1))) void*)g,
                                   (__attribute__((address_space(3))) void*)l, 16, 0, 0);
}

// ---------------------------------------------------------------------------
// prep: xb = bf16(x); sal[row] = sigmoid(x·wsal + b). One wave per row.
// ---------------------------------------------------------------------------
__global__ __launch_bounds__(256) void prep(const float* __restrict__ x,
                                            const float* __restrict__ wsal,
                                            const float* __restrict__ bsal,
                                            __hip_bfloat16* __restrict__ xb,
                                            float* __restrict__ sal) {
  int wave = threadIdx.x >> 6, lane = threadIdx.x & 63;
  size_t row = (size_t)blockIdx.x * 4 + wave;
  const float* xr = x + row * 384;
  float xs[6];
  float part = 0.f;
#pragma unroll
  for (int j = 0; j < 6; j++) {
    int c = lane + 64 * j;
    xs[j] = xr[c];
    part += xs[j] * wsal[c];
  }
#pragma unroll
  for (int off = 32; off >= 1; off >>= 1) part += __shfl_xor(part, off);
  float s = 1.f / (1.f + __expf(-(part + bsal[0])));
#pragma unroll
  for (int j = 0; j < 6; j++) {
    int c = lane + 64 * j;
    xb[row * 384 + c] = __float2bfloat16(xs[j]);
  }
  if (lane == 0) sal[row] = s;
}

// ---------------------------------------------------------------------------
// Weight cast+transpose: wt[n*K+k] = bf16(w[k*N+n]).
// ---------------------------------------------------------------------------
__global__ void wcast_t(const float* __restrict__ w, __hip_bfloat16* __restrict__ wt,
                        int K, int N) {
  int idx = blockIdx.x * 256 + threadIdx.x;
  if (idx >= K * N) return;
  int n = idx / K, k = idx % K;
  wt[idx] = __float2bfloat16(w[(size_t)k * N + n]);
}

// ---------------------------------------------------------------------------
// MFMA GEMM: out[M,Ncols] = A[M,K](bf16) @ BT[Ncols,K]^T, optional row scale,
// per-batch BT via batch = rowBase>>BSHIFT. 128x128 tile, BK=32, 4 waves.
// ---------------------------------------------------------------------------
template <int K, typename OT, bool RS, int BSHIFT>
__global__ __launch_bounds__(256) void gemm_mfma(const __hip_bfloat16* __restrict__ A,
                                                 const __hip_bfloat16* __restrict__ BT,
                                                 OT* __restrict__ out, int Ncols,
                                                 const float* __restrict__ rowScale,
                                                 size_t btBatchStride) {
  __shared__ __align__(16) __hip_bfloat16 Asl[128][32];
  __shared__ __align__(16) __hip_bfloat16 Bsl[128][32];
  int tid = threadIdx.x;
  int lane = tid & 63;
  int w = tid >> 6;
  int wr = w >> 1, wc = w & 1;
  int fr = lane & 15, fq = lane >> 4;
  int rowBase = blockIdx.y * 128, colBase = blockIdx.x * 128;
  const __hip_bfloat16* BTb = BT + (size_t)(rowBase >> BSHIFT) * btBatchStride;

  int r1 = tid >> 2, kc1 = tid & 3;
  int r2 = (tid + 256) >> 2;

  char* aB1 = (char*)Asl + (size_t)(w * 64) * 16;
  char* aB2 = (char*)Asl + (size_t)(256 + w * 64) * 16;
  char* bB1 = (char*)Bsl + (size_t)(w * 64) * 16;
  char* bB2 = (char*)Bsl + (size_t)(256 + w * 64) * 16;

  const __hip_bfloat16* a1 = A + (size_t)(rowBase + r1) * K + kc1 * 8;
  const __hip_bfloat16* a2 = A + (size_t)(rowBase + r2) * K + kc1 * 8;
  const __hip_bfloat16* b1 = BTb + (size_t)(colBase + r1) * K + kc1 * 8;
  const __hip_bfloat16* b2 = BTb + (size_t)(colBase + r2) * K + kc1 * 8;

  f32x4 acc[4][4] = {};

  for (int kk = 0; kk < K; kk += 32) {
    gload16(a1 + kk, aB1);
    gload16(a2 + kk, aB2);
    gload16(b1 + kk, bB1);
    gload16(b2 + kk, bB2);
    __syncthreads();
    bf16x8 af[4], bfv[4];
#pragma unroll
    for (int m = 0; m < 4; m++) af[m] = *(const bf16x8*)&Asl[wr * 64 + m * 16 + fr][fq * 8];
#pragma unroll
    for (int n = 0; n < 4; n++) bfv[n] = *(const bf16x8*)&Bsl[wc * 64 + n * 16 + fr][fq * 8];
#pragma unroll
    for (int m = 0; m < 4; m++)
#pragma unroll
      for (int n = 0; n < 4; n++)
        acc[m][n] = __builtin_amdgcn_mfma_f32_16x16x32_bf16(af[m], bfv[n], acc[m][n], 0, 0, 0);
    __syncthreads();
  }

  if constexpr (RS) {
    float sv[4][4];
#pragma unroll
    for (int m = 0; m < 4; m++)
#pragma unroll
      for (int r = 0; r < 4; r++)
        sv[m][r] = rowScale[rowBase + wr * 64 + m * 16 + fq * 4 + r];
#pragma unroll
    for (int m = 0; m < 4; m++)
#pragma unroll
      for (int n = 0; n < 4; n++)
#pragma unroll
        for (int r = 0; r < 4; r++) acc[m][n][r] *= sv[m][r];
  }

#pragma unroll
  for (int m = 0; m < 4; m++) {
    int row0 = rowBase + wr * 64 + m * 16 + fq * 4;
#pragma unroll
    for (int n = 0; n < 4; n++) {
      int col = colBase + wc * 64 + n * 16 + fr;
      f32x4 v = acc[m][n];
#pragma unroll
      for (int r = 0; r < 4; r++) out[(size_t)(row0 + r) * Ncols + col] = cvt_from_f<OT>(v[r]);
    }
  }
}

// ---------------------------------------------------------------------------
// gemm_vT: vT[b][c][n] = sal[row]·(xb @ wv)[row][c], transposed bf16 write.
// A = xb [65536x384], BT = wvT[384][384]. Grid (3, 512).
// ---------------------------------------------------------------------------
__global__ __launch_bounds__(256) void gemm_vT(const __hip_bfloat16* __restrict__ A,
                                               const __hip_bfloat16* __restrict__ BT,
                                               __hip_bfloat16* __restrict__ vT,
                                               const float* __restrict__ rowScale) {
  constexpr int K = 384;
  __shared__ __align__(16) __hip_bfloat16 Asl[128][32];
  __shared__ __align__(16) __hip_bfloat16 Bsl[128][32];
  int tid = threadIdx.x;
  int lane = tid & 63;
  int w = tid >> 6;
  int wr = w >> 1, wc = w & 1;
  int fr = lane & 15, fq = lane >> 4;
  int rowBase = blockIdx.y * 128, colBase = blockIdx.x * 128;

  int r1 = tid >> 2, kc1 = tid & 3;
  int r2 = (tid + 256) >> 2;

  char* aB1 = (char*)Asl + (size_t)(w * 64) * 16;
  char* aB2 = (char*)Asl + (size_t)(256 + w * 64) * 16;
  char* bB1 = (char*)Bsl + (size_t)(w * 64) * 16;
  char* bB2 = (char*)Bsl + (size_t)(256 + w * 64) * 16;

  const __hip_bfloat16* a1 = A + (size_t)(rowBase + r1) * K + kc1 * 8;
  const __hip_bfloat16* a2 = A + (size_t)(rowBase + r2) * K + kc1 * 8;
  const __hip_bfloat16* b1 = BT + (size_t)(colBase + r1) * K + kc1 * 8;
  const __hip_bfloat16* b2 = BT + (size_t)(colBase + r2) * K + kc1 * 8;

  f32x4 acc[4][4] = {};

  for (int kk = 0; kk < K; kk += 32) {
    gload16(a1 + kk, aB1);
    gload16(a2 + kk, aB2);
    gload16(b1 + kk, bB1);
    gload16(b2 + kk, bB2);
    __syncthreads();
    bf16x8 af[4], bfv[4];
#pragma unroll
    for (int m = 0; m < 4; m++) af[m] = *(const bf16x8*)&Asl[wr * 64 + m * 16 + fr][fq * 8];
#pragma unroll
    for (int n = 0; n < 4; n++) bfv[n] = *(const bf16x8*)&Bsl[wc * 64 + n * 16 + fr][fq * 8];
#pragma unroll
    for (int m = 0; m < 4; m++)
#pragma unroll
      for (int n = 0; n < 4; n++)
        acc[m][n] = __builtin_amdgcn_mfma_f32_16x16x32_bf16(af[m], bfv[n], acc[m][n], 0, 0, 0);
    __syncthreads();
  }

  float sv[4][4];
#pragma unroll
  for (int m = 0; m < 4; m++)
#pragma unroll
    for (int r = 0; r < 4; r++)
      sv[m][r] = rowScale[rowBase + wr * 64 + m * 16 + fq * 4 + r];

#pragma unroll
  for (int m = 0; m < 4; m++) {
    int row0 = rowBase + wr * 64 + m * 16 + fq * 4;
    int bb = row0 >> 12;
    int n0 = row0 & 4095;
#pragma unroll
    for (int n = 0; n < 4; n++) {
      int col = colBase + wc * 64 + n * 16 + fr;
      __hip_bfloat16 tb[4];
#pragma unroll
      for (int r = 0; r < 4; r++) tb[r] = __float2bfloat16(acc[m][n][r] * sv[m][r]);
      *(unsigned long long*)(vT + ((size_t)bb * 384 + col) * 4096 + n0) = *(unsigned long long*)tb;
    }
  }
}

// ---------------------------------------------------------------------------
// gemm_logits: lgT[b*128+hm][n] = sal[row]·(xb @ WlT^T)[row][hm], f32
// transposed write. A = xb, BT = WlT[128][384]. Grid (1, 512).
// ---------------------------------------------------------------------------
__global__ __launch_bounds__(256) void gemm_logits(const __hip_bfloat16* __restrict__ A,
                                                   const __hip_bfloat16* __restrict__ BT,
                                                   float* __restrict__ lgT,
                                                   const float* __restrict__ rowScale) {
  constexpr int K = 384;
  __shared__ __align__(16) __hip_bfloat16 Asl[128][32];
  __shared__ __align__(16) __hip_bfloat16 Bsl[128][32];
  int tid = threadIdx.x;
  int lane = tid & 63;
  int w = tid >> 6;
  int wr = w >> 1, wc = w & 1;
  int fr = lane & 15, fq = lane >> 4;
  int rowBase = blockIdx.y * 128;

  int r1 = tid >> 2, kc1 = tid & 3;
  int r2 = (tid + 256) >> 2;

  char* aB1 = (char*)Asl + (size_t)(w * 64) * 16;
  char* aB2 = (char*)Asl + (size_t)(256 + w * 64) * 16;
  char* bB1 = (char*)Bsl + (size_t)(w * 64) * 16;
  char* bB2 = (char*)Bsl + (size_t)(256 + w * 64) * 16;

  const __hip_bfloat16* a1 = A + (size_t)(rowBase + r1) * K + kc1 * 8;
  const __hip_bfloat16* a2 = A + (size_t)(rowBase + r2) * K + kc1 * 8;
  const __hip_bfloat16* b1 = BT + (size_t)r1 * K + kc1 * 8;
  const __hip_bfloat16* b2 = BT + (size_t)r2 * K + kc1 * 8;

  f32x4 acc[4][4] = {};

  for (int kk = 0; kk < K; kk += 32) {
    gload16(a1 + kk, aB1);
    gload16(a2 + kk, aB2);
    gload16(b1 + kk, bB1);
    gload16(b2 + kk, bB2);
    __syncthreads();
    bf16x8 af[4], bfv[4];
#pragma unroll
    for (int m = 0; m < 4; m++) af[m] = *(const bf16x8*)&Asl[wr * 64 + m * 16 + fr][fq * 8];
#pragma unroll
    for (int n = 0; n < 4; n++) bfv[n] = *(const bf16x8*)&Bsl[wc * 64 + n * 16 + fr][fq * 8];
#pragma unroll
    for (int m = 0; m < 4; m++)
#pragma unroll
      for (int n = 0; n < 4; n++)
        acc[m][n] = __builtin_amdgcn_mfma_f32_16x16x32_bf16(af[m], bfv[n], acc[m][n], 0, 0, 0);
    __syncthreads();
  }

  float sv[4][4];
#pragma unroll
  for (int m = 0; m < 4; m++)
#pragma unroll
    for (int r = 0; r < 4; r++)
      sv[m][r] = rowScale[rowBase + wr * 64 + m * 16 + fq * 4 + r];

#pragma unroll
  for (int m = 0; m < 4; m++) {
    int row0 = rowBase + wr * 64 + m * 16 + fq * 4;
    int bb = row0 >> 12;
    int n0 = row0 & 4095;
#pragma unroll
    for (int n = 0; n < 4; n++) {
      int col = wc * 64 + n * 16 + fr;  // 0..127 = hm
      float4 v;
      v.x = acc[m][n][0] * sv[m][0];
      v.y = acc[m][n][1] * sv[m][1];
      v.z = acc[m][n][2] * sv[m][2];
      v.w = acc[m][n][3] * sv[m][3];
      *(float4*)(lgT + ((size_t)bb * 128 + col) * 4096 + n0) = v;
    }
  }
}

// ---------------------------------------------------------------------------
// softmax_rows: PT[g][n] = softmax_n(lgT[g][n]), bf16 out. Block per row g.
// ---------------------------------------------------------------------------
__global__ __launch_bounds__(256) void softmax_rows(const float* __restrict__ lgT,
                                                    __hip_bfloat16* __restrict__ PT) {
  int g = blockIdx.x;
  const float* row = lgT + (size_t)g * 4096;
  int tid = threadIdx.x, wv = tid >> 6, lane = tid & 63;
  __shared__ float redm[4], reds[4];
  float v[16];
  const float4* rp = (const float4*)(row + tid * 16);
#pragma unroll
  for (int i = 0; i < 4; i++) {
    float4 q = rp[i];
    v[i * 4] = q.x; v[i * 4 + 1] = q.y; v[i * 4 + 2] = q.z; v[i * 4 + 3] = q.w;
  }
  float mx = v[0];
#pragma unroll
  for (int i = 1; i < 16; i++) mx = fmaxf(mx, v[i]);
#pragma unroll
  for (int off = 1; off < 64; off <<= 1) mx = fmaxf(mx, __shfl_xor(mx, off));
  if (lane == 0) redm[wv] = mx;
  __syncthreads();
  mx = fmaxf(fmaxf(redm[0], redm[1]), fmaxf(redm[2], redm[3]));
  float s = 0.f;
#pragma unroll
  for (int i = 0; i < 16; i++) {
    v[i] = __expf(v[i] - mx);
    s += v[i];
  }
#pragma unroll
  for (int off = 1; off < 64; off <<= 1) s += __shfl_xor(s, off);
  if (lane == 0) reds[wv] = s;
  __syncthreads();
  s = (reds[0] + reds[1]) + (reds[2] + reds[3]);
  float inv = 1.f / s;
  __hip_bfloat16 tb[16];
#pragma unroll
  for (int i = 0; i < 16; i++) tb[i] = __float2bfloat16(v[i] * inv);
  __hip_bfloat16* op = PT + (size_t)g * 4096 + tid * 16;
  *(ulonglong2*)op = *(ulonglong2*)tb;
  *(ulonglong2*)(op + 8) = *(ulonglong2*)(tb + 8);
}

// ---------------------------------------------------------------------------
// fill_wl: WlT[hm][ci] = sum_d w_kv_agg[ci][h*48+d] * qseed[m][h*48+d].
// ---------------------------------------------------------------------------
__global__ void fill_wl(const float* __restrict__ wkv, const float* __restrict__ qseed,
                        __hip_bfloat16* __restrict__ WlT) {
  int idx = blockIdx.x * 256 + threadIdx.x;  // 49152
  int hm = idx / 384, ci = idx - hm * 384;
  int h = hm >> 4, m = hm & 15;
  const float* wp = wkv + (size_t)ci * 768 + h * 48;
  const float* qp = qseed + m * 384 + h * 48;
  float acc = 0.f;
#pragma unroll
  for (int d = 0; d < 48; d++) acc += wp[d] * qp[d];
  WlT[idx] = __float2bfloat16(acc);
}

// ---------------------------------------------------------------------------
// anch_fix: anch1[b][m][c] = seeds[m][c] + outF[b*128 + (c/48)*16 + m][c].
// ---------------------------------------------------------------------------
__global__ void anch_fix(const float* __restrict__ outF, const float* __restrict__ seeds,
                         float* __restrict__ anch1) {
  int idx = blockIdx.x * 256 + threadIdx.x;  // 98304
  int b = idx / 6144;
  int rem = idx - b * 6144;
  int m = rem / 384, c = rem - m * 384;
  int h = c / 48;
  anch1[idx] = seeds[rem] + outF[((size_t)b * 128 + h * 16 + m) * 384 + c];
}

// ---------------------------------------------------------------------------
// pgemm: P = softmax_per_head(xb @ W_pbT_b^T), written bf16 to A2[:,384+hm].
// ---------------------------------------------------------------------------
__global__ __launch_bounds__(256) void pgemm(const __hip_bfloat16* __restrict__ A,
                                             const __hip_bfloat16* __restrict__ wpbT,
                                             __hip_bfloat16* __restrict__ A2) {
  constexpr int K = 384;
  __shared__ __align__(16) __hip_bfloat16 Asl[128][32];
  __shared__ __align__(16) __hip_bfloat16 Bsl[128][32];
  int tid = threadIdx.x;
  int lane = tid & 63;
  int w = tid >> 6;
  int wr = w >> 1, wc = w & 1;
  int fr = lane & 15, fq = lane >> 4;
  int rowBase = blockIdx.y * 128;
  const __hip_bfloat16* BTb = wpbT + (size_t)(rowBase >> 12) * (128 * 384);

  int r1 = tid >> 2, kc1 = tid & 3;
  int r2 = (tid + 256) >> 2;

  char* aB1 = (char*)Asl + (size_t)(w * 64) * 16;
  char* aB2 = (char*)Asl + (size_t)(256 + w * 64) * 16;
  char* bB1 = (char*)Bsl + (size_t)(w * 64) * 16;
  char* bB2 = (char*)Bsl + (size_t)(256 + w * 64) * 16;

  const __hip_bfloat16* a1 = A + (size_t)(rowBase + r1) * K + kc1 * 8;
  const __hip_bfloat16* a2 = A + (size_t)(rowBase + r2) * K + kc1 * 8;
  const __hip_bfloat16* b1 = BTb + (size_t)r1 * K + kc1 * 8;
  const __hip_bfloat16* b2 = BTb + (size_t)r2 * K + kc1 * 8;

  f32x4 acc[4][4] = {};

  for (int kk = 0; kk < K; kk += 32) {
    gload16(a1 + kk, aB1);
    gload16(a2 + kk, aB2);
    gload16(b1 + kk, bB1);
    gload16(b2 + kk, bB2);
    __syncthreads();
    bf16x8 af[4], bfv[4];
#pragma unroll
    for (int m = 0; m < 4; m++) af[m] = *(const bf16x8*)&Asl[wr * 64 + m * 16 + fr][fq * 8];
#pragma unroll
    for (int n = 0; n < 4; n++) bfv[n] = *(const bf16x8*)&Bsl[wc * 64 + n * 16 + fr][fq * 8];
#pragma unroll
    for (int m = 0; m < 4; m++)
#pragma unroll
      for (int n = 0; n < 4; n++)
        acc[m][n] = __builtin_amdgcn_mfma_f32_16x16x32_bf16(af[m], bfv[n], acc[m][n], 0, 0, 0);
    __syncthreads();
  }

  // epilogue: per (row, head) softmax over the 16-lane fr group.
#pragma unroll
  for (int m = 0; m < 4; m++) {
    int row0 = rowBase + wr * 64 + m * 16 + fq * 4;
#pragma unroll
    for (int n = 0; n < 4; n++) {
      int col = wc * 64 + n * 16 + fr;
      f32x4 v = acc[m][n];
      f32x4 mx = v;
#pragma unroll
      for (int off = 1; off < 16; off <<= 1)
#pragma unroll
        for (int r = 0; r < 4; r++) mx[r] = fmaxf(mx[r], __shfl_xor(mx[r], off));
      f32x4 e;
#pragma unroll
      for (int r = 0; r < 4; r++) e[r] = __expf(v[r] - mx[r]);
      f32x4 s = e;
#pragma unroll
      for (int off = 1; off < 16; off <<= 1)
#pragma unroll
        for (int r = 0; r < 4; r++) s[r] += __shfl_xor(s[r], off);
#pragma unroll
      for (int r = 0; r < 4; r++)
        A2[(size_t)(row0 + r) * 512 + 384 + col] = __float2bfloat16(e[r] / s[r]);
    }
  }
}

// ---------------------------------------------------------------------------
// anchor_proj2: out[b,16,wstride] = A[b,16,384] @ W[384,wstride].
// ---------------------------------------------------------------------------
__global__ __launch_bounds__(256) void anchor_proj2(const float* __restrict__ A,
                                                    const float* __restrict__ W,
                                                    float* __restrict__ out, int wstride,
                                                    int scaleCols) {
  int cs = blockIdx.x * 16;
  int b = blockIdx.y;
  __shared__ float a1[16][385];
  int tid = threadIdx.x;
  for (int idx = tid; idx < 6144; idx += 256) a1[idx / 384][idx % 384] = A[b * 6144 + idx];
  __syncthreads();
  int m = tid >> 4, cc = tid & 15;
  int col = cs + cc;
  const float* wp = W + col;
  float acc0 = 0.f, acc1 = 0.f, acc2 = 0.f, acc3 = 0.f;
#pragma unroll 4
  for (int k = 0; k < 384; k += 4) {
    acc0 += a1[m][k] * wp[(size_t)k * wstride];
    acc1 += a1[m][k + 1] * wp[(size_t)(k + 1) * wstride];
    acc2 += a1[m][k + 2] * wp[(size_t)(k + 2) * wstride];
    acc3 += a1[m][k + 3] * wp[(size_t)(k + 3) * wstride];
  }
  float acc = (acc0 + acc1) + (acc2 + acc3);
  if (col < scaleCols) acc *= SCALE;
  out[((size_t)b * 16 + m) * wstride + col] = acc;
}

// ---------------------------------------------------------------------------
// Self attention on anchors (16x16, per (b,h)); anchors2 = anchors1 + out.
// ---------------------------------------------------------------------------
__global__ void self_attn(const float* __restrict__ qsf, const float* __restrict__ kvs,
                          const float* __restrict__ anch1, float* __restrict__ anch2) {
  int h = blockIdx.x & 7, b = blockIdx.x >> 3;
  __shared__ float qs[16][48], ks[16][48], vs[16][48], p[16][17];
  int tid = threadIdx.x;
  for (int idx = tid; idx < 768; idx += 256) {
    int m = idx / 48, d = idx % 48;
    qs[m][d] = qsf[(b * 16 + m) * 384 + h * 48 + d];
    ks[m][d] = kvs[(b * 16 + m) * 768 + h * 48 + d];
    vs[m][d] = kvs[(b * 16 + m) * 768 + 384 + h * 48 + d];
  }
  __syncthreads();
  {
    int mq = tid >> 4, mk = tid & 15;
    float acc = 0.f;
    for (int d = 0; d < 48; d++) acc += qs[mq][d] * ks[mk][d];
    p[mq][mk] = acc;
  }
  __syncthreads();
  if (tid < 16) {
    float mx = -1e30f;
    for (int mk = 0; mk < 16; mk++) mx = fmaxf(mx, p[tid][mk]);
    float sum = 0.f;
    for (int mk = 0; mk < 16; mk++) {
      float e = __expf(p[tid][mk] - mx);
      p[tid][mk] = e;
      sum += e;
    }
    float inv = 1.f / sum;
    for (int mk = 0; mk < 16; mk++) p[tid][mk] *= inv;
  }
  __syncthreads();
  for (int idx = tid; idx < 768; idx += 256) {
    int m = idx / 48, d = idx % 48;
    float acc = 0.f;
    for (int mk = 0; mk < 16; mk++) acc += p[m][mk] * vs[mk][d];
    int c = h * 48 + d;
    anch2[(b * 16 + m) * 384 + c] = anch1[(b * 16 + m) * 384 + c] + acc;
  }
}

// ---------------------------------------------------------------------------
// fill_wpb: W_pbT[b][hm][k] = sum_d w_q_bcast[k][h*48+d] * k_b[b][m][h*48+d].
// ---------------------------------------------------------------------------
__global__ void fill_wpb(const float* __restrict__ wq, const float* __restrict__ kvb,
                         __hip_bfloat16* __restrict__ wpbT) {
  int idx = blockIdx.x * 256 + threadIdx.x;  // 786432
  int b = idx / 49152;
  int rem = idx - b * 49152;
  int hm = rem / 384, k = rem - hm * 384;
  int h = hm >> 4, m = hm & 15;
  const float* kp = kvb + ((size_t)(b * 16 + m)) * 768 + h * 48;
  const float* wp = wq + (size_t)k * 384 + h * 48;
  float acc = 0.f;
#pragma unroll
  for (int d = 0; d < 48; d++) acc += wp[d] * kp[d];
  wpbT[idx] = __float2bfloat16(acc);
}

// ---------------------------------------------------------------------------
// fill_bt2: BT2[b][cp][k2]:  k2<384 -> w_proj[k2][cp]
//                            k2>=384 -> sum_d v_b[b][m][h*48+d]*w_proj[h*48+d][cp]
// ---------------------------------------------------------------------------
__global__ void fill_bt2(const float* __restrict__ wproj, const float* __restrict__ kvb,
                         __hip_bfloat16* __restrict__ bt2) {
  int idx = blockIdx.x * 256 + threadIdx.x;  // 3145728
  int b = idx / 196608;
  int rem = idx - b * 196608;
  int cp = rem / 512, k2 = rem - cp * 512;
  float v;
  if (k2 < 384) {
    v = wproj[(size_t)k2 * 384 + cp];
  } else {
    int hm = k2 - 384, h = hm >> 4, m = hm & 15;
    const float* vp = kvb + ((size_t)(b * 16 + m)) * 768 + 384 + h * 48;
    const float* wp2 = wproj + (size_t)(h * 48) * 384 + cp;
    v = 0.f;
#pragma unroll
    for (int d = 0; d < 48; d++) v += vp[d] * wp2[(size_t)d * 384];
  }
  bt2[idx] = __float2bfloat16(v);
}

// ---------------------------------------------------------------------------
// dwconv2: depthwise 3x3 conv, no LDS/no syncs. Writes A2[:,0:384] (stride 512).
// ---------------------------------------------------------------------------
__global__ __launch_bounds__(256) void dwconv2(const __hip_bfloat16* __restrict__ xb,
                                               const float* __restrict__ dwk,
                                               __hip_bfloat16* __restrict__ A2) {
  int b = blockIdx.y;
  int wv = threadIdx.x >> 6, lane = threadIdx.x & 63;
  int c0 = lane * 6;
  float kw[6][9];
#pragma unroll
  for (int i = 0; i < 6; i++)
#pragma unroll
    for (int ki = 0; ki < 9; ki++) kw[i][ki] = dwk[(c0 + i) * 9 + ki];
  for (int it = 0; it < 8; it++) {
    int p = blockIdx.x * 32 + wv * 8 + it;
    int y = p >> 6, w = p & 63;
    size_t prow = (size_t)b * 4096 + p;
    float acc[6] = {};
#pragma unroll
    for (int dy = -1; dy <= 1; dy++) {
      int yy = y + dy;
      if (yy < 0 || yy >= 64) continue;  // wave-uniform
#pragma unroll
      for (int dx = -1; dx <= 1; dx++) {
        int ww = w + dx;
        if (ww < 0 || ww >= 64) continue;
        int ki = (dy + 1) * 3 + (dx + 1);
        const __hip_bfloat16* xp = xb + ((size_t)(b * 4096 + yy * 64 + ww)) * 384 + c0;
#pragma unroll
        for (int i = 0; i < 6; i++) acc[i] += __bfloat162float(xp[i]) * kw[i][ki];
      }
    }
    __hip_bfloat16 tb[6];
#pragma unroll
    for (int i = 0; i < 6; i++) tb[i] = __float2bfloat16(acc[i]);
    __hip_bfloat16* gp = A2 + prow * 512 + c0;
    *(unsigned int*)(gp) = *(unsigned int*)(tb);
    *(unsigned int*)(gp + 2) = *(unsigned int*)(tb + 2);
    *(unsigned int*)(gp + 4) = *(unsigned int*)(tb + 4);
  }
}

// ---------------------------------------------------------------------------
extern "C" void kernel_launch(void* const* d_in, const int* in_sizes, int n_in,
                              void* d_out, int out_size, void* d_ws, size_t ws_size,
                              hipStream_t stream) {
  (void)in_sizes; (void)n_in; (void)out_size; (void)ws_size;
  const float* x = (const float*)d_in[0];
  const float* wsal = (const float*)d_in[3];
  const float* bsal = (const float*)d_in[4];
  const float* seeds = (const float*)d_in[5];
  const float* w_q_agg = (const float*)d_in[6];
  const float* w_kv_agg = (const float*)d_in[7];
  const float* w_q_self = (const float*)d_in[8];
  const float* w_kv_self = (const float*)d_in[9];
  const float* w_q_bcast = (const float*)d_in[10];
  const float* w_kv_bcast = (const float*)d_in[11];
  const float* dwk = (const float*)d_in[12];
  const float* w_proj = (const float*)d_in[13];
  float* out = (float*)d_out;

  char* ws = (char*)d_ws;
  size_t off = 0;
  auto take = [&](size_t bytes) -> void* {
    void* p = ws + off;
    off += (bytes + 255) & ~(size_t)255;
    return p;
  };
  __hip_bfloat16* xb = (__hip_bfloat16*)take(50331648);      // bf16(x)
  __hip_bfloat16* vT = (__hip_bfloat16*)take(50331648);      // [16][384][4096] bf16
  float* logitsT = (float*)take(33554432);                   // [2048][4096] f32
  __hip_bfloat16* PT = (__hip_bfloat16*)take(16777216);      // [2048][4096] bf16
  float* outF = (float*)take(3145728);                       // [2048][384] f32
  float* qseed = (float*)take(24576);
  float* sal = (float*)take(262144);
  float* anch1 = (float*)take(393216);
  float* anch2 = (float*)take(393216);
  float* q_self = (float*)take(393216);
  float* kv_self = (float*)take(786432);
  float* kv_b = (float*)take(786432);
  __hip_bfloat16* wkvT = (__hip_bfloat16*)take(589824);   // [768][384] bf16
  __hip_bfloat16* WlT = (__hip_bfloat16*)take(98304);     // [128][384] bf16
  __hip_bfloat16* wpbT = (__hip_bfloat16*)take(1572864);  // [16][128][384] bf16
  __hip_bfloat16* bt2 = (__hip_bfloat16*)take(6291456);   // [16][384][512] bf16
  // A2 [65536][512] bf16 = 64 MB aliases vT + logitsT (both dead after PV GEMM)
  __hip_bfloat16* A2 = vT;

  // 0) weight prep (tiny)
  wcast_t<<<1152, 256, 0, stream>>>(w_kv_agg, wkvT, 384, 768);
  // 1) xb + saliency
  prep<<<16384, 256, 0, stream>>>(x, wsal, bsal, xb, sal);
  // 2) vT[b][c][n] = sal·(xb @ wv) transposed  (v-half of old kv GEMM)
  gemm_vT<<<dim3(3, 512), 256, 0, stream>>>(xb, wkvT + 384 * 384, vT, sal);
  // 3) agg attention as GEMMs: qseed -> Wl -> logits -> softmax -> PV
  anchor_proj2<<<dim3(24, 1), 256, 0, stream>>>(seeds, w_q_agg, qseed, 384, 384);
  fill_wl<<<192, 256, 0, stream>>>(w_kv_agg, qseed, WlT);
  gemm_logits<<<dim3(1, 512), 256, 0, stream>>>(xb, WlT, logitsT, sal);
  softmax_rows<<<2048, 256, 0, stream>>>(logitsT, PT);
  gemm_mfma<4096, float, false, 7><<<dim3(3, 16), 256, 0, stream>>>(PT, vT, outF, 384, nullptr, (size_t)384 * 4096);
  anch_fix<<<384, 256, 0, stream>>>(outF, seeds, anch1);
  // 4) anchor self-attention -> anchors2
  anchor_proj2<<<dim3(24, 16), 256, 0, stream>>>(anch1, w_q_self, q_self, 384, 384);
  anchor_proj2<<<dim3(48, 16), 256, 0, stream>>>(anch1, w_kv_self, kv_self, 768, 0);
  self_attn<<<128, 256, 0, stream>>>(q_self, kv_self, anch1, anch2);
  // 5) kv_bcast = anchors2 @ w_kv_bcast (SCALE on k half)
  anchor_proj2<<<dim3(48, 16), 256, 0, stream>>>(anch2, w_kv_bcast, kv_b, 768, 384);
  // 6) per-batch folded weights
  fill_wpb<<<3072, 256, 0, stream>>>(w_q_bcast, kv_b, wpbT);
  fill_bt2<<<12288, 256, 0, stream>>>(w_proj, kv_b, bt2);
  // 7) A2[:,0:384] = dwconv(xb)  (vT/logitsT dead -> A2)
  dwconv2<<<dim3(128, 16), 256, 0, stream>>>(xb, dwk, A2);
  // 8) A2[:,384:512] = P = softmax(xb @ W_pbT_b)
  pgemm<<<dim3(1, 512), 256, 0, stream>>>(xb, wpbT, A2);
  // 9) out = A2 @ BT2_b   (K=512, f32 out)
  gemm_mfma<512, float, false, 12><<<dim3(3, 512), 256, 0, stream>>>(A2, bt2, out, 384, nullptr, (size_t)384 * 512);
}

// Round 8
// 415.177 us; speedup vs baseline: 5.4741x; 1.1540x over previous
//
#include <hip/hip_runtime.h>
#include <hip/hip_bf16.h>

// Problem constants: B=16, N=4096, C=384, M=16, NH=8, HD=48, H=W=64
#define SCALE 0.14433756729740643f  // 48^-0.5

typedef __attribute__((ext_vector_type(8))) short bf16x8;
typedef __attribute__((ext_vector_type(4))) float f32x4;

template <typename T> __device__ inline T cvt_from_f(float v);
template <> __device__ inline float cvt_from_f<float>(float v) { return v; }
template <> __device__ inline __hip_bfloat16 cvt_from_f<__hip_bfloat16>(float v) { return __float2bfloat16(v); }

__device__ inline void gload16(const void* g, void* l) {
  __builtin_amdgcn_global_load_lds((const __attribute__((address_space(1))) void*)g,
                                   (__attribute__((address_space(3))) void*)l, 16, 0, 0);
}

// ---------------------------------------------------------------------------
// prep: xb = bf16(x); sal[row] = sigmoid(x·wsal + b). One wave per row.
// ---------------------------------------------------------------------------
__global__ __launch_bounds__(256) void prep(const float* __restrict__ x,
                                            const float* __restrict__ wsal,
                                            const float* __restrict__ bsal,
                                            __hip_bfloat16* __restrict__ xb,
                                            float* __restrict__ sal) {
  int wave = threadIdx.x >> 6, lane = threadIdx.x & 63;
  size_t row = (size_t)blockIdx.x * 4 + wave;
  const float* xr = x + row * 384;
  float xs[6];
  float part = 0.f;
#pragma unroll
  for (int j = 0; j < 6; j++) {
    int c = lane + 64 * j;
    xs[j] = xr[c];
    part += xs[j] * wsal[c];
  }
#pragma unroll
  for (int off = 32; off >= 1; off >>= 1) part += __shfl_xor(part, off);
  float s = 1.f / (1.f + __expf(-(part + bsal[0])));
#pragma unroll
  for (int j = 0; j < 6; j++) {
    int c = lane + 64 * j;
    xb[row * 384 + c] = __float2bfloat16(xs[j]);
  }
  if (lane == 0) sal[row] = s;
}

// ---------------------------------------------------------------------------
// wcast_tv: wvlT[n][k] = bf16(w_kv_agg[k][384+n])  (v-columns transposed)
// ---------------------------------------------------------------------------
__global__ void wcast_tv(const float* __restrict__ w, __hip_bfloat16* __restrict__ wt) {
  int idx = blockIdx.x * 256 + threadIdx.x;  // 147456
  if (idx >= 384 * 384) return;
  int n = idx / 384, k = idx % 384;
  wt[idx] = __float2bfloat16(w[(size_t)k * 768 + 384 + n]);
}

// ---------------------------------------------------------------------------
// MFMA GEMM: out[M,Ncols] = A[M,K](bf16) @ BT[Ncols,K]^T, per-batch BT via
// batch = rowBase>>BSHIFT. 128x128 tile, BK=32, 4 waves (m97 structure).
// ---------------------------------------------------------------------------
template <int K, typename OT, int BSHIFT>
__global__ __launch_bounds__(256) void gemm_mfma(const __hip_bfloat16* __restrict__ A,
                                                 const __hip_bfloat16* __restrict__ BT,
                                                 OT* __restrict__ out, int Ncols,
                                                 size_t btBatchStride) {
  __shared__ __align__(16) __hip_bfloat16 Asl[128][32];
  __shared__ __align__(16) __hip_bfloat16 Bsl[128][32];
  int tid = threadIdx.x;
  int lane = tid & 63;
  int w = tid >> 6;
  int wr = w >> 1, wc = w & 1;
  int fr = lane & 15, fq = lane >> 4;
  int rowBase = blockIdx.y * 128, colBase = blockIdx.x * 128;
  const __hip_bfloat16* BTb = BT + (size_t)(rowBase >> BSHIFT) * btBatchStride;

  int r1 = tid >> 2, kc1 = tid & 3;
  int r2 = (tid + 256) >> 2;

  char* aB1 = (char*)Asl + (size_t)(w * 64) * 16;
  char* aB2 = (char*)Asl + (size_t)(256 + w * 64) * 16;
  char* bB1 = (char*)Bsl + (size_t)(w * 64) * 16;
  char* bB2 = (char*)Bsl + (size_t)(256 + w * 64) * 16;

  const __hip_bfloat16* a1 = A + (size_t)(rowBase + r1) * K + kc1 * 8;
  const __hip_bfloat16* a2 = A + (size_t)(rowBase + r2) * K + kc1 * 8;
  const __hip_bfloat16* b1 = BTb + (size_t)(colBase + r1) * K + kc1 * 8;
  const __hip_bfloat16* b2 = BTb + (size_t)(colBase + r2) * K + kc1 * 8;

  f32x4 acc[4][4] = {};

  for (int kk = 0; kk < K; kk += 32) {
    gload16(a1 + kk, aB1);
    gload16(a2 + kk, aB2);
    gload16(b1 + kk, bB1);
    gload16(b2 + kk, bB2);
    __syncthreads();
    bf16x8 af[4], bfv[4];
#pragma unroll
    for (int m = 0; m < 4; m++) af[m] = *(const bf16x8*)&Asl[wr * 64 + m * 16 + fr][fq * 8];
#pragma unroll
    for (int n = 0; n < 4; n++) bfv[n] = *(const bf16x8*)&Bsl[wc * 64 + n * 16 + fr][fq * 8];
#pragma unroll
    for (int m = 0; m < 4; m++)
#pragma unroll
      for (int n = 0; n < 4; n++)
        acc[m][n] = __builtin_amdgcn_mfma_f32_16x16x32_bf16(af[m], bfv[n], acc[m][n], 0, 0, 0);
    __syncthreads();
  }

#pragma unroll
  for (int m = 0; m < 4; m++) {
    int row0 = rowBase + wr * 64 + m * 16 + fq * 4;
#pragma unroll
    for (int n = 0; n < 4; n++) {
      int col = colBase + wc * 64 + n * 16 + fr;
      f32x4 v = acc[m][n];
#pragma unroll
      for (int r = 0; r < 4; r++) out[(size_t)(row0 + r) * Ncols + col] = cvt_from_f<OT>(v[r]);
    }
  }
}

// ---------------------------------------------------------------------------
// gemm_vlog: one pass over xb computes BOTH
//   x<3 : vT[b][c][n]  = sal·(xb @ wv)          (transposed bf16)
//   x==3: lgT[b*128+hm][n] = sal·(xb @ Wl^T)    (transposed f32)
// BT = wvlT[512][384] (v rows 0..383, Wl rows 384..511). Grid (4, 512).
// ---------------------------------------------------------------------------
__global__ __launch_bounds__(256) void gemm_vlog(const __hip_bfloat16* __restrict__ A,
                                                 const __hip_bfloat16* __restrict__ BT,
                                                 __hip_bfloat16* __restrict__ vT,
                                                 float* __restrict__ lgT,
                                                 const float* __restrict__ rowScale) {
  constexpr int K = 384;
  __shared__ __align__(16) __hip_bfloat16 Asl[128][32];
  __shared__ __align__(16) __hip_bfloat16 Bsl[128][32];
  int tid = threadIdx.x;
  int lane = tid & 63;
  int w = tid >> 6;
  int wr = w >> 1, wc = w & 1;
  int fr = lane & 15, fq = lane >> 4;
  int rowBase = blockIdx.y * 128, colBase = blockIdx.x * 128;

  int r1 = tid >> 2, kc1 = tid & 3;
  int r2 = (tid + 256) >> 2;

  char* aB1 = (char*)Asl + (size_t)(w * 64) * 16;
  char* aB2 = (char*)Asl + (size_t)(256 + w * 64) * 16;
  char* bB1 = (char*)Bsl + (size_t)(w * 64) * 16;
  char* bB2 = (char*)Bsl + (size_t)(256 + w * 64) * 16;

  const __hip_bfloat16* a1 = A + (size_t)(rowBase + r1) * K + kc1 * 8;
  const __hip_bfloat16* a2 = A + (size_t)(rowBase + r2) * K + kc1 * 8;
  const __hip_bfloat16* b1 = BT + (size_t)(colBase + r1) * K + kc1 * 8;
  const __hip_bfloat16* b2 = BT + (size_t)(colBase + r2) * K + kc1 * 8;

  f32x4 acc[4][4] = {};

  for (int kk = 0; kk < K; kk += 32) {
    gload16(a1 + kk, aB1);
    gload16(a2 + kk, aB2);
    gload16(b1 + kk, bB1);
    gload16(b2 + kk, bB2);
    __syncthreads();
    bf16x8 af[4], bfv[4];
#pragma unroll
    for (int m = 0; m < 4; m++) af[m] = *(const bf16x8*)&Asl[wr * 64 + m * 16 + fr][fq * 8];
#pragma unroll
    for (int n = 0; n < 4; n++) bfv[n] = *(const bf16x8*)&Bsl[wc * 64 + n * 16 + fr][fq * 8];
#pragma unroll
    for (int m = 0; m < 4; m++)
#pragma unroll
      for (int n = 0; n < 4; n++)
        acc[m][n] = __builtin_amdgcn_mfma_f32_16x16x32_bf16(af[m], bfv[n], acc[m][n], 0, 0, 0);
    __syncthreads();
  }

  float sv[4][4];
#pragma unroll
  for (int m = 0; m < 4; m++)
#pragma unroll
    for (int r = 0; r < 4; r++)
      sv[m][r] = rowScale[rowBase + wr * 64 + m * 16 + fq * 4 + r];

  if (blockIdx.x < 3) {
    // v epilogue: transposed bf16 write
#pragma unroll
    for (int m = 0; m < 4; m++) {
      int row0 = rowBase + wr * 64 + m * 16 + fq * 4;
      int bb = row0 >> 12;
      int n0 = row0 & 4095;
#pragma unroll
      for (int n = 0; n < 4; n++) {
        int col = colBase + wc * 64 + n * 16 + fr;
        __hip_bfloat16 tb[4];
#pragma unroll
        for (int r = 0; r < 4; r++) tb[r] = __float2bfloat16(acc[m][n][r] * sv[m][r]);
        *(unsigned long long*)(vT + ((size_t)bb * 384 + col) * 4096 + n0) = *(unsigned long long*)tb;
      }
    }
  } else {
    // logits epilogue: transposed f32 write
#pragma unroll
    for (int m = 0; m < 4; m++) {
      int row0 = rowBase + wr * 64 + m * 16 + fq * 4;
      int bb = row0 >> 12;
      int n0 = row0 & 4095;
#pragma unroll
      for (int n = 0; n < 4; n++) {
        int col = wc * 64 + n * 16 + fr;  // 0..127 = hm
        float4 v;
        v.x = acc[m][n][0] * sv[m][0];
        v.y = acc[m][n][1] * sv[m][1];
        v.z = acc[m][n][2] * sv[m][2];
        v.w = acc[m][n][3] * sv[m][3];
        *(float4*)(lgT + ((size_t)bb * 128 + col) * 4096 + n0) = v;
      }
    }
  }
}

// ---------------------------------------------------------------------------
// gemm_pv: split-K PV. pbuf[z][g][c] = PT[g, z*512:(z+1)*512] @ vT_b^T slice.
// Grid (3, 16, 8). A = PT [2048][4096]; BT = vT per batch (g>>7).
// ---------------------------------------------------------------------------
__global__ __launch_bounds__(256) void gemm_pv(const __hip_bfloat16* __restrict__ PT,
                                               const __hip_bfloat16* __restrict__ vT,
                                               float* __restrict__ pbuf) {
  __shared__ __align__(16) __hip_bfloat16 Asl[128][32];
  __shared__ __align__(16) __hip_bfloat16 Bsl[128][32];
  int tid = threadIdx.x;
  int lane = tid & 63;
  int w = tid >> 6;
  int wr = w >> 1, wc = w & 1;
  int fr = lane & 15, fq = lane >> 4;
  int rowBase = blockIdx.y * 128, colBase = blockIdx.x * 128;
  int kz = blockIdx.z;
  const __hip_bfloat16* BTb = vT + (size_t)(rowBase >> 7) * 384 * 4096;

  int r1 = tid >> 2, kc1 = tid & 3;
  int r2 = (tid + 256) >> 2;

  char* aB1 = (char*)Asl + (size_t)(w * 64) * 16;
  char* aB2 = (char*)Asl + (size_t)(256 + w * 64) * 16;
  char* bB1 = (char*)Bsl + (size_t)(w * 64) * 16;
  char* bB2 = (char*)Bsl + (size_t)(256 + w * 64) * 16;

  const __hip_bfloat16* a1 = PT + (size_t)(rowBase + r1) * 4096 + kz * 512 + kc1 * 8;
  const __hip_bfloat16* a2 = PT + (size_t)(rowBase + r2) * 4096 + kz * 512 + kc1 * 8;
  const __hip_bfloat16* b1 = BTb + (size_t)(colBase + r1) * 4096 + kz * 512 + kc1 * 8;
  const __hip_bfloat16* b2 = BTb + (size_t)(colBase + r2) * 4096 + kz * 512 + kc1 * 8;

  f32x4 acc[4][4] = {};

  for (int kk = 0; kk < 512; kk += 32) {
    gload16(a1 + kk, aB1);
    gload16(a2 + kk, aB2);
    gload16(b1 + kk, bB1);
    gload16(b2 + kk, bB2);
    __syncthreads();
    bf16x8 af[4], bfv[4];
#pragma unroll
    for (int m = 0; m < 4; m++) af[m] = *(const bf16x8*)&Asl[wr * 64 + m * 16 + fr][fq * 8];
#pragma unroll
    for (int n = 0; n < 4; n++) bfv[n] = *(const bf16x8*)&Bsl[wc * 64 + n * 16 + fr][fq * 8];
#pragma unroll
    for (int m = 0; m < 4; m++)
#pragma unroll
      for (int n = 0; n < 4; n++)
        acc[m][n] = __builtin_amdgcn_mfma_f32_16x16x32_bf16(af[m], bfv[n], acc[m][n], 0, 0, 0);
    __syncthreads();
  }

  float* outz = pbuf + (size_t)kz * 786432;
#pragma unroll
  for (int m = 0; m < 4; m++) {
    int row0 = rowBase + wr * 64 + m * 16 + fq * 4;
#pragma unroll
    for (int n = 0; n < 4; n++) {
      int col = colBase + wc * 64 + n * 16 + fr;
      f32x4 v = acc[m][n];
#pragma unroll
      for (int r = 0; r < 4; r++) outz[(size_t)(row0 + r) * 384 + col] = v[r];
    }
  }
}

// ---------------------------------------------------------------------------
// anch_fix2: anch1[b][m][c] = seeds[m][c] + sum_z pbuf[z][b*128+h(c)*16+m][c].
// ---------------------------------------------------------------------------
__global__ void anch_fix2(const float* __restrict__ pbuf, const float* __restrict__ seeds,
                          float* __restrict__ anch1) {
  int idx = blockIdx.x * 256 + threadIdx.x;  // 98304
  int b = idx / 6144;
  int rem = idx - b * 6144;
  int m = rem / 384, c = rem - m * 384;
  int g = b * 128 + (c / 48) * 16 + m;
  const float* p = pbuf + (size_t)g * 384 + c;
  float s = 0.f;
#pragma unroll
  for (int z = 0; z < 8; z++) s += p[(size_t)z * 786432];
  anch1[idx] = seeds[rem] + s;
}

// ---------------------------------------------------------------------------
// softmax_rows: PT[g][n] = softmax_n(lgT[g][n]), bf16 out. Block per row g.
// ---------------------------------------------------------------------------
__global__ __launch_bounds__(256) void softmax_rows(const float* __restrict__ lgT,
                                                    __hip_bfloat16* __restrict__ PT) {
  int g = blockIdx.x;
  const float* row = lgT + (size_t)g * 4096;
  int tid = threadIdx.x, wv = tid >> 6, lane = tid & 63;
  __shared__ float redm[4], reds[4];
  float v[16];
  const float4* rp = (const float4*)(row + tid * 16);
#pragma unroll
  for (int i = 0; i < 4; i++) {
    float4 q = rp[i];
    v[i * 4] = q.x; v[i * 4 + 1] = q.y; v[i * 4 + 2] = q.z; v[i * 4 + 3] = q.w;
  }
  float mx = v[0];
#pragma unroll
  for (int i = 1; i < 16; i++) mx = fmaxf(mx, v[i]);
#pragma unroll
  for (int off = 1; off < 64; off <<= 1) mx = fmaxf(mx, __shfl_xor(mx, off));
  if (lane == 0) redm[wv] = mx;
  __syncthreads();
  mx = fmaxf(fmaxf(redm[0], redm[1]), fmaxf(redm[2], redm[3]));
  float s = 0.f;
#pragma unroll
  for (int i = 0; i < 16; i++) {
    v[i] = __expf(v[i] - mx);
    s += v[i];
  }
#pragma unroll
  for (int off = 1; off < 64; off <<= 1) s += __shfl_xor(s, off);
  if (lane == 0) reds[wv] = s;
  __syncthreads();
  s = (reds[0] + reds[1]) + (reds[2] + reds[3]);
  float inv = 1.f / s;
  __hip_bfloat16 tb[16];
#pragma unroll
  for (int i = 0; i < 16; i++) tb[i] = __float2bfloat16(v[i] * inv);
  __hip_bfloat16* op = PT + (size_t)g * 4096 + tid * 16;
  *(ulonglong2*)op = *(ulonglong2*)tb;
  *(ulonglong2*)(op + 8) = *(ulonglong2*)(tb + 8);
}

// ---------------------------------------------------------------------------
// fill_wl: wvlT[384+hm][ci] = sum_d w_kv_agg[ci][h*48+d] * qseed[m][h*48+d].
// ---------------------------------------------------------------------------
__global__ void fill_wl(const float* __restrict__ wkv, const float* __restrict__ qseed,
                        __hip_bfloat16* __restrict__ wvlT) {
  int idx = blockIdx.x * 256 + threadIdx.x;  // 49152
  int hm = idx / 384, ci = idx - hm * 384;
  int h = hm >> 4, m = hm & 15;
  const float* wp = wkv + (size_t)ci * 768 + h * 48;
  const float* qp = qseed + m * 384 + h * 48;
  float acc = 0.f;
#pragma unroll
  for (int d = 0; d < 48; d++) acc += wp[d] * qp[d];
  wvlT[384 * 384 + idx] = __float2bfloat16(acc);
}

// ---------------------------------------------------------------------------
// pgemm: P = softmax_per_head(xb @ W_pbT_b^T), written bf16 to A2[:,384+hm].
// ---------------------------------------------------------------------------
__global__ __launch_bounds__(256) void pgemm(const __hip_bfloat16* __restrict__ A,
                                             const __hip_bfloat16* __restrict__ wpbT,
                                             __hip_bfloat16* __restrict__ A2) {
  constexpr int K = 384;
  __shared__ __align__(16) __hip_bfloat16 Asl[128][32];
  __shared__ __align__(16) __hip_bfloat16 Bsl[128][32];
  int tid = threadIdx.x;
  int lane = tid & 63;
  int w = tid >> 6;
  int wr = w >> 1, wc = w & 1;
  int fr = lane & 15, fq = lane >> 4;
  int rowBase = blockIdx.y * 128;
  const __hip_bfloat16* BTb = wpbT + (size_t)(rowBase >> 12) * (128 * 384);

  int r1 = tid >> 2, kc1 = tid & 3;
  int r2 = (tid + 256) >> 2;

  char* aB1 = (char*)Asl + (size_t)(w * 64) * 16;
  char* aB2 = (char*)Asl + (size_t)(256 + w * 64) * 16;
  char* bB1 = (char*)Bsl + (size_t)(w * 64) * 16;
  char* bB2 = (char*)Bsl + (size_t)(256 + w * 64) * 16;

  const __hip_bfloat16* a1 = A + (size_t)(rowBase + r1) * K + kc1 * 8;
  const __hip_bfloat16* a2 = A + (size_t)(rowBase + r2) * K + kc1 * 8;
  const __hip_bfloat16* b1 = BTb + (size_t)r1 * K + kc1 * 8;
  const __hip_bfloat16* b2 = BTb + (size_t)r2 * K + kc1 * 8;

  f32x4 acc[4][4] = {};

  for (int kk = 0; kk < K; kk += 32) {
    gload16(a1 + kk, aB1);
    gload16(a2 + kk, aB2);
    gload16(b1 + kk, bB1);
    gload16(b2 + kk, bB2);
    __syncthreads();
    bf16x8 af[4], bfv[4];
#pragma unroll
    for (int m = 0; m < 4; m++) af[m] = *(const bf16x8*)&Asl[wr * 64 + m * 16 + fr][fq * 8];
#pragma unroll
    for (int n = 0; n < 4; n++) bfv[n] = *(const bf16x8*)&Bsl[wc * 64 + n * 16 + fr][fq * 8];
#pragma unroll
    for (int m = 0; m < 4; m++)
#pragma unroll
      for (int n = 0; n < 4; n++)
        acc[m][n] = __builtin_amdgcn_mfma_f32_16x16x32_bf16(af[m], bfv[n], acc[m][n], 0, 0, 0);
    __syncthreads();
  }

  // epilogue: per (row, head) softmax over the 16-lane fr group.
#pragma unroll
  for (int m = 0; m < 4; m++) {
    int row0 = rowBase + wr * 64 + m * 16 + fq * 4;
#pragma unroll
    for (int n = 0; n < 4; n++) {
      int col = wc * 64 + n * 16 + fr;
      f32x4 v = acc[m][n];
      f32x4 mx = v;
#pragma unroll
      for (int off = 1; off < 16; off <<= 1)
#pragma unroll
        for (int r = 0; r < 4; r++) mx[r] = fmaxf(mx[r], __shfl_xor(mx[r], off));
      f32x4 e;
#pragma unroll
      for (int r = 0; r < 4; r++) e[r] = __expf(v[r] - mx[r]);
      f32x4 s = e;
#pragma unroll
      for (int off = 1; off < 16; off <<= 1)
#pragma unroll
        for (int r = 0; r < 4; r++) s[r] += __shfl_xor(s[r], off);
#pragma unroll
      for (int r = 0; r < 4; r++)
        A2[(size_t)(row0 + r) * 512 + 384 + col] = __float2bfloat16(e[r] / s[r]);
    }
  }
}

// ---------------------------------------------------------------------------
// anchor_proj2: out[b,16,wstride] = A[b,16,384] @ W[384,wstride].
// ---------------------------------------------------------------------------
__global__ __launch_bounds__(256) void anchor_proj2(const float* __restrict__ A,
                                                    const float* __restrict__ W,
                                                    float* __restrict__ out, int wstride,
                                                    int scaleCols) {
  int cs = blockIdx.x * 16;
  int b = blockIdx.y;
  __shared__ float a1[16][385];
  int tid = threadIdx.x;
  for (int idx = tid; idx < 6144; idx += 256) a1[idx / 384][idx % 384] = A[b * 6144 + idx];
  __syncthreads();
  int m = tid >> 4, cc = tid & 15;
  int col = cs + cc;
  const float* wp = W + col;
  float acc0 = 0.f, acc1 = 0.f, acc2 = 0.f, acc3 = 0.f;
#pragma unroll 4
  for (int k = 0; k < 384; k += 4) {
    acc0 += a1[m][k] * wp[(size_t)k * wstride];
    acc1 += a1[m][k + 1] * wp[(size_t)(k + 1) * wstride];
    acc2 += a1[m][k + 2] * wp[(size_t)(k + 2) * wstride];
    acc3 += a1[m][k + 3] * wp[(size_t)(k + 3) * wstride];
  }
  float acc = (acc0 + acc1) + (acc2 + acc3);
  if (col < scaleCols) acc *= SCALE;
  out[((size_t)b * 16 + m) * wstride + col] = acc;
}

// ---------------------------------------------------------------------------
// Self attention on anchors (16x16, per (b,h)); anchors2 = anchors1 + out.
// ---------------------------------------------------------------------------
__global__ void self_attn(const float* __restrict__ qsf, const float* __restrict__ kvs,
                          const float* __restrict__ anch1, float* __restrict__ anch2) {
  int h = blockIdx.x & 7, b = blockIdx.x >> 3;
  __shared__ float qs[16][48], ks[16][48], vs[16][48], p[16][17];
  int tid = threadIdx.x;
  for (int idx = tid; idx < 768; idx += 256) {
    int m = idx / 48, d = idx % 48;
    qs[m][d] = qsf[(b * 16 + m) * 384 + h * 48 + d];
    ks[m][d] = kvs[(b * 16 + m) * 768 + h * 48 + d];
    vs[m][d] = kvs[(b * 16 + m) * 768 + 384 + h * 48 + d];
  }
  __syncthreads();
  {
    int mq = tid >> 4, mk = tid & 15;
    float acc = 0.f;
    for (int d = 0; d < 48; d++) acc += qs[mq][d] * ks[mk][d];
    p[mq][mk] = acc;
  }
  __syncthreads();
  if (tid < 16) {
    float mx = -1e30f;
    for (int mk = 0; mk < 16; mk++) mx = fmaxf(mx, p[tid][mk]);
    float sum = 0.f;
    for (int mk = 0; mk < 16; mk++) {
      float e = __expf(p[tid][mk] - mx);
      p[tid][mk] = e;
      sum += e;
    }
    float inv = 1.f / sum;
    for (int mk = 0; mk < 16; mk++) p[tid][mk] *= inv;
  }
  __syncthreads();
  for (int idx = tid; idx < 768; idx += 256) {
    int m = idx / 48, d = idx % 48;
    float acc = 0.f;
    for (int mk = 0; mk < 16; mk++) acc += p[m][mk] * vs[mk][d];
    int c = h * 48 + d;
    anch2[(b * 16 + m) * 384 + c] = anch1[(b * 16 + m) * 384 + c] + acc;
  }
}

// ---------------------------------------------------------------------------
// fill_wpb: W_pbT[b][hm][k] = sum_d w_q_bcast[k][h*48+d] * k_b[b][m][h*48+d].
// ---------------------------------------------------------------------------
__global__ void fill_wpb(const float* __restrict__ wq, const float* __restrict__ kvb,
                         __hip_bfloat16* __restrict__ wpbT) {
  int idx = blockIdx.x * 256 + threadIdx.x;  // 786432
  int b = idx / 49152;
  int rem = idx - b * 49152;
  int hm = rem / 384, k = rem - hm * 384;
  int h = hm >> 4, m = hm & 15;
  const float* kp = kvb + ((size_t)(b * 16 + m)) * 768 + h * 48;
  const float* wp = wq + (size_t)k * 384 + h * 48;
  float acc = 0.f;
#pragma unroll
  for (int d = 0; d < 48; d++) acc += wp[d] * kp[d];
  wpbT[idx] = __float2bfloat16(acc);
}

// ---------------------------------------------------------------------------
// fill_bt2: BT2[b][cp][k2]:  k2<384 -> w_proj[k2][cp]
//                            k2>=384 -> sum_d v_b[b][m][h*48+d]*w_proj[h*48+d][cp]
// ---------------------------------------------------------------------------
__global__ void fill_bt2(const float* __restrict__ wproj, const float* __restrict__ kvb,
                         __hip_bfloat16* __restrict__ bt2) {
  int idx = blockIdx.x * 256 + threadIdx.x;  // 3145728
  int b = idx / 196608;
  int rem = idx - b * 196608;
  int cp = rem / 512, k2 = rem - cp * 512;
  float v;
  if (k2 < 384) {
    v = wproj[(size_t)k2 * 384 + cp];
  } else {
    int hm = k2 - 384, h = hm >> 4, m = hm & 15;
    const float* vp = kvb + ((size_t)(b * 16 + m)) * 768 + 384 + h * 48;
    const float* wp2 = wproj + (size_t)(h * 48) * 384 + cp;
    v = 0.f;
#pragma unroll
    for (int d = 0; d < 48; d++) v += vp[d] * wp2[(size_t)d * 384];
  }
  bt2[idx] = __float2bfloat16(v);
}

// ---------------------------------------------------------------------------
// dwconv2: depthwise 3x3 conv, no LDS/no syncs. Writes A2[:,0:384] (stride 512).
// ---------------------------------------------------------------------------
__global__ __launch_bounds__(256) void dwconv2(const __hip_bfloat16* __restrict__ xb,
                                               const float* __restrict__ dwk,
                                               __hip_bfloat16* __restrict__ A2) {
  int b = blockIdx.y;
  int wv = threadIdx.x >> 6, lane = threadIdx.x & 63;
  int c0 = lane * 6;
  float kw[6][9];
#pragma unroll
  for (int i = 0; i < 6; i++)
#pragma unroll
    for (int ki = 0; ki < 9; ki++) kw[i][ki] = dwk[(c0 + i) * 9 + ki];
  for (int it = 0; it < 8; it++) {
    int p = blockIdx.x * 32 + wv * 8 + it;
    int y = p >> 6, w = p & 63;
    size_t prow = (size_t)b * 4096 + p;
    float acc[6] = {};
#pragma unroll
    for (int dy = -1; dy <= 1; dy++) {
      int yy = y + dy;
      if (yy < 0 || yy >= 64) continue;  // wave-uniform
#pragma unroll
      for (int dx = -1; dx <= 1; dx++) {
        int ww = w + dx;
        if (ww < 0 || ww >= 64) continue;
        int ki = (dy + 1) * 3 + (dx + 1);
        const __hip_bfloat16* xp = xb + ((size_t)(b * 4096 + yy * 64 + ww)) * 384 + c0;
#pragma unroll
        for (int i = 0; i < 6; i++) acc[i] += __bfloat162float(xp[i]) * kw[i][ki];
      }
    }
    __hip_bfloat16 tb[6];
#pragma unroll
    for (int i = 0; i < 6; i++) tb[i] = __float2bfloat16(acc[i]);
    __hip_bfloat16* gp = A2 + prow * 512 + c0;
    *(unsigned int*)(gp) = *(unsigned int*)(tb);
    *(unsigned int*)(gp + 2) = *(unsigned int*)(tb + 2);
    *(unsigned int*)(gp + 4) = *(unsigned int*)(tb + 4);
  }
}

// ---------------------------------------------------------------------------
extern "C" void kernel_launch(void* const* d_in, const int* in_sizes, int n_in,
                              void* d_out, int out_size, void* d_ws, size_t ws_size,
                              hipStream_t stream) {
  (void)in_sizes; (void)n_in; (void)out_size; (void)ws_size;
  const float* x = (const float*)d_in[0];
  const float* wsal = (const float*)d_in[3];
  const float* bsal = (const float*)d_in[4];
  const float* seeds = (const float*)d_in[5];
  const float* w_q_agg = (const float*)d_in[6];
  const float* w_kv_agg = (const float*)d_in[7];
  const float* w_q_self = (const float*)d_in[8];
  const float* w_kv_self = (const float*)d_in[9];
  const float* w_q_bcast = (const float*)d_in[10];
  const float* w_kv_bcast = (const float*)d_in[11];
  const float* dwk = (const float*)d_in[12];
  const float* w_proj = (const float*)d_in[13];
  float* out = (float*)d_out;

  char* ws = (char*)d_ws;
  size_t off = 0;
  auto take = [&](size_t bytes) -> void* {
    void* p = ws + off;
    off += (bytes + 255) & ~(size_t)255;
    return p;
  };
  __hip_bfloat16* xb = (__hip_bfloat16*)take(50331648);      // bf16(x)
  __hip_bfloat16* vT = (__hip_bfloat16*)take(50331648);      // [16][384][4096] bf16
  float* logitsT = (float*)take(33554432);                   // [2048][4096] f32; -> pbuf
  __hip_bfloat16* PT = (__hip_bfloat16*)take(16777216);      // [2048][4096] bf16
  float* qseed = (float*)take(24576);
  float* sal = (float*)take(262144);
  float* anch1 = (float*)take(393216);
  float* anch2 = (float*)take(393216);
  float* q_self = (float*)take(393216);
  float* kv_self = (float*)take(786432);
  float* kv_b = (float*)take(786432);
  __hip_bfloat16* wvlT = (__hip_bfloat16*)take(393216);   // [512][384] bf16: v ++ Wl
  __hip_bfloat16* wpbT = (__hip_bfloat16*)take(1572864);  // [16][128][384] bf16
  __hip_bfloat16* bt2 = (__hip_bfloat16*)take(6291456);   // [16][384][512] bf16
  float* pbuf = logitsT;           // alias: logitsT dead after softmax_rows
  __hip_bfloat16* A2 = vT;         // alias: vT+pbuf dead after anch_fix2 (64 of 80 MB)

  // 1) xb + saliency
  prep<<<16384, 256, 0, stream>>>(x, wsal, bsal, xb, sal);
  // 2) build combined B: wvlT[0:384] = v-cols^T; wvlT[384:512] = Wl (needs qseed)
  anchor_proj2<<<dim3(24, 1), 256, 0, stream>>>(seeds, w_q_agg, qseed, 384, 384);
  wcast_tv<<<576, 256, 0, stream>>>(w_kv_agg, wvlT);
  fill_wl<<<192, 256, 0, stream>>>(w_kv_agg, qseed, wvlT);
  // 3) one pass over xb: vT (transposed V) + logitsT (transposed logits)
  gemm_vlog<<<dim3(4, 512), 256, 0, stream>>>(xb, wvlT, vT, logitsT, sal);
  // 4) softmax over keys; PV with split-K=8; reduce+seeds -> anchors1
  softmax_rows<<<2048, 256, 0, stream>>>(logitsT, PT);
  gemm_pv<<<dim3(3, 16, 8), 256, 0, stream>>>(PT, vT, pbuf);
  anch_fix2<<<384, 256, 0, stream>>>(pbuf, seeds, anch1);
  // 5) anchor self-attention -> anchors2
  anchor_proj2<<<dim3(24, 16), 256, 0, stream>>>(anch1, w_q_self, q_self, 384, 384);
  anchor_proj2<<<dim3(48, 16), 256, 0, stream>>>(anch1, w_kv_self, kv_self, 768, 0);
  self_attn<<<128, 256, 0, stream>>>(q_self, kv_self, anch1, anch2);
  // 6) kv_bcast = anchors2 @ w_kv_bcast (SCALE on k half)
  anchor_proj2<<<dim3(48, 16), 256, 0, stream>>>(anch2, w_kv_bcast, kv_b, 768, 384);
  // 7) per-batch folded weights
  fill_wpb<<<3072, 256, 0, stream>>>(w_q_bcast, kv_b, wpbT);
  fill_bt2<<<12288, 256, 0, stream>>>(w_proj, kv_b, bt2);
  // 8) A2[:,0:384] = dwconv(xb)  (vT/pbuf dead -> A2)
  dwconv2<<<dim3(128, 16), 256, 0, stream>>>(xb, dwk, A2);
  // 9) A2[:,384:512] = P = softmax(xb @ W_pbT_b)
  pgemm<<<dim3(1, 512), 256, 0, stream>>>(xb, wpbT, A2);
  // 10) out = A2 @ BT2_b   (K=512, f32 out)
  gemm_mfma<512, float, 12><<<dim3(3, 512), 256, 0, stream>>>(A2, bt2, out, 384, (size_t)384 * 512);
}

// Round 9
// 389.382 us; speedup vs baseline: 5.8368x; 1.0662x over previous
//
#include <hip/hip_runtime.h>
#include <hip/hip_bf16.h>

// Problem constants: B=16, N=4096, C=384, M=16, NH=8, HD=48, H=W=64
#define SCALE 0.14433756729740643f  // 48^-0.5

typedef __attribute__((ext_vector_type(8))) short bf16x8;
typedef __attribute__((ext_vector_type(4))) float f32x4;

template <typename T> __device__ inline T cvt_from_f(float v);
template <> __device__ inline float cvt_from_f<float>(float v) { return v; }
template <> __device__ inline __hip_bfloat16 cvt_from_f<__hip_bfloat16>(float v) { return __float2bfloat16(v); }

__device__ inline void gload16(const void* g, void* l) {
  __builtin_amdgcn_global_load_lds((const __attribute__((address_space(1))) void*)g,
                                   (__attribute__((address_space(3))) void*)l, 16, 0, 0);
}

// XCD-bijective swizzle (nwg must be %8==0): same-row-panel column blocks
// become dispatch-adjacent within one XCD chunk -> L2 panel reuse.
__device__ inline int xcd_flat(int nwg) {
  int flat = (blockIdx.z * gridDim.y + blockIdx.y) * gridDim.x + blockIdx.x;
  int per = nwg >> 3;
  return (flat & 7) * per + (flat >> 3);
}

// ---------------------------------------------------------------------------
// prep: xb = bf16(x); sal[row] = sigmoid(x·wsal + b). One wave per row.
// ---------------------------------------------------------------------------
__global__ __launch_bounds__(256) void prep(const float* __restrict__ x,
                                            const float* __restrict__ wsal,
                                            const float* __restrict__ bsal,
                                            __hip_bfloat16* __restrict__ xb,
                                            float* __restrict__ sal) {
  int wave = threadIdx.x >> 6, lane = threadIdx.x & 63;
  size_t row = (size_t)blockIdx.x * 4 + wave;
  const float* xr = x + row * 384;
  float xs[6];
  float part = 0.f;
#pragma unroll
  for (int j = 0; j < 6; j++) {
    int c = lane + 64 * j;
    xs[j] = xr[c];
    part += xs[j] * wsal[c];
  }
#pragma unroll
  for (int off = 32; off >= 1; off >>= 1) part += __shfl_xor(part, off);
  float s = 1.f / (1.f + __expf(-(part + bsal[0])));
#pragma unroll
  for (int j = 0; j < 6; j++) {
    int c = lane + 64 * j;
    xb[row * 384 + c] = __float2bfloat16(xs[j]);
  }
  if (lane == 0) sal[row] = s;
}

// ---------------------------------------------------------------------------
// wcast_tv: wvlT[n][k] = bf16(w_kv_agg[k][384+n])  (v-columns transposed)
// ---------------------------------------------------------------------------
__global__ void wcast_tv(const float* __restrict__ w, __hip_bfloat16* __restrict__ wt) {
  int idx = blockIdx.x * 256 + threadIdx.x;
  if (idx >= 384 * 384) return;
  int n = idx / 384, k = idx % 384;
  wt[idx] = __float2bfloat16(w[(size_t)k * 768 + 384 + n]);
}

// ---------------------------------------------------------------------------
// MFMA GEMM (final proj): out[M,Ncols] = A[M,K] @ BT_b[Ncols,K]^T.
// XCD-swizzled grid. 128x128 tile, BK=32, 4 waves.
// ---------------------------------------------------------------------------
template <int K, typename OT, int BSHIFT>
__global__ __launch_bounds__(256) void gemm_mfma(const __hip_bfloat16* __restrict__ A,
                                                 const __hip_bfloat16* __restrict__ BT,
                                                 OT* __restrict__ out, int Ncols,
                                                 size_t btBatchStride) {
  __shared__ __align__(16) __hip_bfloat16 Asl[128][32];
  __shared__ __align__(16) __hip_bfloat16 Bsl[128][32];
  int nf = xcd_flat(gridDim.x * gridDim.y);
  int bX = nf % gridDim.x, bY = nf / gridDim.x;
  int tid = threadIdx.x;
  int lane = tid & 63;
  int w = tid >> 6;
  int wr = w >> 1, wc = w & 1;
  int fr = lane & 15, fq = lane >> 4;
  int rowBase = bY * 128, colBase = bX * 128;
  const __hip_bfloat16* BTb = BT + (size_t)(rowBase >> BSHIFT) * btBatchStride;

  int r1 = tid >> 2, kc1 = tid & 3;
  int r2 = (tid + 256) >> 2;

  char* aB1 = (char*)Asl + (size_t)(w * 64) * 16;
  char* aB2 = (char*)Asl + (size_t)(256 + w * 64) * 16;
  char* bB1 = (char*)Bsl + (size_t)(w * 64) * 16;
  char* bB2 = (char*)Bsl + (size_t)(256 + w * 64) * 16;

  const __hip_bfloat16* a1 = A + (size_t)(rowBase + r1) * K + kc1 * 8;
  const __hip_bfloat16* a2 = A + (size_t)(rowBase + r2) * K + kc1 * 8;
  const __hip_bfloat16* b1 = BTb + (size_t)(colBase + r1) * K + kc1 * 8;
  const __hip_bfloat16* b2 = BTb + (size_t)(colBase + r2) * K + kc1 * 8;

  f32x4 acc[4][4] = {};

  for (int kk = 0; kk < K; kk += 32) {
    gload16(a1 + kk, aB1);
    gload16(a2 + kk, aB2);
    gload16(b1 + kk, bB1);
    gload16(b2 + kk, bB2);
    __syncthreads();
    bf16x8 af[4], bfv[4];
#pragma unroll
    for (int m = 0; m < 4; m++) af[m] = *(const bf16x8*)&Asl[wr * 64 + m * 16 + fr][fq * 8];
#pragma unroll
    for (int n = 0; n < 4; n++) bfv[n] = *(const bf16x8*)&Bsl[wc * 64 + n * 16 + fr][fq * 8];
#pragma unroll
    for (int m = 0; m < 4; m++)
#pragma unroll
      for (int n = 0; n < 4; n++)
        acc[m][n] = __builtin_amdgcn_mfma_f32_16x16x32_bf16(af[m], bfv[n], acc[m][n], 0, 0, 0);
    __syncthreads();
  }

#pragma unroll
  for (int m = 0; m < 4; m++) {
    int row0 = rowBase + wr * 64 + m * 16 + fq * 4;
#pragma unroll
    for (int n = 0; n < 4; n++) {
      int col = colBase + wc * 64 + n * 16 + fr;
      f32x4 v = acc[m][n];
#pragma unroll
      for (int r = 0; r < 4; r++) out[(size_t)(row0 + r) * Ncols + col] = cvt_from_f<OT>(v[r]);
    }
  }
}

// ---------------------------------------------------------------------------
// gemm_vlog: one pass over xb computes BOTH (XCD-swizzled grid (4,512))
//   x<3 : vT[b][c][n]  = sal·(xb @ wv)          (transposed bf16)
//   x==3: lgT[b*128+hm][n] = sal·(xb @ Wl^T)    (transposed f32)
// ---------------------------------------------------------------------------
__global__ __launch_bounds__(256) void gemm_vlog(const __hip_bfloat16* __restrict__ A,
                                                 const __hip_bfloat16* __restrict__ BT,
                                                 __hip_bfloat16* __restrict__ vT,
                                                 float* __restrict__ lgT,
                                                 const float* __restrict__ rowScale) {
  constexpr int K = 384;
  __shared__ __align__(16) __hip_bfloat16 Asl[128][32];
  __shared__ __align__(16) __hip_bfloat16 Bsl[128][32];
  int nf = xcd_flat(2048);
  int bX = nf & 3, bY = nf >> 2;
  int tid = threadIdx.x;
  int lane = tid & 63;
  int w = tid >> 6;
  int wr = w >> 1, wc = w & 1;
  int fr = lane & 15, fq = lane >> 4;
  int rowBase = bY * 128, colBase = bX * 128;

  int r1 = tid >> 2, kc1 = tid & 3;
  int r2 = (tid + 256) >> 2;

  char* aB1 = (char*)Asl + (size_t)(w * 64) * 16;
  char* aB2 = (char*)Asl + (size_t)(256 + w * 64) * 16;
  char* bB1 = (char*)Bsl + (size_t)(w * 64) * 16;
  char* bB2 = (char*)Bsl + (size_t)(256 + w * 64) * 16;

  const __hip_bfloat16* a1 = A + (size_t)(rowBase + r1) * K + kc1 * 8;
  const __hip_bfloat16* a2 = A + (size_t)(rowBase + r2) * K + kc1 * 8;
  const __hip_bfloat16* b1 = BT + (size_t)(colBase + r1) * K + kc1 * 8;
  const __hip_bfloat16* b2 = BT + (size_t)(colBase + r2) * K + kc1 * 8;

  f32x4 acc[4][4] = {};

  for (int kk = 0; kk < K; kk += 32) {
    gload16(a1 + kk, aB1);
    gload16(a2 + kk, aB2);
    gload16(b1 + kk, bB1);
    gload16(b2 + kk, bB2);
    __syncthreads();
    bf16x8 af[4], bfv[4];
#pragma unroll
    for (int m = 0; m < 4; m++) af[m] = *(const bf16x8*)&Asl[wr * 64 + m * 16 + fr][fq * 8];
#pragma unroll
    for (int n = 0; n < 4; n++) bfv[n] = *(const bf16x8*)&Bsl[wc * 64 + n * 16 + fr][fq * 8];
#pragma unroll
    for (int m = 0; m < 4; m++)
#pragma unroll
      for (int n = 0; n < 4; n++)
        acc[m][n] = __builtin_amdgcn_mfma_f32_16x16x32_bf16(af[m], bfv[n], acc[m][n], 0, 0, 0);
    __syncthreads();
  }

  float sv[4][4];
#pragma unroll
  for (int m = 0; m < 4; m++)
#pragma unroll
    for (int r = 0; r < 4; r++)
      sv[m][r] = rowScale[rowBase + wr * 64 + m * 16 + fq * 4 + r];

  if (bX < 3) {
    // v epilogue: transposed bf16 write
#pragma unroll
    for (int m = 0; m < 4; m++) {
      int row0 = rowBase + wr * 64 + m * 16 + fq * 4;
      int bb = row0 >> 12;
      int n0 = row0 & 4095;
#pragma unroll
      for (int n = 0; n < 4; n++) {
        int col = colBase + wc * 64 + n * 16 + fr;
        __hip_bfloat16 tb[4];
#pragma unroll
        for (int r = 0; r < 4; r++) tb[r] = __float2bfloat16(acc[m][n][r] * sv[m][r]);
        *(unsigned long long*)(vT + ((size_t)bb * 384 + col) * 4096 + n0) = *(unsigned long long*)tb;
      }
    }
  } else {
    // logits epilogue: transposed f32 write
#pragma unroll
    for (int m = 0; m < 4; m++) {
      int row0 = rowBase + wr * 64 + m * 16 + fq * 4;
      int bb = row0 >> 12;
      int n0 = row0 & 4095;
#pragma unroll
      for (int n = 0; n < 4; n++) {
        int col = wc * 64 + n * 16 + fr;  // 0..127 = hm
        float4 v;
        v.x = acc[m][n][0] * sv[m][0];
        v.y = acc[m][n][1] * sv[m][1];
        v.z = acc[m][n][2] * sv[m][2];
        v.w = acc[m][n][3] * sv[m][3];
        *(float4*)(lgT + ((size_t)bb * 128 + col) * 4096 + n0) = v;
      }
    }
  }
}

// ---------------------------------------------------------------------------
// gemm_pv: split-K PV, XCD-swizzled. pbuf[z][g][c] = PT[g, zslice] @ vT_b^T.
// Grid (3, 16, 8).
// ---------------------------------------------------------------------------
__global__ __launch_bounds__(256) void gemm_pv(const __hip_bfloat16* __restrict__ PT,
                                               const __hip_bfloat16* __restrict__ vT,
                                               float* __restrict__ pbuf) {
  __shared__ __align__(16) __hip_bfloat16 Asl[128][32];
  __shared__ __align__(16) __hip_bfloat16 Bsl[128][32];
  int nf = xcd_flat(384);
  int bX = nf % 3, bY = (nf / 3) & 15, kz = nf / 48;
  int tid = threadIdx.x;
  int lane = tid & 63;
  int w = tid >> 6;
  int wr = w >> 1, wc = w & 1;
  int fr = lane & 15, fq = lane >> 4;
  int rowBase = bY * 128, colBase = bX * 128;
  const __hip_bfloat16* BTb = vT + (size_t)bY * 384 * 4096;

  int r1 = tid >> 2, kc1 = tid & 3;
  int r2 = (tid + 256) >> 2;

  char* aB1 = (char*)Asl + (size_t)(w * 64) * 16;
  char* aB2 = (char*)Asl + (size_t)(256 + w * 64) * 16;
  char* bB1 = (char*)Bsl + (size_t)(w * 64) * 16;
  char* bB2 = (char*)Bsl + (size_t)(256 + w * 64) * 16;

  const __hip_bfloat16* a1 = PT + (size_t)(rowBase + r1) * 4096 + kz * 512 + kc1 * 8;
  const __hip_bfloat16* a2 = PT + (size_t)(rowBase + r2) * 4096 + kz * 512 + kc1 * 8;
  const __hip_bfloat16* b1 = BTb + (size_t)(colBase + r1) * 4096 + kz * 512 + kc1 * 8;
  const __hip_bfloat16* b2 = BTb + (size_t)(colBase + r2) * 4096 + kz * 512 + kc1 * 8;

  f32x4 acc[4][4] = {};

  for (int kk = 0; kk < 512; kk += 32) {
    gload16(a1 + kk, aB1);
    gload16(a2 + kk, aB2);
    gload16(b1 + kk, bB1);
    gload16(b2 + kk, bB2);
    __syncthreads();
    bf16x8 af[4], bfv[4];
#pragma unroll
    for (int m = 0; m < 4; m++) af[m] = *(const bf16x8*)&Asl[wr * 64 + m * 16 + fr][fq * 8];
#pragma unroll
    for (int n = 0; n < 4; n++) bfv[n] = *(const bf16x8*)&Bsl[wc * 64 + n * 16 + fr][fq * 8];
#pragma unroll
    for (int m = 0; m < 4; m++)
#pragma unroll
      for (int n = 0; n < 4; n++)
        acc[m][n] = __builtin_amdgcn_mfma_f32_16x16x32_bf16(af[m], bfv[n], acc[m][n], 0, 0, 0);
    __syncthreads();
  }

  float* outz = pbuf + (size_t)kz * 786432;
#pragma unroll
  for (int m = 0; m < 4; m++) {
    int row0 = rowBase + wr * 64 + m * 16 + fq * 4;
#pragma unroll
    for (int n = 0; n < 4; n++) {
      int col = colBase + wc * 64 + n * 16 + fr;
      f32x4 v = acc[m][n];
#pragma unroll
      for (int r = 0; r < 4; r++) outz[(size_t)(row0 + r) * 384 + col] = v[r];
    }
  }
}

// ---------------------------------------------------------------------------
// anch_fix2: anch1[b][m][c] = seeds[m][c] + sum_z pbuf[z][b*128+h(c)*16+m][c].
// ---------------------------------------------------------------------------
__global__ void anch_fix2(const float* __restrict__ pbuf, const float* __restrict__ seeds,
                          float* __restrict__ anch1) {
  int idx = blockIdx.x * 256 + threadIdx.x;  // 98304
  int b = idx / 6144;
  int rem = idx - b * 6144;
  int m = rem / 384, c = rem - m * 384;
  int g = b * 128 + (c / 48) * 16 + m;
  const float* p = pbuf + (size_t)g * 384 + c;
  float s = 0.f;
#pragma unroll
  for (int z = 0; z < 8; z++) s += p[(size_t)z * 786432];
  anch1[idx] = seeds[rem] + s;
}

// ---------------------------------------------------------------------------
// softmax_rows: PT[g][n] = softmax_n(lgT[g][n]), bf16 out. Block per row g.
// ---------------------------------------------------------------------------
__global__ __launch_bounds__(256) void softmax_rows(const float* __restrict__ lgT,
                                                    __hip_bfloat16* __restrict__ PT) {
  int g = blockIdx.x;
  const float* row = lgT + (size_t)g * 4096;
  int tid = threadIdx.x, wv = tid >> 6, lane = tid & 63;
  __shared__ float redm[4], reds[4];
  float v[16];
  const float4* rp = (const float4*)(row + tid * 16);
#pragma unroll
  for (int i = 0; i < 4; i++) {
    float4 q = rp[i];
    v[i * 4] = q.x; v[i * 4 + 1] = q.y; v[i * 4 + 2] = q.z; v[i * 4 + 3] = q.w;
  }
  float mx = v[0];
#pragma unroll
  for (int i = 1; i < 16; i++) mx = fmaxf(mx, v[i]);
#pragma unroll
  for (int off = 1; off < 64; off <<= 1) mx = fmaxf(mx, __shfl_xor(mx, off));
  if (lane == 0) redm[wv] = mx;
  __syncthreads();
  mx = fmaxf(fmaxf(redm[0], redm[1]), fmaxf(redm[2], redm[3]));
  float s = 0.f;
#pragma unroll
  for (int i = 0; i < 16; i++) {
    v[i] = __expf(v[i] - mx);
    s += v[i];
  }
#pragma unroll
  for (int off = 1; off < 64; off <<= 1) s += __shfl_xor(s, off);
  if (lane == 0) reds[wv] = s;
  __syncthreads();
  s = (reds[0] + reds[1]) + (reds[2] + reds[3]);
  float inv = 1.f / s;
  __hip_bfloat16 tb[16];
#pragma unroll
  for (int i = 0; i < 16; i++) tb[i] = __float2bfloat16(v[i] * inv);
  __hip_bfloat16* op = PT + (size_t)g * 4096 + tid * 16;
  *(ulonglong2*)op = *(ulonglong2*)tb;
  *(ulonglong2*)(op + 8) = *(ulonglong2*)(tb + 8);
}

// ---------------------------------------------------------------------------
// fill_wl: wvlT[384+hm][ci] = sum_d w_kv_agg[ci][h*48+d] * qseed[m][h*48+d].
// ---------------------------------------------------------------------------
__global__ void fill_wl(const float* __restrict__ wkv, const float* __restrict__ qseed,
                        __hip_bfloat16* __restrict__ wvlT) {
  int idx = blockIdx.x * 256 + threadIdx.x;  // 49152
  int hm = idx / 384, ci = idx - hm * 384;
  int h = hm >> 4, m = hm & 15;
  const float* wp = wkv + (size_t)ci * 768 + h * 48;
  const float* qp = qseed + m * 384 + h * 48;
  float acc = 0.f;
#pragma unroll
  for (int d = 0; d < 48; d++) acc += wp[d] * qp[d];
  wvlT[384 * 384 + idx] = __float2bfloat16(acc);
}

// ---------------------------------------------------------------------------
// pgemm: P = softmax_per_head(xb @ W_pbT_b^T), written bf16 to A2[:,384+hm].
// ---------------------------------------------------------------------------
__global__ __launch_bounds__(256) void pgemm(const __hip_bfloat16* __restrict__ A,
                                             const __hip_bfloat16* __restrict__ wpbT,
                                             __hip_bfloat16* __restrict__ A2) {
  constexpr int K = 384;
  __shared__ __align__(16) __hip_bfloat16 Asl[128][32];
  __shared__ __align__(16) __hip_bfloat16 Bsl[128][32];
  int tid = threadIdx.x;
  int lane = tid & 63;
  int w = tid >> 6;
  int wr = w >> 1, wc = w & 1;
  int fr = lane & 15, fq = lane >> 4;
  int rowBase = blockIdx.y * 128;
  const __hip_bfloat16* BTb = wpbT + (size_t)(rowBase >> 12) * (128 * 384);

  int r1 = tid >> 2, kc1 = tid & 3;
  int r2 = (tid + 256) >> 2;

  char* aB1 = (char*)Asl + (size_t)(w * 64) * 16;
  char* aB2 = (char*)Asl + (size_t)(256 + w * 64) * 16;
  char* bB1 = (char*)Bsl + (size_t)(w * 64) * 16;
  char* bB2 = (char*)Bsl + (size_t)(256 + w * 64) * 16;

  const __hip_bfloat16* a1 = A + (size_t)(rowBase + r1) * K + kc1 * 8;
  const __hip_bfloat16* a2 = A + (size_t)(rowBase + r2) * K + kc1 * 8;
  const __hip_bfloat16* b1 = BTb + (size_t)r1 * K + kc1 * 8;
  const __hip_bfloat16* b2 = BTb + (size_t)r2 * K + kc1 * 8;

  f32x4 acc[4][4] = {};

  for (int kk = 0; kk < K; kk += 32) {
    gload16(a1 + kk, aB1);
    gload16(a2 + kk, aB2);
    gload16(b1 + kk, bB1);
    gload16(b2 + kk, bB2);
    __syncthreads();
    bf16x8 af[4], bfv[4];
#pragma unroll
    for (int m = 0; m < 4; m++) af[m] = *(const bf16x8*)&Asl[wr * 64 + m * 16 + fr][fq * 8];
#pragma unroll
    for (int n = 0; n < 4; n++) bfv[n] = *(const bf16x8*)&Bsl[wc * 64 + n * 16 + fr][fq * 8];
#pragma unroll
    for (int m = 0; m < 4; m++)
#pragma unroll
      for (int n = 0; n < 4; n++)
        acc[m][n] = __builtin_amdgcn_mfma_f32_16x16x32_bf16(af[m], bfv[n], acc[m][n], 0, 0, 0);
    __syncthreads();
  }

  // epilogue: per (row, head) softmax over the 16-lane fr group.
#pragma unroll
  for (int m = 0; m < 4; m++) {
    int row0 = rowBase + wr * 64 + m * 16 + fq * 4;
#pragma unroll
    for (int n = 0; n < 4; n++) {
      int col = wc * 64 + n * 16 + fr;
      f32x4 v = acc[m][n];
      f32x4 mx = v;
#pragma unroll
      for (int off = 1; off < 16; off <<= 1)
#pragma unroll
        for (int r = 0; r < 4; r++) mx[r] = fmaxf(mx[r], __shfl_xor(mx[r], off));
      f32x4 e;
#pragma unroll
      for (int r = 0; r < 4; r++) e[r] = __expf(v[r] - mx[r]);
      f32x4 s = e;
#pragma unroll
      for (int off = 1; off < 16; off <<= 1)
#pragma unroll
        for (int r = 0; r < 4; r++) s[r] += __shfl_xor(s[r], off);
#pragma unroll
      for (int r = 0; r < 4; r++)
        A2[(size_t)(row0 + r) * 512 + 384 + col] = __float2bfloat16(e[r] / s[r]);
    }
  }
}

// ---------------------------------------------------------------------------
// anchor_proj2: out[b,16,wstride] = A[b,16,384] @ W[384,wstride].
// ---------------------------------------------------------------------------
__global__ __launch_bounds__(256) void anchor_proj2(const float* __restrict__ A,
                                                    const float* __restrict__ W,
                                                    float* __restrict__ out, int wstride,
                                                    int scaleCols) {
  int cs = blockIdx.x * 16;
  int b = blockIdx.y;
  __shared__ float a1[16][385];
  int tid = threadIdx.x;
  for (int idx = tid; idx < 6144; idx += 256) a1[idx / 384][idx % 384] = A[b * 6144 + idx];
  __syncthreads();
  int m = tid >> 4, cc = tid & 15;
  int col = cs + cc;
  const float* wp = W + col;
  float acc0 = 0.f, acc1 = 0.f, acc2 = 0.f, acc3 = 0.f;
#pragma unroll 4
  for (int k = 0; k < 384; k += 4) {
    acc0 += a1[m][k] * wp[(size_t)k * wstride];
    acc1 += a1[m][k + 1] * wp[(size_t)(k + 1) * wstride];
    acc2 += a1[m][k + 2] * wp[(size_t)(k + 2) * wstride];
    acc3 += a1[m][k + 3] * wp[(size_t)(k + 3) * wstride];
  }
  float acc = (acc0 + acc1) + (acc2 + acc3);
  if (col < scaleCols) acc *= SCALE;
  out[((size_t)b * 16 + m) * wstride + col] = acc;
}

// ---------------------------------------------------------------------------
// Self attention on anchors (16x16, per (b,h)); anchors2 = anchors1 + out.
// ---------------------------------------------------------------------------
__global__ void self_attn(const float* __restrict__ qsf, const float* __restrict__ kvs,
                          const float* __restrict__ anch1, float* __restrict__ anch2) {
  int h = blockIdx.x & 7, b = blockIdx.x >> 3;
  __shared__ float qs[16][48], ks[16][48], vs[16][48], p[16][17];
  int tid = threadIdx.x;
  for (int idx = tid; idx < 768; idx += 256) {
    int m = idx / 48, d = idx % 48;
    qs[m][d] = qsf[(b * 16 + m) * 384 + h * 48 + d];
    ks[m][d] = kvs[(b * 16 + m) * 768 + h * 48 + d];
    vs[m][d] = kvs[(b * 16 + m) * 768 + 384 + h * 48 + d];
  }
  __syncthreads();
  {
    int mq = tid >> 4, mk = tid & 15;
    float acc = 0.f;
    for (int d = 0; d < 48; d++) acc += qs[mq][d] * ks[mk][d];
    p[mq][mk] = acc;
  }
  __syncthreads();
  if (tid < 16) {
    float mx = -1e30f;
    for (int mk = 0; mk < 16; mk++) mx = fmaxf(mx, p[tid][mk]);
    float sum = 0.f;
    for (int mk = 0; mk < 16; mk++) {
      float e = __expf(p[tid][mk] - mx);
      p[tid][mk] = e;
      sum += e;
    }
    float inv = 1.f / sum;
    for (int mk = 0; mk < 16; mk++) p[tid][mk] *= inv;
  }
  __syncthreads();
  for (int idx = tid; idx < 768; idx += 256) {
    int m = idx / 48, d = idx % 48;
    float acc = 0.f;
    for (int mk = 0; mk < 16; mk++) acc += p[m][mk] * vs[mk][d];
    int c = h * 48 + d;
    anch2[(b * 16 + m) * 384 + c] = anch1[(b * 16 + m) * 384 + c] + acc;
  }
}

// ---------------------------------------------------------------------------
// fill_wpb: W_pbT[b][hm][k] = sum_d w_q_bcast[k][h*48+d] * k_b[b][m][h*48+d].
// ---------------------------------------------------------------------------
__global__ void fill_wpb(const float* __restrict__ wq, const float* __restrict__ kvb,
                         __hip_bfloat16* __restrict__ wpbT) {
  int idx = blockIdx.x * 256 + threadIdx.x;  // 786432
  int b = idx / 49152;
  int rem = idx - b * 49152;
  int hm = rem / 384, k = rem - hm * 384;
  int h = hm >> 4, m = hm & 15;
  const float* kp = kvb + ((size_t)(b * 16 + m)) * 768 + h * 48;
  const float* wp = wq + (size_t)k * 384 + h * 48;
  float acc = 0.f;
#pragma unroll
  for (int d = 0; d < 48; d++) acc += wp[d] * kp[d];
  wpbT[idx] = __float2bfloat16(acc);
}

// ---------------------------------------------------------------------------
// fill_bt2: BT2[b][cp][k2]:  k2<384 -> w_proj[k2][cp]
//                            k2>=384 -> sum_d v_b[b][m][h*48+d]*w_proj[h*48+d][cp]
// ---------------------------------------------------------------------------
__global__ void fill_bt2(const float* __restrict__ wproj, const float* __restrict__ kvb,
                         __hip_bfloat16* __restrict__ bt2) {
  int idx = blockIdx.x * 256 + threadIdx.x;  // 3145728
  int b = idx / 196608;
  int rem = idx - b * 196608;
  int cp = rem / 512, k2 = rem - cp * 512;
  float v;
  if (k2 < 384) {
    v = wproj[(size_t)k2 * 384 + cp];
  } else {
    int hm = k2 - 384, h = hm >> 4, m = hm & 15;
    const float* vp = kvb + ((size_t)(b * 16 + m)) * 768 + 384 + h * 48;
    const float* wp2 = wproj + (size_t)(h * 48) * 384 + cp;
    v = 0.f;
#pragma unroll
    for (int d = 0; d < 48; d++) v += vp[d] * wp2[(size_t)d * 384];
  }
  bt2[idx] = __float2bfloat16(v);
}

// ---------------------------------------------------------------------------
// dwconv2: depthwise 3x3 conv, no LDS/no syncs. Writes A2[:,0:384] (stride 512).
// ---------------------------------------------------------------------------
__global__ __launch_bounds__(256) void dwconv2(const __hip_bfloat16* __restrict__ xb,
                                               const float* __restrict__ dwk,
                                               __hip_bfloat16* __restrict__ A2) {
  int b = blockIdx.y;
  int wv = threadIdx.x >> 6, lane = threadIdx.x & 63;
  int c0 = lane * 6;
  float kw[6][9];
#pragma unroll
  for (int i = 0; i < 6; i++)
#pragma unroll
    for (int ki = 0; ki < 9; ki++) kw[i][ki] = dwk[(c0 + i) * 9 + ki];
  for (int it = 0; it < 8; it++) {
    int p = blockIdx.x * 32 + wv * 8 + it;
    int y = p >> 6, w = p & 63;
    size_t prow = (size_t)b * 4096 + p;
    float acc[6] = {};
#pragma unroll
    for (int dy = -1; dy <= 1; dy++) {
      int yy = y + dy;
      if (yy < 0 || yy >= 64) continue;  // wave-uniform
#pragma unroll
      for (int dx = -1; dx <= 1; dx++) {
        int ww = w + dx;
        if (ww < 0 || ww >= 64) continue;
        int ki = (dy + 1) * 3 + (dx + 1);
        const __hip_bfloat16* xp = xb + ((size_t)(b * 4096 + yy * 64 + ww)) * 384 + c0;
#pragma unroll
        for (int i = 0; i < 6; i++) acc[i] += __bfloat162float(xp[i]) * kw[i][ki];
      }
    }
    __hip_bfloat16 tb[6];
#pragma unroll
    for (int i = 0; i < 6; i++) tb[i] = __float2bfloat16(acc[i]);
    __hip_bfloat16* gp = A2 + prow * 512 + c0;
    *(unsigned int*)(gp) = *(unsigned int*)(tb);
    *(unsigned int*)(gp + 2) = *(unsigned int*)(tb + 2);
    *(unsigned int*)(gp + 4) = *(unsigned int*)(tb + 4);
  }
}

// ---------------------------------------------------------------------------
extern "C" void kernel_launch(void* const* d_in, const int* in_sizes, int n_in,
                              void* d_out, int out_size, void* d_ws, size_t ws_size,
                              hipStream_t stream) {
  (void)in_sizes; (void)n_in; (void)out_size; (void)ws_size;
  const float* x = (const float*)d_in[0];
  const float* wsal = (const float*)d_in[3];
  const float* bsal = (const float*)d_in[4];
  const float* seeds = (const float*)d_in[5];
  const float* w_q_agg = (const float*)d_in[6];
  const float* w_kv_agg = (const float*)d_in[7];
  const float* w_q_self = (const float*)d_in[8];
  const float* w_kv_self = (const float*)d_in[9];
  const float* w_q_bcast = (const float*)d_in[10];
  const float* w_kv_bcast = (const float*)d_in[11];
  const float* dwk = (const float*)d_in[12];
  const float* w_proj = (const float*)d_in[13];
  float* out = (float*)d_out;

  char* ws = (char*)d_ws;
  size_t off = 0;
  auto take = [&](size_t bytes) -> void* {
    void* p = ws + off;
    off += (bytes + 255) & ~(size_t)255;
    return p;
  };
  __hip_bfloat16* xb = (__hip_bfloat16*)take(50331648);      // bf16(x)
  __hip_bfloat16* vT = (__hip_bfloat16*)take(50331648);      // [16][384][4096] bf16
  float* logitsT = (float*)take(33554432);                   // [2048][4096] f32; -> pbuf
  __hip_bfloat16* PT = (__hip_bfloat16*)take(16777216);      // [2048][4096] bf16
  float* qseed = (float*)take(24576);
  float* sal = (float*)take(262144);
  float* anch1 = (float*)take(393216);
  float* anch2 = (float*)take(393216);
  float* q_self = (float*)take(393216);
  float* kv_self = (float*)take(786432);
  float* kv_b = (float*)take(786432);
  __hip_bfloat16* wvlT = (__hip_bfloat16*)take(393216);   // [512][384] bf16: v ++ Wl
  __hip_bfloat16* wpbT = (__hip_bfloat16*)take(1572864);  // [16][128][384] bf16
  __hip_bfloat16* bt2 = (__hip_bfloat16*)take(6291456);   // [16][384][512] bf16
  float* pbuf = logitsT;           // alias: logitsT dead after softmax_rows
  __hip_bfloat16* A2 = vT;         // alias: vT+pbuf dead after anch_fix2 (64 of 80 MB)

  // 1) xb + saliency
  prep<<<16384, 256, 0, stream>>>(x, wsal, bsal, xb, sal);
  // 2) build combined B: wvlT[0:384] = v-cols^T; wvlT[384:512] = Wl (needs qseed)
  anchor_proj2<<<dim3(24, 1), 256, 0, stream>>>(seeds, w_q_agg, qseed, 384, 384);
  wcast_tv<<<576, 256, 0, stream>>>(w_kv_agg, wvlT);
  fill_wl<<<192, 256, 0, stream>>>(w_kv_agg, qseed, wvlT);
  // 3) one pass over xb: vT (transposed V) + logitsT (transposed logits)
  gemm_vlog<<<dim3(4, 512), 256, 0, stream>>>(xb, wvlT, vT, logitsT, sal);
  // 4) softmax over keys; PV with split-K=8; reduce+seeds -> anchors1
  softmax_rows<<<2048, 256, 0, stream>>>(logitsT, PT);
  gemm_pv<<<dim3(3, 16, 8), 256, 0, stream>>>(PT, vT, pbuf);
  anch_fix2<<<384, 256, 0, stream>>>(pbuf, seeds, anch1);
  // 5) anchor self-attention -> anchors2
  anchor_proj2<<<dim3(24, 16), 256, 0, stream>>>(anch1, w_q_self, q_self, 384, 384);
  anchor_proj2<<<dim3(48, 16), 256, 0, stream>>>(anch1, w_kv_self, kv_self, 768, 0);
  self_attn<<<128, 256, 0, stream>>>(q_self, kv_self, anch1, anch2);
  // 6) kv_bcast = anchors2 @ w_kv_bcast (SCALE on k half)
  anchor_proj2<<<dim3(48, 16), 256, 0, stream>>>(anch2, w_kv_bcast, kv_b, 768, 384);
  // 7) per-batch folded weights
  fill_wpb<<<3072, 256, 0, stream>>>(w_q_bcast, kv_b, wpbT);
  fill_bt2<<<12288, 256, 0, stream>>>(w_proj, kv_b, bt2);
  // 8) A2[:,0:384] = dwconv(xb)  (vT/pbuf dead -> A2)
  dwconv2<<<dim3(128, 16), 256, 0, stream>>>(xb, dwk, A2);
  // 9) A2[:,384:512] = P = softmax(xb @ W_pbT_b)
  pgemm<<<dim3(1, 512), 256, 0, stream>>>(xb, wpbT, A2);
  // 10) out = A2 @ BT2_b   (K=512, f32 out)
  gemm_mfma<512, float, 12><<<dim3(3, 512), 256, 0, stream>>>(A2, bt2, out, 384, (size_t)384 * 512);
}

// Round 10
// 372.975 us; speedup vs baseline: 6.0935x; 1.0440x over previous
//
#include <hip/hip_runtime.h>
#include <hip/hip_bf16.h>

// Problem constants: B=16, N=4096, C=384, M=16, NH=8, HD=48, H=W=64
#define SCALE 0.14433756729740643f  // 48^-0.5

typedef __attribute__((ext_vector_type(8))) short bf16x8;
typedef __attribute__((ext_vector_type(4))) float f32x4;

template <typename T> __device__ inline T cvt_from_f(float v);
template <> __device__ inline float cvt_from_f<float>(float v) { return v; }
template <> __device__ inline __hip_bfloat16 cvt_from_f<__hip_bfloat16>(float v) { return __float2bfloat16(v); }

__device__ inline void gload16(const void* g, void* l) {
  __builtin_amdgcn_global_load_lds((const __attribute__((address_space(1))) void*)g,
                                   (__attribute__((address_space(3))) void*)l, 16, 0, 0);
}

// XCD-bijective swizzle (nwg must be %8==0): same-row-panel column blocks
// become dispatch-adjacent within one XCD chunk -> L2 panel reuse.
__device__ inline int xcd_flat(int nwg) {
  int flat = (blockIdx.z * gridDim.y + blockIdx.y) * gridDim.x + blockIdx.x;
  int per = nwg >> 3;
  return (flat & 7) * per + (flat >> 3);
}

// ---------------------------------------------------------------------------
// prep: xb = bf16(x); sal[row] = sigmoid(x·wsal + b). One wave per row.
// ---------------------------------------------------------------------------
__global__ __launch_bounds__(256) void prep(const float* __restrict__ x,
                                            const float* __restrict__ wsal,
                                            const float* __restrict__ bsal,
                                            __hip_bfloat16* __restrict__ xb,
                                            float* __restrict__ sal) {
  int wave = threadIdx.x >> 6, lane = threadIdx.x & 63;
  size_t row = (size_t)blockIdx.x * 4 + wave;
  const float* xr = x + row * 384;
  float xs[6];
  float part = 0.f;
#pragma unroll
  for (int j = 0; j < 6; j++) {
    int c = lane + 64 * j;
    xs[j] = xr[c];
    part += xs[j] * wsal[c];
  }
#pragma unroll
  for (int off = 32; off >= 1; off >>= 1) part += __shfl_xor(part, off);
  float s = 1.f / (1.f + __expf(-(part + bsal[0])));
#pragma unroll
  for (int j = 0; j < 6; j++) {
    int c = lane + 64 * j;
    xb[row * 384 + c] = __float2bfloat16(xs[j]);
  }
  if (lane == 0) sal[row] = s;
}

// ---------------------------------------------------------------------------
// wcast_tv: wvlT[n][k] = bf16(w_kv_agg[k][384+n])  (v-columns transposed)
// ---------------------------------------------------------------------------
__global__ void wcast_tv(const float* __restrict__ w, __hip_bfloat16* __restrict__ wt) {
  int idx = blockIdx.x * 256 + threadIdx.x;
  if (idx >= 384 * 384) return;
  int n = idx / 384, k = idx % 384;
  wt[idx] = __float2bfloat16(w[(size_t)k * 768 + 384 + n]);
}

// ---------------------------------------------------------------------------
// MFMA GEMM (final proj): out[M,Ncols] = A[M,K] @ BT_b[Ncols,K]^T.
// XCD-swizzled grid. 128x128 tile, BK=32, 4 waves.
// ---------------------------------------------------------------------------
template <int K, typename OT, int BSHIFT>
__global__ __launch_bounds__(256) void gemm_mfma(const __hip_bfloat16* __restrict__ A,
                                                 const __hip_bfloat16* __restrict__ BT,
                                                 OT* __restrict__ out, int Ncols,
                                                 size_t btBatchStride) {
  __shared__ __align__(16) __hip_bfloat16 Asl[128][32];
  __shared__ __align__(16) __hip_bfloat16 Bsl[128][32];
  int nf = xcd_flat(gridDim.x * gridDim.y);
  int bX = nf % gridDim.x, bY = nf / gridDim.x;
  int tid = threadIdx.x;
  int lane = tid & 63;
  int w = tid >> 6;
  int wr = w >> 1, wc = w & 1;
  int fr = lane & 15, fq = lane >> 4;
  int rowBase = bY * 128, colBase = bX * 128;
  const __hip_bfloat16* BTb = BT + (size_t)(rowBase >> BSHIFT) * btBatchStride;

  int r1 = tid >> 2, kc1 = tid & 3;
  int r2 = (tid + 256) >> 2;

  char* aB1 = (char*)Asl + (size_t)(w * 64) * 16;
  char* aB2 = (char*)Asl + (size_t)(256 + w * 64) * 16;
  char* bB1 = (char*)Bsl + (size_t)(w * 64) * 16;
  char* bB2 = (char*)Bsl + (size_t)(256 + w * 64) * 16;

  const __hip_bfloat16* a1 = A + (size_t)(rowBase + r1) * K + kc1 * 8;
  const __hip_bfloat16* a2 = A + (size_t)(rowBase + r2) * K + kc1 * 8;
  const __hip_bfloat16* b1 = BTb + (size_t)(colBase + r1) * K + kc1 * 8;
  const __hip_bfloat16* b2 = BTb + (size_t)(colBase + r2) * K + kc1 * 8;

  f32x4 acc[4][4] = {};

  for (int kk = 0; kk < K; kk += 32) {
    gload16(a1 + kk, aB1);
    gload16(a2 + kk, aB2);
    gload16(b1 + kk, bB1);
    gload16(b2 + kk, bB2);
    __syncthreads();
    bf16x8 af[4], bfv[4];
#pragma unroll
    for (int m = 0; m < 4; m++) af[m] = *(const bf16x8*)&Asl[wr * 64 + m * 16 + fr][fq * 8];
#pragma unroll
    for (int n = 0; n < 4; n++) bfv[n] = *(const bf16x8*)&Bsl[wc * 64 + n * 16 + fr][fq * 8];
#pragma unroll
    for (int m = 0; m < 4; m++)
#pragma unroll
      for (int n = 0; n < 4; n++)
        acc[m][n] = __builtin_amdgcn_mfma_f32_16x16x32_bf16(af[m], bfv[n], acc[m][n], 0, 0, 0);
    __syncthreads();
  }

#pragma unroll
  for (int m = 0; m < 4; m++) {
    int row0 = rowBase + wr * 64 + m * 16 + fq * 4;
#pragma unroll
    for (int n = 0; n < 4; n++) {
      int col = colBase + wc * 64 + n * 16 + fr;
      f32x4 v = acc[m][n];
#pragma unroll
      for (int r = 0; r < 4; r++) out[(size_t)(row0 + r) * Ncols + col] = cvt_from_f<OT>(v[r]);
    }
  }
}

// ---------------------------------------------------------------------------
// gemm_vlog: one pass over xb computes BOTH (XCD-swizzled grid (4,512))
//   x<3 : vT[b][c][n]  = sal·(xb @ wv)          (transposed bf16)
//   x==3: lgT[b*128+hm][n] = sal·(xb @ Wl^T)    (transposed bf16)
// ---------------------------------------------------------------------------
__global__ __launch_bounds__(256) void gemm_vlog(const __hip_bfloat16* __restrict__ A,
                                                 const __hip_bfloat16* __restrict__ BT,
                                                 __hip_bfloat16* __restrict__ vT,
                                                 __hip_bfloat16* __restrict__ lgT,
                                                 const float* __restrict__ rowScale) {
  constexpr int K = 384;
  __shared__ __align__(16) __hip_bfloat16 Asl[128][32];
  __shared__ __align__(16) __hip_bfloat16 Bsl[128][32];
  int nf = xcd_flat(2048);
  int bX = nf & 3, bY = nf >> 2;
  int tid = threadIdx.x;
  int lane = tid & 63;
  int w = tid >> 6;
  int wr = w >> 1, wc = w & 1;
  int fr = lane & 15, fq = lane >> 4;
  int rowBase = bY * 128, colBase = bX * 128;

  int r1 = tid >> 2, kc1 = tid & 3;
  int r2 = (tid + 256) >> 2;

  char* aB1 = (char*)Asl + (size_t)(w * 64) * 16;
  char* aB2 = (char*)Asl + (size_t)(256 + w * 64) * 16;
  char* bB1 = (char*)Bsl + (size_t)(w * 64) * 16;
  char* bB2 = (char*)Bsl + (size_t)(256 + w * 64) * 16;

  const __hip_bfloat16* a1 = A + (size_t)(rowBase + r1) * K + kc1 * 8;
  const __hip_bfloat16* a2 = A + (size_t)(rowBase + r2) * K + kc1 * 8;
  const __hip_bfloat16* b1 = BT + (size_t)(colBase + r1) * K + kc1 * 8;
  const __hip_bfloat16* b2 = BT + (size_t)(colBase + r2) * K + kc1 * 8;

  f32x4 acc[4][4] = {};

  for (int kk = 0; kk < K; kk += 32) {
    gload16(a1 + kk, aB1);
    gload16(a2 + kk, aB2);
    gload16(b1 + kk, bB1);
    gload16(b2 + kk, bB2);
    __syncthreads();
    bf16x8 af[4], bfv[4];
#pragma unroll
    for (int m = 0; m < 4; m++) af[m] = *(const bf16x8*)&Asl[wr * 64 + m * 16 + fr][fq * 8];
#pragma unroll
    for (int n = 0; n < 4; n++) bfv[n] = *(const bf16x8*)&Bsl[wc * 64 + n * 16 + fr][fq * 8];
#pragma unroll
    for (int m = 0; m < 4; m++)
#pragma unroll
      for (int n = 0; n < 4; n++)
        acc[m][n] = __builtin_amdgcn_mfma_f32_16x16x32_bf16(af[m], bfv[n], acc[m][n], 0, 0, 0);
    __syncthreads();
  }

  float sv[4][4];
#pragma unroll
  for (int m = 0; m < 4; m++)
#pragma unroll
    for (int r = 0; r < 4; r++)
      sv[m][r] = rowScale[rowBase + wr * 64 + m * 16 + fq * 4 + r];

  if (bX < 3) {
    // v epilogue: transposed bf16 write
#pragma unroll
    for (int m = 0; m < 4; m++) {
      int row0 = rowBase + wr * 64 + m * 16 + fq * 4;
      int bb = row0 >> 12;
      int n0 = row0 & 4095;
#pragma unroll
      for (int n = 0; n < 4; n++) {
        int col = colBase + wc * 64 + n * 16 + fr;
        __hip_bfloat16 tb[4];
#pragma unroll
        for (int r = 0; r < 4; r++) tb[r] = __float2bfloat16(acc[m][n][r] * sv[m][r]);
        *(unsigned long long*)(vT + ((size_t)bb * 384 + col) * 4096 + n0) = *(unsigned long long*)tb;
      }
    }
  } else {
    // logits epilogue: transposed bf16 write
#pragma unroll
    for (int m = 0; m < 4; m++) {
      int row0 = rowBase + wr * 64 + m * 16 + fq * 4;
      int bb = row0 >> 12;
      int n0 = row0 & 4095;
#pragma unroll
      for (int n = 0; n < 4; n++) {
        int col = wc * 64 + n * 16 + fr;  // 0..127 = hm
        __hip_bfloat16 tb[4];
#pragma unroll
        for (int r = 0; r < 4; r++) tb[r] = __float2bfloat16(acc[m][n][r] * sv[m][r]);
        *(unsigned long long*)(lgT + ((size_t)bb * 128 + col) * 4096 + n0) = *(unsigned long long*)tb;
      }
    }
  }
}

// ---------------------------------------------------------------------------
// gemm_pv: split-K PV, XCD-swizzled. pbuf[z][g][c] = PT[g, zslice] @ vT_b^T.
// Grid (3, 16, 8).
// ---------------------------------------------------------------------------
__global__ __launch_bounds__(256) void gemm_pv(const __hip_bfloat16* __restrict__ PT,
                                               const __hip_bfloat16* __restrict__ vT,
                                               float* __restrict__ pbuf) {
  __shared__ __align__(16) __hip_bfloat16 Asl[128][32];
  __shared__ __align__(16) __hip_bfloat16 Bsl[128][32];
  int nf = xcd_flat(384);
  int bX = nf % 3, bY = (nf / 3) & 15, kz = nf / 48;
  int tid = threadIdx.x;
  int lane = tid & 63;
  int w = tid >> 6;
  int wr = w >> 1, wc = w & 1;
  int fr = lane & 15, fq = lane >> 4;
  int rowBase = bY * 128, colBase = bX * 128;
  const __hip_bfloat16* BTb = vT + (size_t)bY * 384 * 4096;

  int r1 = tid >> 2, kc1 = tid & 3;
  int r2 = (tid + 256) >> 2;

  char* aB1 = (char*)Asl + (size_t)(w * 64) * 16;
  char* aB2 = (char*)Asl + (size_t)(256 + w * 64) * 16;
  char* bB1 = (char*)Bsl + (size_t)(w * 64) * 16;
  char* bB2 = (char*)Bsl + (size_t)(256 + w * 64) * 16;

  const __hip_bfloat16* a1 = PT + (size_t)(rowBase + r1) * 4096 + kz * 512 + kc1 * 8;
  const __hip_bfloat16* a2 = PT + (size_t)(rowBase + r2) * 4096 + kz * 512 + kc1 * 8;
  const __hip_bfloat16* b1 = BTb + (size_t)(colBase + r1) * 4096 + kz * 512 + kc1 * 8;
  const __hip_bfloat16* b2 = BTb + (size_t)(colBase + r2) * 4096 + kz * 512 + kc1 * 8;

  f32x4 acc[4][4] = {};

  for (int kk = 0; kk < 512; kk += 32) {
    gload16(a1 + kk, aB1);
    gload16(a2 + kk, aB2);
    gload16(b1 + kk, bB1);
    gload16(b2 + kk, bB2);
    __syncthreads();
    bf16x8 af[4], bfv[4];
#pragma unroll
    for (int m = 0; m < 4; m++) af[m] = *(const bf16x8*)&Asl[wr * 64 + m * 16 + fr][fq * 8];
#pragma unroll
    for (int n = 0; n < 4; n++) bfv[n] = *(const bf16x8*)&Bsl[wc * 64 + n * 16 + fr][fq * 8];
#pragma unroll
    for (int m = 0; m < 4; m++)
#pragma unroll
      for (int n = 0; n < 4; n++)
        acc[m][n] = __builtin_amdgcn_mfma_f32_16x16x32_bf16(af[m], bfv[n], acc[m][n], 0, 0, 0);
    __syncthreads();
  }

  float* outz = pbuf + (size_t)kz * 786432;
#pragma unroll
  for (int m = 0; m < 4; m++) {
    int row0 = rowBase + wr * 64 + m * 16 + fq * 4;
#pragma unroll
    for (int n = 0; n < 4; n++) {
      int col = colBase + wc * 64 + n * 16 + fr;
      f32x4 v = acc[m][n];
#pragma unroll
      for (int r = 0; r < 4; r++) outz[(size_t)(row0 + r) * 384 + col] = v[r];
    }
  }
}

// ---------------------------------------------------------------------------
// anch_fix2: anch1[b][m][c] = seeds[m][c] + sum_z pbuf[z][b*128+h(c)*16+m][c].
// ---------------------------------------------------------------------------
__global__ void anch_fix2(const float* __restrict__ pbuf, const float* __restrict__ seeds,
                          float* __restrict__ anch1) {
  int idx = blockIdx.x * 256 + threadIdx.x;  // 98304
  int b = idx / 6144;
  int rem = idx - b * 6144;
  int m = rem / 384, c = rem - m * 384;
  int g = b * 128 + (c / 48) * 16 + m;
  const float* p = pbuf + (size_t)g * 384 + c;
  float s = 0.f;
#pragma unroll
  for (int z = 0; z < 8; z++) s += p[(size_t)z * 786432];
  anch1[idx] = seeds[rem] + s;
}

// ---------------------------------------------------------------------------
// softmax_rows: PT[g][n] = softmax_n(lgT[g][n]) (bf16 in/out). Block per row.
// ---------------------------------------------------------------------------
__global__ __launch_bounds__(256) void softmax_rows(const __hip_bfloat16* __restrict__ lgT,
                                                    __hip_bfloat16* __restrict__ PT) {
  int g = blockIdx.x;
  const __hip_bfloat16* row = lgT + (size_t)g * 4096;
  int tid = threadIdx.x, wv = tid >> 6, lane = tid & 63;
  __shared__ float redm[4], reds[4];
  float v[16];
  union { ulonglong2 u; __hip_bfloat16 h[8]; } L0, L1;
  L0.u = *(const ulonglong2*)(row + tid * 16);
  L1.u = *(const ulonglong2*)(row + tid * 16 + 8);
#pragma unroll
  for (int i = 0; i < 8; i++) {
    v[i] = __bfloat162float(L0.h[i]);
    v[8 + i] = __bfloat162float(L1.h[i]);
  }
  float mx = v[0];
#pragma unroll
  for (int i = 1; i < 16; i++) mx = fmaxf(mx, v[i]);
#pragma unroll
  for (int off = 1; off < 64; off <<= 1) mx = fmaxf(mx, __shfl_xor(mx, off));
  if (lane == 0) redm[wv] = mx;
  __syncthreads();
  mx = fmaxf(fmaxf(redm[0], redm[1]), fmaxf(redm[2], redm[3]));
  float s = 0.f;
#pragma unroll
  for (int i = 0; i < 16; i++) {
    v[i] = __expf(v[i] - mx);
    s += v[i];
  }
#pragma unroll
  for (int off = 1; off < 64; off <<= 1) s += __shfl_xor(s, off);
  if (lane == 0) reds[wv] = s;
  __syncthreads();
  s = (reds[0] + reds[1]) + (reds[2] + reds[3]);
  float inv = 1.f / s;
  __hip_bfloat16 tb[16];
#pragma unroll
  for (int i = 0; i < 16; i++) tb[i] = __float2bfloat16(v[i] * inv);
  __hip_bfloat16* op = PT + (size_t)g * 4096 + tid * 16;
  *(ulonglong2*)op = *(ulonglong2*)tb;
  *(ulonglong2*)(op + 8) = *(ulonglong2*)(tb + 8);
}

// ---------------------------------------------------------------------------
// fill_wl: wvlT[384+hm][ci] = sum_d w_kv_agg[ci][h*48+d] * qseed[m][h*48+d].
// ---------------------------------------------------------------------------
__global__ void fill_wl(const float* __restrict__ wkv, const float* __restrict__ qseed,
                        __hip_bfloat16* __restrict__ wvlT) {
  int idx = blockIdx.x * 256 + threadIdx.x;  // 49152
  int hm = idx / 384, ci = idx - hm * 384;
  int h = hm >> 4, m = hm & 15;
  const float* wp = wkv + (size_t)ci * 768 + h * 48;
  const float* qp = qseed + m * 384 + h * 48;
  float acc = 0.f;
#pragma unroll
  for (int d = 0; d < 48; d++) acc += wp[d] * qp[d];
  wvlT[384 * 384 + idx] = __float2bfloat16(acc);
}

// ---------------------------------------------------------------------------
// pgemm_conv: P = softmax_per_head(xb @ W_pbT_b^T) -> A2[:,384:512]  (GEMM)
//             + depthwise 3x3 conv of xb          -> A2[:,0:384]     (fused)
// Grid (1, 512): each block owns a 128-row panel.
// ---------------------------------------------------------------------------
__global__ __launch_bounds__(256) void pgemm_conv(const __hip_bfloat16* __restrict__ A,
                                                  const __hip_bfloat16* __restrict__ wpbT,
                                                  const float* __restrict__ dwk,
                                                  __hip_bfloat16* __restrict__ A2) {
  constexpr int K = 384;
  __shared__ __align__(16) __hip_bfloat16 Asl[128][32];
  __shared__ __align__(16) __hip_bfloat16 Bsl[128][32];
  int tid = threadIdx.x;
  int lane = tid & 63;
  int w = tid >> 6;
  int wr = w >> 1, wc = w & 1;
  int fr = lane & 15, fq = lane >> 4;
  int rowBase = blockIdx.y * 128;
  const __hip_bfloat16* BTb = wpbT + (size_t)(rowBase >> 12) * (128 * 384);

  int r1 = tid >> 2, kc1 = tid & 3;
  int r2 = (tid + 256) >> 2;

  char* aB1 = (char*)Asl + (size_t)(w * 64) * 16;
  char* aB2 = (char*)Asl + (size_t)(256 + w * 64) * 16;
  char* bB1 = (char*)Bsl + (size_t)(w * 64) * 16;
  char* bB2 = (char*)Bsl + (size_t)(256 + w * 64) * 16;

  const __hip_bfloat16* a1 = A + (size_t)(rowBase + r1) * K + kc1 * 8;
  const __hip_bfloat16* a2 = A + (size_t)(rowBase + r2) * K + kc1 * 8;
  const __hip_bfloat16* b1 = BTb + (size_t)r1 * K + kc1 * 8;
  const __hip_bfloat16* b2 = BTb + (size_t)r2 * K + kc1 * 8;

  f32x4 acc[4][4] = {};

  for (int kk = 0; kk < K; kk += 32) {
    gload16(a1 + kk, aB1);
    gload16(a2 + kk, aB2);
    gload16(b1 + kk, bB1);
    gload16(b2 + kk, bB2);
    __syncthreads();
    bf16x8 af[4], bfv[4];
#pragma unroll
    for (int m = 0; m < 4; m++) af[m] = *(const bf16x8*)&Asl[wr * 64 + m * 16 + fr][fq * 8];
#pragma unroll
    for (int n = 0; n < 4; n++) bfv[n] = *(const bf16x8*)&Bsl[wc * 64 + n * 16 + fr][fq * 8];
#pragma unroll
    for (int m = 0; m < 4; m++)
#pragma unroll
      for (int n = 0; n < 4; n++)
        acc[m][n] = __builtin_amdgcn_mfma_f32_16x16x32_bf16(af[m], bfv[n], acc[m][n], 0, 0, 0);
    __syncthreads();
  }

  // epilogue: per (row, head) softmax over the 16-lane fr group -> A2[:,384+col]
#pragma unroll
  for (int m = 0; m < 4; m++) {
    int row0 = rowBase + wr * 64 + m * 16 + fq * 4;
#pragma unroll
    for (int n = 0; n < 4; n++) {
      int col = wc * 64 + n * 16 + fr;
      f32x4 v = acc[m][n];
      f32x4 mx = v;
#pragma unroll
      for (int off = 1; off < 16; off <<= 1)
#pragma unroll
        for (int r = 0; r < 4; r++) mx[r] = fmaxf(mx[r], __shfl_xor(mx[r], off));
      f32x4 e;
#pragma unroll
      for (int r = 0; r < 4; r++) e[r] = __expf(v[r] - mx[r]);
      f32x4 s = e;
#pragma unroll
      for (int off = 1; off < 16; off <<= 1)
#pragma unroll
        for (int r = 0; r < 4; r++) s[r] += __shfl_xor(s[r], off);
#pragma unroll
      for (int r = 0; r < 4; r++)
        A2[(size_t)(row0 + r) * 512 + 384 + col] = __float2bfloat16(e[r] / s[r]);
    }
  }

  // conv phase: wave = position chunk; lane owns 6 contiguous channels.
  // xb rows for this panel are L2-warm from the GEMM staging.
  int c0 = lane * 6;
  float kw[6][9];
#pragma unroll
  for (int i = 0; i < 6; i++)
#pragma unroll
    for (int ki = 0; ki < 9; ki++) kw[i][ki] = dwk[(c0 + i) * 9 + ki];
  int bb2 = rowBase >> 12;
  int p0 = rowBase & 4095;
  for (int it = 0; it < 32; it++) {
    int p = p0 + w * 32 + it;
    int y = p >> 6, wx = p & 63;
    size_t prow = (size_t)rowBase + w * 32 + it;
    float acc2[6] = {};
#pragma unroll
    for (int dy = -1; dy <= 1; dy++) {
      int yy = y + dy;
      if (yy < 0 || yy >= 64) continue;  // wave-uniform
#pragma unroll
      for (int dx = -1; dx <= 1; dx++) {
        int ww2 = wx + dx;
        if (ww2 < 0 || ww2 >= 64) continue;
        int ki = (dy + 1) * 3 + (dx + 1);
        const __hip_bfloat16* xp = A + ((size_t)(bb2 * 4096 + yy * 64 + ww2)) * 384 + c0;
#pragma unroll
        for (int i = 0; i < 6; i++) acc2[i] += __bfloat162float(xp[i]) * kw[i][ki];
      }
    }
    __hip_bfloat16 tb[6];
#pragma unroll
    for (int i = 0; i < 6; i++) tb[i] = __float2bfloat16(acc2[i]);
    __hip_bfloat16* gp = A2 + prow * 512 + c0;
    *(unsigned int*)(gp) = *(unsigned int*)(tb);
    *(unsigned int*)(gp + 2) = *(unsigned int*)(tb + 2);
    *(unsigned int*)(gp + 4) = *(unsigned int*)(tb + 4);
  }
}

// ---------------------------------------------------------------------------
// anchor_proj2: out[b,16,wstride] = A[b,16,384] @ W[384,wstride].
// ---------------------------------------------------------------------------
__global__ __launch_bounds__(256) void anchor_proj2(const float* __restrict__ A,
                                                    const float* __restrict__ W,
                                                    float* __restrict__ out, int wstride,
                                                    int scaleCols) {
  int cs = blockIdx.x * 16;
  int b = blockIdx.y;
  __shared__ float a1[16][385];
  int tid = threadIdx.x;
  for (int idx = tid; idx < 6144; idx += 256) a1[idx / 384][idx % 384] = A[b * 6144 + idx];
  __syncthreads();
  int m = tid >> 4, cc = tid & 15;
  int col = cs + cc;
  const float* wp = W + col;
  float acc0 = 0.f, acc1 = 0.f, acc2 = 0.f, acc3 = 0.f;
#pragma unroll 4
  for (int k = 0; k < 384; k += 4) {
    acc0 += a1[m][k] * wp[(size_t)k * wstride];
    acc1 += a1[m][k + 1] * wp[(size_t)(k + 1) * wstride];
    acc2 += a1[m][k + 2] * wp[(size_t)(k + 2) * wstride];
    acc3 += a1[m][k + 3] * wp[(size_t)(k + 3) * wstride];
  }
  float acc = (acc0 + acc1) + (acc2 + acc3);
  if (col < scaleCols) acc *= SCALE;
  out[((size_t)b * 16 + m) * wstride + col] = acc;
}

// ---------------------------------------------------------------------------
// anchor_proj_qkv: fused q_self (x<24) + kv_self (x>=24) projections.
// Grid (72, 16).
// ---------------------------------------------------------------------------
__global__ __launch_bounds__(256) void anchor_proj_qkv(const float* __restrict__ A,
                                                       const float* __restrict__ Wq,
                                                       const float* __restrict__ Wkv,
                                                       float* __restrict__ q_out,
                                                       float* __restrict__ kv_out) {
  bool isQ = blockIdx.x < 24;
  int bx = isQ ? blockIdx.x : blockIdx.x - 24;
  const float* W = isQ ? Wq : Wkv;
  float* outp = isQ ? q_out : kv_out;
  int wstride = isQ ? 384 : 768;
  float scale = isQ ? SCALE : 1.f;
  int cs = bx * 16;
  int b = blockIdx.y;
  __shared__ float a1[16][385];
  int tid = threadIdx.x;
  for (int idx = tid; idx < 6144; idx += 256) a1[idx / 384][idx % 384] = A[b * 6144 + idx];
  __syncthreads();
  int m = tid >> 4, cc = tid & 15;
  int col = cs + cc;
  const float* wp = W + col;
  float acc0 = 0.f, acc1 = 0.f, acc2 = 0.f, acc3 = 0.f;
#pragma unroll 4
  for (int k = 0; k < 384; k += 4) {
    acc0 += a1[m][k] * wp[(size_t)k * wstride];
    acc1 += a1[m][k + 1] * wp[(size_t)(k + 1) * wstride];
    acc2 += a1[m][k + 2] * wp[(size_t)(k + 2) * wstride];
    acc3 += a1[m][k + 3] * wp[(size_t)(k + 3) * wstride];
  }
  float acc = ((acc0 + acc1) + (acc2 + acc3)) * scale;
  outp[((size_t)b * 16 + m) * wstride + col] = acc;
}

// ---------------------------------------------------------------------------
// Self attention on anchors (16x16, per (b,h)); anchors2 = anchors1 + out.
// ---------------------------------------------------------------------------
__global__ void self_attn(const float* __restrict__ qsf, const float* __restrict__ kvs,
                          const float* __restrict__ anch1, float* __restrict__ anch2) {
  int h = blockIdx.x & 7, b = blockIdx.x >> 3;
  __shared__ float qs[16][48], ks[16][48], vs[16][48], p[16][17];
  int tid = threadIdx.x;
  for (int idx = tid; idx < 768; idx += 256) {
    int m = idx / 48, d = idx % 48;
    qs[m][d] = qsf[(b * 16 + m) * 384 + h * 48 + d];
    ks[m][d] = kvs[(b * 16 + m) * 768 + h * 48 + d];
    vs[m][d] = kvs[(b * 16 + m) * 768 + 384 + h * 48 + d];
  }
  __syncthreads();
  {
    int mq = tid >> 4, mk = tid & 15;
    float acc = 0.f;
    for (int d = 0; d < 48; d++) acc += qs[mq][d] * ks[mk][d];
    p[mq][mk] = acc;
  }
  __syncthreads();
  if (tid < 16) {
    float mx = -1e30f;
    for (int mk = 0; mk < 16; mk++) mx = fmaxf(mx, p[tid][mk]);
    float sum = 0.f;
    for (int mk = 0; mk < 16; mk++) {
      float e = __expf(p[tid][mk] - mx);
      p[tid][mk] = e;
      sum += e;
    }
    float inv = 1.f / sum;
    for (int mk = 0; mk < 16; mk++) p[tid][mk] *= inv;
  }
  __syncthreads();
  for (int idx = tid; idx < 768; idx += 256) {
    int m = idx / 48, d = idx % 48;
    float acc = 0.f;
    for (int mk = 0; mk < 16; mk++) acc += p[m][mk] * vs[mk][d];
    int c = h * 48 + d;
    anch2[(b * 16 + m) * 384 + c] = anch1[(b * 16 + m) * 384 + c] + acc;
  }
}

// ---------------------------------------------------------------------------
// fill_wb: merged fill_wpb (idx<786432) + fill_bt2 (rest). Grid 15360.
// ---------------------------------------------------------------------------
__global__ void fill_wb(const float* __restrict__ wq, const float* __restrict__ wproj,
                        const float* __restrict__ kvb,
                        __hip_bfloat16* __restrict__ wpbT,
                        __hip_bfloat16* __restrict__ bt2) {
  int idx = blockIdx.x * 256 + threadIdx.x;
  if (idx < 786432) {
    // W_pbT[b][hm][k] = sum_d w_q_bcast[k][h*48+d] * k_b[b][m][h*48+d]
    int b = idx / 49152;
    int rem = idx - b * 49152;
    int hm = rem / 384, k = rem - hm * 384;
    int h = hm >> 4, m = hm & 15;
    const float* kp = kvb + ((size_t)(b * 16 + m)) * 768 + h * 48;
    const float* wp = wq + (size_t)k * 384 + h * 48;
    float acc = 0.f;
#pragma unroll
    for (int d = 0; d < 48; d++) acc += wp[d] * kp[d];
    wpbT[idx] = __float2bfloat16(acc);
  } else {
    int j = idx - 786432;  // 0..3145727
    int b = j / 196608;
    int rem = j - b * 196608;
    int cp = rem / 512, k2 = rem - cp * 512;
    float v;
    if (k2 < 384) {
      v = wproj[(size_t)k2 * 384 + cp];
    } else {
      int hm = k2 - 384, h = hm >> 4, m = hm & 15;
      const float* vp = kvb + ((size_t)(b * 16 + m)) * 768 + 384 + h * 48;
      const float* wp2 = wproj + (size_t)(h * 48) * 384 + cp;
      v = 0.f;
#pragma unroll
      for (int d = 0; d < 48; d++) v += vp[d] * wp2[(size_t)d * 384];
    }
    bt2[j] = __float2bfloat16(v);
  }
}

// ---------------------------------------------------------------------------
extern "C" void kernel_launch(void* const* d_in, const int* in_sizes, int n_in,
                              void* d_out, int out_size, void* d_ws, size_t ws_size,
                              hipStream_t stream) {
  (void)in_sizes; (void)n_in; (void)out_size; (void)ws_size;
  const float* x = (const float*)d_in[0];
  const float* wsal = (const float*)d_in[3];
  const float* bsal = (const float*)d_in[4];
  const float* seeds = (const float*)d_in[5];
  const float* w_q_agg = (const float*)d_in[6];
  const float* w_kv_agg = (const float*)d_in[7];
  const float* w_q_self = (const float*)d_in[8];
  const float* w_kv_self = (const float*)d_in[9];
  const float* w_q_bcast = (const float*)d_in[10];
  const float* w_kv_bcast = (const float*)d_in[11];
  const float* dwk = (const float*)d_in[12];
  const float* w_proj = (const float*)d_in[13];
  float* out = (float*)d_out;

  char* ws = (char*)d_ws;
  size_t off = 0;
  auto take = [&](size_t bytes) -> void* {
    void* p = ws + off;
    off += (bytes + 255) & ~(size_t)255;
    return p;
  };
  __hip_bfloat16* xb = (__hip_bfloat16*)take(50331648);      // bf16(x)
  __hip_bfloat16* vT = (__hip_bfloat16*)take(50331648);      // [16][384][4096] bf16
  char* lgRegion = (char*)take(33554432);                    // bf16 logits (16MB) / pbuf f32 (25MB)
  __hip_bfloat16* PT = (__hip_bfloat16*)take(16777216);      // [2048][4096] bf16
  float* qseed = (float*)take(24576);
  float* sal = (float*)take(262144);
  float* anch1 = (float*)take(393216);
  float* anch2 = (float*)take(393216);
  float* q_self = (float*)take(393216);
  float* kv_self = (float*)take(786432);
  float* kv_b = (float*)take(786432);
  __hip_bfloat16* wvlT = (__hip_bfloat16*)take(393216);   // [512][384] bf16: v ++ Wl
  __hip_bfloat16* wpbT = (__hip_bfloat16*)take(1572864);  // [16][128][384] bf16
  __hip_bfloat16* bt2 = (__hip_bfloat16*)take(6291456);   // [16][384][512] bf16
  __hip_bfloat16* logitsT = (__hip_bfloat16*)lgRegion;    // [2048][4096] bf16
  float* pbuf = (float*)lgRegion;  // alias: logits dead after softmax_rows
  __hip_bfloat16* A2 = vT;         // alias: vT+pbuf dead after anch_fix2 (64 of 80 MB)

  // 1) xb + saliency
  prep<<<16384, 256, 0, stream>>>(x, wsal, bsal, xb, sal);
  // 2) build combined B: wvlT[0:384] = v-cols^T; wvlT[384:512] = Wl (needs qseed)
  anchor_proj2<<<dim3(24, 1), 256, 0, stream>>>(seeds, w_q_agg, qseed, 384, 384);
  wcast_tv<<<576, 256, 0, stream>>>(w_kv_agg, wvlT);
  fill_wl<<<192, 256, 0, stream>>>(w_kv_agg, qseed, wvlT);
  // 3) one pass over xb: vT (transposed V) + logitsT (transposed bf16 logits)
  gemm_vlog<<<dim3(4, 512), 256, 0, stream>>>(xb, wvlT, vT, logitsT, sal);
  // 4) softmax over keys; PV with split-K=8; reduce+seeds -> anchors1
  softmax_rows<<<2048, 256, 0, stream>>>(logitsT, PT);
  gemm_pv<<<dim3(3, 16, 8), 256, 0, stream>>>(PT, vT, pbuf);
  anch_fix2<<<384, 256, 0, stream>>>(pbuf, seeds, anch1);
  // 5) anchor self-attention -> anchors2 (q_self + kv_self fused)
  anchor_proj_qkv<<<dim3(72, 16), 256, 0, stream>>>(anch1, w_q_self, w_kv_self, q_self, kv_self);
  self_attn<<<128, 256, 0, stream>>>(q_self, kv_self, anch1, anch2);
  // 6) kv_bcast = anchors2 @ w_kv_bcast (SCALE on k half)
  anchor_proj2<<<dim3(48, 16), 256, 0, stream>>>(anch2, w_kv_bcast, kv_b, 768, 384);
  // 7) per-batch folded weights (wpbT + bt2 in one launch)
  fill_wb<<<15360, 256, 0, stream>>>(w_q_bcast, w_proj, kv_b, wpbT, bt2);
  // 8+9) A2 = [dwconv(xb) | softmax(xb @ W_pbT_b)]  (fused; vT/pbuf dead -> A2)
  pgemm_conv<<<dim3(1, 512), 256, 0, stream>>>(xb, wpbT, dwk, A2);
  // 10) out = A2 @ BT2_b   (K=512, f32 out)
  gemm_mfma<512, float, 12><<<dim3(3, 512), 256, 0, stream>>>(A2, bt2, out, 384, (size_t)384 * 512);
}

// Round 11
// 352.927 us; speedup vs baseline: 6.4397x; 1.0568x over previous
//
#include <hip/hip_runtime.h>
#include <hip/hip_bf16.h>

// Problem constants: B=16, N=4096, C=384, M=16, NH=8, HD=48, H=W=64
#define SCALE 0.14433756729740643f  // 48^-0.5

typedef __attribute__((ext_vector_type(8))) short bf16x8;
typedef __attribute__((ext_vector_type(4))) float f32x4;

template <typename T> __device__ inline T cvt_from_f(float v);
template <> __device__ inline float cvt_from_f<float>(float v) { return v; }
template <> __device__ inline __hip_bfloat16 cvt_from_f<__hip_bfloat16>(float v) { return __float2bfloat16(v); }

__device__ inline void gload16(const void* g, void* l) {
  __builtin_amdgcn_global_load_lds((const __attribute__((address_space(1))) void*)g,
                                   (__attribute__((address_space(3))) void*)l, 16, 0, 0);
}

// XCD-bijective swizzle (nwg must be %8==0): same-row-panel column blocks
// become dispatch-adjacent within one XCD chunk -> L2 panel reuse.
__device__ inline int xcd_flat(int nwg) {
  int flat = (blockIdx.z * gridDim.y + blockIdx.y) * gridDim.x + blockIdx.x;
  int per = nwg >> 3;
  return (flat & 7) * per + (flat >> 3);
}

// ---------------------------------------------------------------------------
// prep: xb = bf16(x); sal[row] = sigmoid(x·wsal + b). One wave per row.
// ---------------------------------------------------------------------------
__global__ __launch_bounds__(256) void prep(const float* __restrict__ x,
                                            const float* __restrict__ wsal,
                                            const float* __restrict__ bsal,
                                            __hip_bfloat16* __restrict__ xb,
                                            float* __restrict__ sal) {
  int wave = threadIdx.x >> 6, lane = threadIdx.x & 63;
  size_t row = (size_t)blockIdx.x * 4 + wave;
  const float* xr = x + row * 384;
  float xs[6];
  float part = 0.f;
#pragma unroll
  for (int j = 0; j < 6; j++) {
    int c = lane + 64 * j;
    xs[j] = xr[c];
    part += xs[j] * wsal[c];
  }
#pragma unroll
  for (int off = 32; off >= 1; off >>= 1) part += __shfl_xor(part, off);
  float s = 1.f / (1.f + __expf(-(part + bsal[0])));
#pragma unroll
  for (int j = 0; j < 6; j++) {
    int c = lane + 64 * j;
    xb[row * 384 + c] = __float2bfloat16(xs[j]);
  }
  if (lane == 0) sal[row] = s;
}

// ---------------------------------------------------------------------------
// wcast_tv: wvlT[n][k] = bf16(w_kv_agg[k][384+n])  (v-columns transposed)
// ---------------------------------------------------------------------------
__global__ void wcast_tv(const float* __restrict__ w, __hip_bfloat16* __restrict__ wt) {
  int idx = blockIdx.x * 256 + threadIdx.x;
  if (idx >= 384 * 384) return;
  int n = idx / 384, k = idx % 384;
  wt[idx] = __float2bfloat16(w[(size_t)k * 768 + 384 + n]);
}

// ---------------------------------------------------------------------------
// MFMA GEMM (final proj): out[M,Ncols] = A[M,K] @ BT_b[Ncols,K]^T.
// XCD-swizzled grid. 128x128 tile, BK=32, 4 waves.
// ---------------------------------------------------------------------------
template <int K, typename OT, int BSHIFT>
__global__ __launch_bounds__(256) void gemm_mfma(const __hip_bfloat16* __restrict__ A,
                                                 const __hip_bfloat16* __restrict__ BT,
                                                 OT* __restrict__ out, int Ncols,
                                                 size_t btBatchStride) {
  __shared__ __align__(16) __hip_bfloat16 Asl[128][32];
  __shared__ __align__(16) __hip_bfloat16 Bsl[128][32];
  int nf = xcd_flat(gridDim.x * gridDim.y);
  int bX = nf % gridDim.x, bY = nf / gridDim.x;
  int tid = threadIdx.x;
  int lane = tid & 63;
  int w = tid >> 6;
  int wr = w >> 1, wc = w & 1;
  int fr = lane & 15, fq = lane >> 4;
  int rowBase = bY * 128, colBase = bX * 128;
  const __hip_bfloat16* BTb = BT + (size_t)(rowBase >> BSHIFT) * btBatchStride;

  int r1 = tid >> 2, kc1 = tid & 3;
  int r2 = (tid + 256) >> 2;

  char* aB1 = (char*)Asl + (size_t)(w * 64) * 16;
  char* aB2 = (char*)Asl + (size_t)(256 + w * 64) * 16;
  char* bB1 = (char*)Bsl + (size_t)(w * 64) * 16;
  char* bB2 = (char*)Bsl + (size_t)(256 + w * 64) * 16;

  const __hip_bfloat16* a1 = A + (size_t)(rowBase + r1) * K + kc1 * 8;
  const __hip_bfloat16* a2 = A + (size_t)(rowBase + r2) * K + kc1 * 8;
  const __hip_bfloat16* b1 = BTb + (size_t)(colBase + r1) * K + kc1 * 8;
  const __hip_bfloat16* b2 = BTb + (size_t)(colBase + r2) * K + kc1 * 8;

  f32x4 acc[4][4] = {};

  for (int kk = 0; kk < K; kk += 32) {
    gload16(a1 + kk, aB1);
    gload16(a2 + kk, aB2);
    gload16(b1 + kk, bB1);
    gload16(b2 + kk, bB2);
    __syncthreads();
    bf16x8 af[4], bfv[4];
#pragma unroll
    for (int m = 0; m < 4; m++) af[m] = *(const bf16x8*)&Asl[wr * 64 + m * 16 + fr][fq * 8];
#pragma unroll
    for (int n = 0; n < 4; n++) bfv[n] = *(const bf16x8*)&Bsl[wc * 64 + n * 16 + fr][fq * 8];
#pragma unroll
    for (int m = 0; m < 4; m++)
#pragma unroll
      for (int n = 0; n < 4; n++)
        acc[m][n] = __builtin_amdgcn_mfma_f32_16x16x32_bf16(af[m], bfv[n], acc[m][n], 0, 0, 0);
    __syncthreads();
  }

#pragma unroll
  for (int m = 0; m < 4; m++) {
    int row0 = rowBase + wr * 64 + m * 16 + fq * 4;
#pragma unroll
    for (int n = 0; n < 4; n++) {
      int col = colBase + wc * 64 + n * 16 + fr;
      f32x4 v = acc[m][n];
#pragma unroll
      for (int r = 0; r < 4; r++) out[(size_t)(row0 + r) * Ncols + col] = cvt_from_f<OT>(v[r]);
    }
  }
}

// ---------------------------------------------------------------------------
// gemm_vlog: one pass over xb computes BOTH (XCD-swizzled grid (4,512))
//   x<3 : vT[b][c][n]  = sal·(xb @ wv)          (transposed bf16)
//   x==3: lgT[b*128+hm][n] = sal·(xb @ Wl^T)    (transposed bf16)
// ---------------------------------------------------------------------------
__global__ __launch_bounds__(256) void gemm_vlog(const __hip_bfloat16* __restrict__ A,
                                                 const __hip_bfloat16* __restrict__ BT,
                                                 __hip_bfloat16* __restrict__ vT,
                                                 __hip_bfloat16* __restrict__ lgT,
                                                 const float* __restrict__ rowScale) {
  constexpr int K = 384;
  __shared__ __align__(16) __hip_bfloat16 Asl[128][32];
  __shared__ __align__(16) __hip_bfloat16 Bsl[128][32];
  int nf = xcd_flat(2048);
  int bX = nf & 3, bY = nf >> 2;
  int tid = threadIdx.x;
  int lane = tid & 63;
  int w = tid >> 6;
  int wr = w >> 1, wc = w & 1;
  int fr = lane & 15, fq = lane >> 4;
  int rowBase = bY * 128, colBase = bX * 128;

  int r1 = tid >> 2, kc1 = tid & 3;
  int r2 = (tid + 256) >> 2;

  char* aB1 = (char*)Asl + (size_t)(w * 64) * 16;
  char* aB2 = (char*)Asl + (size_t)(256 + w * 64) * 16;
  char* bB1 = (char*)Bsl + (size_t)(w * 64) * 16;
  char* bB2 = (char*)Bsl + (size_t)(256 + w * 64) * 16;

  const __hip_bfloat16* a1 = A + (size_t)(rowBase + r1) * K + kc1 * 8;
  const __hip_bfloat16* a2 = A + (size_t)(rowBase + r2) * K + kc1 * 8;
  const __hip_bfloat16* b1 = BT + (size_t)(colBase + r1) * K + kc1 * 8;
  const __hip_bfloat16* b2 = BT + (size_t)(colBase + r2) * K + kc1 * 8;

  f32x4 acc[4][4] = {};

  for (int kk = 0; kk < K; kk += 32) {
    gload16(a1 + kk, aB1);
    gload16(a2 + kk, aB2);
    gload16(b1 + kk, bB1);
    gload16(b2 + kk, bB2);
    __syncthreads();
    bf16x8 af[4], bfv[4];
#pragma unroll
    for (int m = 0; m < 4; m++) af[m] = *(const bf16x8*)&Asl[wr * 64 + m * 16 + fr][fq * 8];
#pragma unroll
    for (int n = 0; n < 4; n++) bfv[n] = *(const bf16x8*)&Bsl[wc * 64 + n * 16 + fr][fq * 8];
#pragma unroll
    for (int m = 0; m < 4; m++)
#pragma unroll
      for (int n = 0; n < 4; n++)
        acc[m][n] = __builtin_amdgcn_mfma_f32_16x16x32_bf16(af[m], bfv[n], acc[m][n], 0, 0, 0);
    __syncthreads();
  }

  float sv[4][4];
#pragma unroll
  for (int m = 0; m < 4; m++)
#pragma unroll
    for (int r = 0; r < 4; r++)
      sv[m][r] = rowScale[rowBase + wr * 64 + m * 16 + fq * 4 + r];

  if (bX < 3) {
    // v epilogue: transposed bf16 write
#pragma unroll
    for (int m = 0; m < 4; m++) {
      int row0 = rowBase + wr * 64 + m * 16 + fq * 4;
      int bb = row0 >> 12;
      int n0 = row0 & 4095;
#pragma unroll
      for (int n = 0; n < 4; n++) {
        int col = colBase + wc * 64 + n * 16 + fr;
        __hip_bfloat16 tb[4];
#pragma unroll
        for (int r = 0; r < 4; r++) tb[r] = __float2bfloat16(acc[m][n][r] * sv[m][r]);
        *(unsigned long long*)(vT + ((size_t)bb * 384 + col) * 4096 + n0) = *(unsigned long long*)tb;
      }
    }
  } else {
    // logits epilogue: transposed bf16 write
#pragma unroll
    for (int m = 0; m < 4; m++) {
      int row0 = rowBase + wr * 64 + m * 16 + fq * 4;
      int bb = row0 >> 12;
      int n0 = row0 & 4095;
#pragma unroll
      for (int n = 0; n < 4; n++) {
        int col = wc * 64 + n * 16 + fr;  // 0..127 = hm
        __hip_bfloat16 tb[4];
#pragma unroll
        for (int r = 0; r < 4; r++) tb[r] = __float2bfloat16(acc[m][n][r] * sv[m][r]);
        *(unsigned long long*)(lgT + ((size_t)bb * 128 + col) * 4096 + n0) = *(unsigned long long*)tb;
      }
    }
  }
}

// ---------------------------------------------------------------------------
// gemm_pv: split-K PV, XCD-swizzled. pbuf[z][g][c] = PT[g, zslice] @ vT_b^T.
// Grid (3, 16, 8).
// ---------------------------------------------------------------------------
__global__ __launch_bounds__(256) void gemm_pv(const __hip_bfloat16* __restrict__ PT,
                                               const __hip_bfloat16* __restrict__ vT,
                                               float* __restrict__ pbuf) {
  __shared__ __align__(16) __hip_bfloat16 Asl[128][32];
  __shared__ __align__(16) __hip_bfloat16 Bsl[128][32];
  int nf = xcd_flat(384);
  int bX = nf % 3, bY = (nf / 3) & 15, kz = nf / 48;
  int tid = threadIdx.x;
  int lane = tid & 63;
  int w = tid >> 6;
  int wr = w >> 1, wc = w & 1;
  int fr = lane & 15, fq = lane >> 4;
  int rowBase = bY * 128, colBase = bX * 128;
  const __hip_bfloat16* BTb = vT + (size_t)bY * 384 * 4096;

  int r1 = tid >> 2, kc1 = tid & 3;
  int r2 = (tid + 256) >> 2;

  char* aB1 = (char*)Asl + (size_t)(w * 64) * 16;
  char* aB2 = (char*)Asl + (size_t)(256 + w * 64) * 16;
  char* bB1 = (char*)Bsl + (size_t)(w * 64) * 16;
  char* bB2 = (char*)Bsl + (size_t)(256 + w * 64) * 16;

  const __hip_bfloat16* a1 = PT + (size_t)(rowBase + r1) * 4096 + kz * 512 + kc1 * 8;
  const __hip_bfloat16* a2 = PT + (size_t)(rowBase + r2) * 4096 + kz * 512 + kc1 * 8;
  const __hip_bfloat16* b1 = BTb + (size_t)(colBase + r1) * 4096 + kz * 512 + kc1 * 8;
  const __hip_bfloat16* b2 = BTb + (size_t)(colBase + r2) * 4096 + kz * 512 + kc1 * 8;

  f32x4 acc[4][4] = {};

  for (int kk = 0; kk < 512; kk += 32) {
    gload16(a1 + kk, aB1);
    gload16(a2 + kk, aB2);
    gload16(b1 + kk, bB1);
    gload16(b2 + kk, bB2);
    __syncthreads();
    bf16x8 af[4], bfv[4];
#pragma unroll
    for (int m = 0; m < 4; m++) af[m] = *(const bf16x8*)&Asl[wr * 64 + m * 16 + fr][fq * 8];
#pragma unroll
    for (int n = 0; n < 4; n++) bfv[n] = *(const bf16x8*)&Bsl[wc * 64 + n * 16 + fr][fq * 8];
#pragma unroll
    for (int m = 0; m < 4; m++)
#pragma unroll
      for (int n = 0; n < 4; n++)
        acc[m][n] = __builtin_amdgcn_mfma_f32_16x16x32_bf16(af[m], bfv[n], acc[m][n], 0, 0, 0);
    __syncthreads();
  }

  float* outz = pbuf + (size_t)kz * 786432;
#pragma unroll
  for (int m = 0; m < 4; m++) {
    int row0 = rowBase + wr * 64 + m * 16 + fq * 4;
#pragma unroll
    for (int n = 0; n < 4; n++) {
      int col = colBase + wc * 64 + n * 16 + fr;
      f32x4 v = acc[m][n];
#pragma unroll
      for (int r = 0; r < 4; r++) outz[(size_t)(row0 + r) * 384 + col] = v[r];
    }
  }
}

// ---------------------------------------------------------------------------
// anch_fix2: anch1[b][m][c] = seeds[m][c] + sum_z pbuf[z][b*128+h(c)*16+m][c].
// ---------------------------------------------------------------------------
__global__ void anch_fix2(const float* __restrict__ pbuf, const float* __restrict__ seeds,
                          float* __restrict__ anch1) {
  int idx = blockIdx.x * 256 + threadIdx.x;  // 98304
  int b = idx / 6144;
  int rem = idx - b * 6144;
  int m = rem / 384, c = rem - m * 384;
  int g = b * 128 + (c / 48) * 16 + m;
  const float* p = pbuf + (size_t)g * 384 + c;
  float s = 0.f;
#pragma unroll
  for (int z = 0; z < 8; z++) s += p[(size_t)z * 786432];
  anch1[idx] = seeds[rem] + s;
}

// ---------------------------------------------------------------------------
// softmax_rows: PT[g][n] = softmax_n(lgT[g][n]) (bf16 in/out). Block per row.
// ---------------------------------------------------------------------------
__global__ __launch_bounds__(256) void softmax_rows(const __hip_bfloat16* __restrict__ lgT,
                                                    __hip_bfloat16* __restrict__ PT) {
  int g = blockIdx.x;
  const __hip_bfloat16* row = lgT + (size_t)g * 4096;
  int tid = threadIdx.x, wv = tid >> 6, lane = tid & 63;
  __shared__ float redm[4], reds[4];
  float v[16];
  union { ulonglong2 u; __hip_bfloat16 h[8]; } L0, L1;
  L0.u = *(const ulonglong2*)(row + tid * 16);
  L1.u = *(const ulonglong2*)(row + tid * 16 + 8);
#pragma unroll
  for (int i = 0; i < 8; i++) {
    v[i] = __bfloat162float(L0.h[i]);
    v[8 + i] = __bfloat162float(L1.h[i]);
  }
  float mx = v[0];
#pragma unroll
  for (int i = 1; i < 16; i++) mx = fmaxf(mx, v[i]);
#pragma unroll
  for (int off = 1; off < 64; off <<= 1) mx = fmaxf(mx, __shfl_xor(mx, off));
  if (lane == 0) redm[wv] = mx;
  __syncthreads();
  mx = fmaxf(fmaxf(redm[0], redm[1]), fmaxf(redm[2], redm[3]));
  float s = 0.f;
#pragma unroll
  for (int i = 0; i < 16; i++) {
    v[i] = __expf(v[i] - mx);
    s += v[i];
  }
#pragma unroll
  for (int off = 1; off < 64; off <<= 1) s += __shfl_xor(s, off);
  if (lane == 0) reds[wv] = s;
  __syncthreads();
  s = (reds[0] + reds[1]) + (reds[2] + reds[3]);
  float inv = 1.f / s;
  __hip_bfloat16 tb[16];
#pragma unroll
  for (int i = 0; i < 16; i++) tb[i] = __float2bfloat16(v[i] * inv);
  __hip_bfloat16* op = PT + (size_t)g * 4096 + tid * 16;
  *(ulonglong2*)op = *(ulonglong2*)tb;
  *(ulonglong2*)(op + 8) = *(ulonglong2*)(tb + 8);
}

// ---------------------------------------------------------------------------
// fill_wl: wvlT[384+hm][ci] = sum_d w_kv_agg[ci][h*48+d] * qseed[m][h*48+d].
// ---------------------------------------------------------------------------
__global__ void fill_wl(const float* __restrict__ wkv, const float* __restrict__ qseed,
                        __hip_bfloat16* __restrict__ wvlT) {
  int idx = blockIdx.x * 256 + threadIdx.x;  // 49152
  int hm = idx / 384, ci = idx - hm * 384;
  int h = hm >> 4, m = hm & 15;
  const float* wp = wkv + (size_t)ci * 768 + h * 48;
  const float* qp = qseed + m * 384 + h * 48;
  float acc = 0.f;
#pragma unroll
  for (int d = 0; d < 48; d++) acc += wp[d] * qp[d];
  wvlT[384 * 384 + idx] = __float2bfloat16(acc);
}

// ---------------------------------------------------------------------------
// wtrans: bt2[b][cp][k2<384] = bf16(w_proj[k2][cp]) via LDS 64x64 transpose,
// replicated to all 16 batch slices. Grid (6, 6, 4); z covers 4 batches.
// ---------------------------------------------------------------------------
__global__ __launch_bounds__(256) void wtrans(const float* __restrict__ wproj,
                                              __hip_bfloat16* __restrict__ bt2) {
  __shared__ float t[64][65];
  int kt = blockIdx.x * 64, ct = blockIdx.y * 64;
  int tid = threadIdx.x;
  int c = tid & 63, r4 = tid >> 6;
#pragma unroll
  for (int i = 0; i < 16; i++) {
    int r = i * 4 + r4;
    t[r][c] = wproj[(size_t)(kt + r) * 384 + ct + c];
  }
  __syncthreads();
  // convert once
  __hip_bfloat16 vals[16];
#pragma unroll
  for (int i = 0; i < 16; i++) vals[i] = __float2bfloat16(t[c][i * 4 + r4]);
  for (int b = blockIdx.z * 4; b < blockIdx.z * 4 + 4; b++) {
    __hip_bfloat16* dst = bt2 + (size_t)b * 196608;
#pragma unroll
    for (int i = 0; i < 16; i++) {
      int rr = i * 4 + r4;
      dst[(size_t)(ct + rr) * 512 + kt + c] = vals[i];
    }
  }
}

// ---------------------------------------------------------------------------
// fill_wv2: bt2[b][cp][384+h*16+m] = sum_d v_b[b][m][h*48+d]*w_proj[h*48+d][cp].
// Block per (h, b); lane = cp -> coalesced w_proj row reads.
// ---------------------------------------------------------------------------
__global__ __launch_bounds__(256) void fill_wv2(const float* __restrict__ wproj,
                                                const float* __restrict__ kvb,
                                                __hip_bfloat16* __restrict__ bt2) {
  int h = blockIdx.x, b = blockIdx.y;
  __shared__ float vbs[16][48];
  int tid = threadIdx.x;
  for (int idx = tid; idx < 768; idx += 256) {
    int m = idx / 48, d = idx % 48;
    vbs[m][d] = kvb[(size_t)(b * 16 + m) * 768 + 384 + h * 48 + d];
  }
  __syncthreads();
  for (int cp = tid; cp < 384; cp += 256) {
    float acc[16] = {};
    for (int d = 0; d < 48; d++) {
      float wv = wproj[(size_t)(h * 48 + d) * 384 + cp];
#pragma unroll
      for (int m = 0; m < 16; m++) acc[m] += vbs[m][d] * wv;
    }
    __hip_bfloat16 tb[16];
#pragma unroll
    for (int m = 0; m < 16; m++) tb[m] = __float2bfloat16(acc[m]);
    __hip_bfloat16* dst = bt2 + (size_t)b * 196608 + (size_t)cp * 512 + 384 + h * 16;
    *(ulonglong2*)dst = *(ulonglong2*)tb;
    *(ulonglong2*)(dst + 8) = *(ulonglong2*)(tb + 8);
  }
}

// ---------------------------------------------------------------------------
// fill_wpb2: wpbT[b][h*16+m][k] = sum_d w_q_bcast[k][h*48+d]*k_b[b][m][h*48+d].
// Block per (h, b); lane = k -> per-lane contiguous 48-float w rows; output
// staged through LDS for coalesced bf16 writes.
// ---------------------------------------------------------------------------
__global__ __launch_bounds__(256) void fill_wpb2(const float* __restrict__ wq,
                                                 const float* __restrict__ kvb,
                                                 __hip_bfloat16* __restrict__ wpbT) {
  int h = blockIdx.x, b = blockIdx.y;
  __shared__ float kbs[16][48];
  __shared__ __hip_bfloat16 obuf[16][264];
  int tid = threadIdx.x;
  for (int idx = tid; idx < 768; idx += 256) {
    int m = idx / 48, d = idx % 48;
    kbs[m][d] = kvb[(size_t)(b * 16 + m) * 768 + h * 48 + d];  // SCALE pre-folded
  }
  __syncthreads();
  for (int kbase = 0; kbase < 384; kbase += 256) {
    int chunk = (kbase == 0) ? 256 : 128;
    if (tid < chunk) {
      int k = kbase + tid;
      const float4* wp = (const float4*)(wq + (size_t)k * 384 + h * 48);
      float acc[16] = {};
#pragma unroll
      for (int dq = 0; dq < 12; dq++) {
        float4 wv = wp[dq];
#pragma unroll
        for (int m = 0; m < 16; m++)
          acc[m] += kbs[m][dq * 4] * wv.x + kbs[m][dq * 4 + 1] * wv.y +
                    kbs[m][dq * 4 + 2] * wv.z + kbs[m][dq * 4 + 3] * wv.w;
      }
#pragma unroll
      for (int m = 0; m < 16; m++) obuf[m][tid] = __float2bfloat16(acc[m]);
    }
    __syncthreads();
    for (int widx = tid; widx < 16 * chunk; widx += 256) {
      int m = widx / chunk, kk = widx - m * chunk;
      wpbT[(size_t)b * 49152 + (size_t)(h * 16 + m) * 384 + kbase + kk] = obuf[m][kk];
    }
    __syncthreads();
  }
}

// ---------------------------------------------------------------------------
// pgemm_conv: P = softmax_per_head(xb @ W_pbT_b^T) -> A2[:,384:512]  (GEMM)
//             + depthwise 3x3 conv of xb          -> A2[:,0:384]     (fused)
// ---------------------------------------------------------------------------
__global__ __launch_bounds__(256) void pgemm_conv(const __hip_bfloat16* __restrict__ A,
                                                  const __hip_bfloat16* __restrict__ wpbT,
                                                  const float* __restrict__ dwk,
                                                  __hip_bfloat16* __restrict__ A2) {
  constexpr int K = 384;
  __shared__ __align__(16) __hip_bfloat16 Asl[128][32];
  __shared__ __align__(16) __hip_bfloat16 Bsl[128][32];
  int tid = threadIdx.x;
  int lane = tid & 63;
  int w = tid >> 6;
  int wr = w >> 1, wc = w & 1;
  int fr = lane & 15, fq = lane >> 4;
  int rowBase = blockIdx.y * 128;
  const __hip_bfloat16* BTb = wpbT + (size_t)(rowBase >> 12) * (128 * 384);

  int r1 = tid >> 2, kc1 = tid & 3;
  int r2 = (tid + 256) >> 2;

  char* aB1 = (char*)Asl + (size_t)(w * 64) * 16;
  char* aB2 = (char*)Asl + (size_t)(256 + w * 64) * 16;
  char* bB1 = (char*)Bsl + (size_t)(w * 64) * 16;
  char* bB2 = (char*)Bsl + (size_t)(256 + w * 64) * 16;

  const __hip_bfloat16* a1 = A + (size_t)(rowBase + r1) * K + kc1 * 8;
  const __hip_bfloat16* a2 = A + (size_t)(rowBase + r2) * K + kc1 * 8;
  const __hip_bfloat16* b1 = BTb + (size_t)r1 * K + kc1 * 8;
  const __hip_bfloat16* b2 = BTb + (size_t)r2 * K + kc1 * 8;

  f32x4 acc[4][4] = {};

  for (int kk = 0; kk < K; kk += 32) {
    gload16(a1 + kk, aB1);
    gload16(a2 + kk, aB2);
    gload16(b1 + kk, bB1);
    gload16(b2 + kk, bB2);
    __syncthreads();
    bf16x8 af[4], bfv[4];
#pragma unroll
    for (int m = 0; m < 4; m++) af[m] = *(const bf16x8*)&Asl[wr * 64 + m * 16 + fr][fq * 8];
#pragma unroll
    for (int n = 0; n < 4; n++) bfv[n] = *(const bf16x8*)&Bsl[wc * 64 + n * 16 + fr][fq * 8];
#pragma unroll
    for (int m = 0; m < 4; m++)
#pragma unroll
      for (int n = 0; n < 4; n++)
        acc[m][n] = __builtin_amdgcn_mfma_f32_16x16x32_bf16(af[m], bfv[n], acc[m][n], 0, 0, 0);
    __syncthreads();
  }

  // epilogue: per (row, head) softmax over the 16-lane fr group -> A2[:,384+col]
#pragma unroll
  for (int m = 0; m < 4; m++) {
    int row0 = rowBase + wr * 64 + m * 16 + fq * 4;
#pragma unroll
    for (int n = 0; n < 4; n++) {
      int col = wc * 64 + n * 16 + fr;
      f32x4 v = acc[m][n];
      f32x4 mx = v;
#pragma unroll
      for (int off = 1; off < 16; off <<= 1)
#pragma unroll
        for (int r = 0; r < 4; r++) mx[r] = fmaxf(mx[r], __shfl_xor(mx[r], off));
      f32x4 e;
#pragma unroll
      for (int r = 0; r < 4; r++) e[r] = __expf(v[r] - mx[r]);
      f32x4 s = e;
#pragma unroll
      for (int off = 1; off < 16; off <<= 1)
#pragma unroll
        for (int r = 0; r < 4; r++) s[r] += __shfl_xor(s[r], off);
#pragma unroll
      for (int r = 0; r < 4; r++)
        A2[(size_t)(row0 + r) * 512 + 384 + col] = __float2bfloat16(e[r] / s[r]);
    }
  }

  // conv phase: wave = position chunk; lane owns 6 contiguous channels.
  int c0 = lane * 6;
  float kw[6][9];
#pragma unroll
  for (int i = 0; i < 6; i++)
#pragma unroll
    for (int ki = 0; ki < 9; ki++) kw[i][ki] = dwk[(c0 + i) * 9 + ki];
  int bb2 = rowBase >> 12;
  int p0 = rowBase & 4095;
  for (int it = 0; it < 32; it++) {
    int p = p0 + w * 32 + it;
    int y = p >> 6, wx = p & 63;
    size_t prow = (size_t)rowBase + w * 32 + it;
    float acc2[6] = {};
#pragma unroll
    for (int dy = -1; dy <= 1; dy++) {
      int yy = y + dy;
      if (yy < 0 || yy >= 64) continue;  // wave-uniform
#pragma unroll
      for (int dx = -1; dx <= 1; dx++) {
        int ww2 = wx + dx;
        if (ww2 < 0 || ww2 >= 64) continue;
        int ki = (dy + 1) * 3 + (dx + 1);
        const __hip_bfloat16* xp = A + ((size_t)(bb2 * 4096 + yy * 64 + ww2)) * 384 + c0;
#pragma unroll
        for (int i = 0; i < 6; i++) acc2[i] += __bfloat162float(xp[i]) * kw[i][ki];
      }
    }
    __hip_bfloat16 tb[6];
#pragma unroll
    for (int i = 0; i < 6; i++) tb[i] = __float2bfloat16(acc2[i]);
    __hip_bfloat16* gp = A2 + prow * 512 + c0;
    *(unsigned int*)(gp) = *(unsigned int*)(tb);
    *(unsigned int*)(gp + 2) = *(unsigned int*)(tb + 2);
    *(unsigned int*)(gp + 4) = *(unsigned int*)(tb + 4);
  }
}

// ---------------------------------------------------------------------------
// anchor_proj2: out[b,16,wstride] = A[b,16,384] @ W[384,wstride].
// ---------------------------------------------------------------------------
__global__ __launch_bounds__(256) void anchor_proj2(const float* __restrict__ A,
                                                    const float* __restrict__ W,
                                                    float* __restrict__ out, int wstride,
                                                    int scaleCols) {
  int cs = blockIdx.x * 16;
  int b = blockIdx.y;
  __shared__ float a1[16][385];
  int tid = threadIdx.x;
  for (int idx = tid; idx < 6144; idx += 256) a1[idx / 384][idx % 384] = A[b * 6144 + idx];
  __syncthreads();
  int m = tid >> 4, cc = tid & 15;
  int col = cs + cc;
  const float* wp = W + col;
  float acc0 = 0.f, acc1 = 0.f, acc2 = 0.f, acc3 = 0.f;
#pragma unroll 4
  for (int k = 0; k < 384; k += 4) {
    acc0 += a1[m][k] * wp[(size_t)k * wstride];
    acc1 += a1[m][k + 1] * wp[(size_t)(k + 1) * wstride];
    acc2 += a1[m][k + 2] * wp[(size_t)(k + 2) * wstride];
    acc3 += a1[m][k + 3] * wp[(size_t)(k + 3) * wstride];
  }
  float acc = (acc0 + acc1) + (acc2 + acc3);
  if (col < scaleCols) acc *= SCALE;
  out[((size_t)b * 16 + m) * wstride + col] = acc;
}

// ---------------------------------------------------------------------------
// anchor_proj_qkv: fused q_self (x<24) + kv_self (x>=24) projections.
// ---------------------------------------------------------------------------
__global__ __launch_bounds__(256) void anchor_proj_qkv(const float* __restrict__ A,
                                                       const float* __restrict__ Wq,
                                                       const float* __restrict__ Wkv,
                                                       float* __restrict__ q_out,
                                                       float* __restrict__ kv_out) {
  bool isQ = blockIdx.x < 24;
  int bx = isQ ? blockIdx.x : blockIdx.x - 24;
  const float* W = isQ ? Wq : Wkv;
  float* outp = isQ ? q_out : kv_out;
  int wstride = isQ ? 384 : 768;
  float scale = isQ ? SCALE : 1.f;
  int cs = bx * 16;
  int b = blockIdx.y;
  __shared__ float a1[16][385];
  int tid = threadIdx.x;
  for (int idx = tid; idx < 6144; idx += 256) a1[idx / 384][idx % 384] = A[b * 6144 + idx];
  __syncthreads();
  int m = tid >> 4, cc = tid & 15;
  int col = cs + cc;
  const float* wp = W + col;
  float acc0 = 0.f, acc1 = 0.f, acc2 = 0.f, acc3 = 0.f;
#pragma unroll 4
  for (int k = 0; k < 384; k += 4) {
    acc0 += a1[m][k] * wp[(size_t)k * wstride];
    acc1 += a1[m][k + 1] * wp[(size_t)(k + 1) * wstride];
    acc2 += a1[m][k + 2] * wp[(size_t)(k + 2) * wstride];
    acc3 += a1[m][k + 3] * wp[(size_t)(k + 3) * wstride];
  }
  float acc = ((acc0 + acc1) + (acc2 + acc3)) * scale;
  outp[((size_t)b * 16 + m) * wstride + col] = acc;
}

// ---------------------------------------------------------------------------
// Self attention on anchors (16x16, per (b,h)); anchors2 = anchors1 + out.
// ---------------------------------------------------------------------------
__global__ void self_attn(const float* __restrict__ qsf, const float* __restrict__ kvs,
                          const float* __restrict__ anch1, float* __restrict__ anch2) {
  int h = blockIdx.x & 7, b = blockIdx.x >> 3;
  __shared__ float qs[16][48], ks[16][48], vs[16][48], p[16][17];
  int tid = threadIdx.x;
  for (int idx = tid; idx < 768; idx += 256) {
    int m = idx / 48, d = idx % 48;
    qs[m][d] = qsf[(b * 16 + m) * 384 + h * 48 + d];
    ks[m][d] = kvs[(b * 16 + m) * 768 + h * 48 + d];
    vs[m][d] = kvs[(b * 16 + m) * 768 + 384 + h * 48 + d];
  }
  __syncthreads();
  {
    int mq = tid >> 4, mk = tid & 15;
    float acc = 0.f;
    for (int d = 0; d < 48; d++) acc += qs[mq][d] * ks[mk][d];
    p[mq][mk] = acc;
  }
  __syncthreads();
  if (tid < 16) {
    float mx = -1e30f;
    for (int mk = 0; mk < 16; mk++) mx = fmaxf(mx, p[tid][mk]);
    float sum = 0.f;
    for (int mk = 0; mk < 16; mk++) {
      float e = __expf(p[tid][mk] - mx);
      p[tid][mk] = e;
      sum += e;
    }
    float inv = 1.f / sum;
    for (int mk = 0; mk < 16; mk++) p[tid][mk] *= inv;
  }
  __syncthreads();
  for (int idx = tid; idx < 768; idx += 256) {
    int m = idx / 48, d = idx % 48;
    float acc = 0.f;
    for (int mk = 0; mk < 16; mk++) acc += p[m][mk] * vs[mk][d];
    int c = h * 48 + d;
    anch2[(b * 16 + m) * 384 + c] = anch1[(b * 16 + m) * 384 + c] + acc;
  }
}

// ---------------------------------------------------------------------------
extern "C" void kernel_launch(void* const* d_in, const int* in_sizes, int n_in,
                              void* d_out, int out_size, void* d_ws, size_t ws_size,
                              hipStream_t stream) {
  (void)in_sizes; (void)n_in; (void)out_size; (void)ws_size;
  const float* x = (const float*)d_in[0];
  const float* wsal = (const float*)d_in[3];
  const float* bsal = (const float*)d_in[4];
  const float* seeds = (const float*)d_in[5];
  const float* w_q_agg = (const float*)d_in[6];
  const float* w_kv_agg = (const float*)d_in[7];
  const float* w_q_self = (const float*)d_in[8];
  const float* w_kv_self = (const float*)d_in[9];
  const float* w_q_bcast = (const float*)d_in[10];
  const float* w_kv_bcast = (const float*)d_in[11];
  const float* dwk = (const float*)d_in[12];
  const float* w_proj = (const float*)d_in[13];
  float* out = (float*)d_out;

  char* ws = (char*)d_ws;
  size_t off = 0;
  auto take = [&](size_t bytes) -> void* {
    void* p = ws + off;
    off += (bytes + 255) & ~(size_t)255;
    return p;
  };
  __hip_bfloat16* xb = (__hip_bfloat16*)take(50331648);      // bf16(x)
  __hip_bfloat16* vT = (__hip_bfloat16*)take(50331648);      // [16][384][4096] bf16
  char* lgRegion = (char*)take(33554432);                    // bf16 logits (16MB) / pbuf f32 (25MB)
  __hip_bfloat16* PT = (__hip_bfloat16*)take(16777216);      // [2048][4096] bf16
  float* qseed = (float*)take(24576);
  float* sal = (float*)take(262144);
  float* anch1 = (float*)take(393216);
  float* anch2 = (float*)take(393216);
  float* q_self = (float*)take(393216);
  float* kv_self = (float*)take(786432);
  float* kv_b = (float*)take(786432);
  __hip_bfloat16* wvlT = (__hip_bfloat16*)take(393216);   // [512][384] bf16: v ++ Wl
  __hip_bfloat16* wpbT = (__hip_bfloat16*)take(1572864);  // [16][128][384] bf16
  __hip_bfloat16* bt2 = (__hip_bfloat16*)take(6291456);   // [16][384][512] bf16
  __hip_bfloat16* logitsT = (__hip_bfloat16*)lgRegion;    // [2048][4096] bf16
  float* pbuf = (float*)lgRegion;  // alias: logits dead after softmax_rows
  __hip_bfloat16* A2 = vT;         // alias: vT+pbuf dead after anch_fix2 (64 of 80 MB)

  // 1) xb + saliency
  prep<<<16384, 256, 0, stream>>>(x, wsal, bsal, xb, sal);
  // 2) build combined B: wvlT[0:384] = v-cols^T; wvlT[384:512] = Wl (needs qseed)
  anchor_proj2<<<dim3(24, 1), 256, 0, stream>>>(seeds, w_q_agg, qseed, 384, 384);
  wcast_tv<<<576, 256, 0, stream>>>(w_kv_agg, wvlT);
  fill_wl<<<192, 256, 0, stream>>>(w_kv_agg, qseed, wvlT);
  // 2b) bt2 upper half: w_proj^T replicated (batch-independent, LDS transpose)
  wtrans<<<dim3(6, 6, 4), 256, 0, stream>>>(w_proj, bt2);
  // 3) one pass over xb: vT (transposed V) + logitsT (transposed bf16 logits)
  gemm_vlog<<<dim3(4, 512), 256, 0, stream>>>(xb, wvlT, vT, logitsT, sal);
  // 4) softmax over keys; PV with split-K=8; reduce+seeds -> anchors1
  softmax_rows<<<2048, 256, 0, stream>>>(logitsT, PT);
  gemm_pv<<<dim3(3, 16, 8), 256, 0, stream>>>(PT, vT, pbuf);
  anch_fix2<<<384, 256, 0, stream>>>(pbuf, seeds, anch1);
  // 5) anchor self-attention -> anchors2 (q_self + kv_self fused)
  anchor_proj_qkv<<<dim3(72, 16), 256, 0, stream>>>(anch1, w_q_self, w_kv_self, q_self, kv_self);
  self_attn<<<128, 256, 0, stream>>>(q_self, kv_self, anch1, anch2);
  // 6) kv_bcast = anchors2 @ w_kv_bcast (SCALE on k half)
  anchor_proj2<<<dim3(48, 16), 256, 0, stream>>>(anch2, w_kv_bcast, kv_b, 768, 384);
  // 7) per-batch folded weights, coalesced-access versions
  fill_wpb2<<<dim3(8, 16), 256, 0, stream>>>(w_q_bcast, kv_b, wpbT);
  fill_wv2<<<dim3(8, 16), 256, 0, stream>>>(w_proj, kv_b, bt2);
  // 8+9) A2 = [dwconv(xb) | softmax(xb @ W_pbT_b)]  (fused; vT/pbuf dead -> A2)
  pgemm_conv<<<dim3(1, 512), 256, 0, stream>>>(xb, wpbT, dwk, A2);
  // 10) out = A2 @ BT2_b   (K=512, f32 out)
  gemm_mfma<512, float, 12><<<dim3(3, 512), 256, 0, stream>>>(A2, bt2, out, 384, (size_t)384 * 512);
}

// Round 12
// 345.257 us; speedup vs baseline: 6.5827x; 1.0222x over previous
//
#include <hip/hip_runtime.h>
#include <hip/hip_bf16.h>

// Problem constants: B=16, N=4096, C=384, M=16, NH=8, HD=48, H=W=64
#define SCALE 0.14433756729740643f  // 48^-0.5

typedef __attribute__((ext_vector_type(8))) short bf16x8;
typedef __attribute__((ext_vector_type(4))) float f32x4;

template <typename T> __device__ inline T cvt_from_f(float v);
template <> __device__ inline float cvt_from_f<float>(float v) { return v; }
template <> __device__ inline __hip_bfloat16 cvt_from_f<__hip_bfloat16>(float v) { return __float2bfloat16(v); }

__device__ inline void gload16(const void* g, void* l) {
  __builtin_amdgcn_global_load_lds((const __attribute__((address_space(1))) void*)g,
                                   (__attribute__((address_space(3))) void*)l, 16, 0, 0);
}

// XCD-bijective swizzle (nwg must be %8==0): same-row-panel column blocks
// become dispatch-adjacent within one XCD chunk -> L2 panel reuse.
__device__ inline int xcd_flat(int nwg) {
  int flat = (blockIdx.z * gridDim.y + blockIdx.y) * gridDim.x + blockIdx.x;
  int per = nwg >> 3;
  return (flat & 7) * per + (flat >> 3);
}

// ---------------------------------------------------------------------------
// prep: xb = bf16(x); sal[row] = sigmoid(x·wsal + b). One wave per row.
// ---------------------------------------------------------------------------
__global__ __launch_bounds__(256) void prep(const float* __restrict__ x,
                                            const float* __restrict__ wsal,
                                            const float* __restrict__ bsal,
                                            __hip_bfloat16* __restrict__ xb,
                                            float* __restrict__ sal) {
  int wave = threadIdx.x >> 6, lane = threadIdx.x & 63;
  size_t row = (size_t)blockIdx.x * 4 + wave;
  const float* xr = x + row * 384;
  float xs[6];
  float part = 0.f;
#pragma unroll
  for (int j = 0; j < 6; j++) {
    int c = lane + 64 * j;
    xs[j] = xr[c];
    part += xs[j] * wsal[c];
  }
#pragma unroll
  for (int off = 32; off >= 1; off >>= 1) part += __shfl_xor(part, off);
  float s = 1.f / (1.f + __expf(-(part + bsal[0])));
#pragma unroll
  for (int j = 0; j < 6; j++) {
    int c = lane + 64 * j;
    xb[row * 384 + c] = __float2bfloat16(xs[j]);
  }
  if (lane == 0) sal[row] = s;
}

// ---------------------------------------------------------------------------
// wcast_tv: wvlT[n][k] = bf16(w_kv_agg[k][384+n])  (v-columns transposed)
// ---------------------------------------------------------------------------
__global__ void wcast_tv(const float* __restrict__ w, __hip_bfloat16* __restrict__ wt) {
  int idx = blockIdx.x * 256 + threadIdx.x;
  if (idx >= 384 * 384) return;
  int n = idx / 384, k = idx % 384;
  wt[idx] = __float2bfloat16(w[(size_t)k * 768 + 384 + n]);
}

// ---------------------------------------------------------------------------
// MFMA GEMM (final proj): out[M,Ncols] = A[M,K] @ BT_b[Ncols,K]^T.
// XCD-swizzled grid. 128x128 tile, BK=32, 4 waves.
// ---------------------------------------------------------------------------
template <int K, typename OT, int BSHIFT>
__global__ __launch_bounds__(256) void gemm_mfma(const __hip_bfloat16* __restrict__ A,
                                                 const __hip_bfloat16* __restrict__ BT,
                                                 OT* __restrict__ out, int Ncols,
                                                 size_t btBatchStride) {
  __shared__ __align__(16) __hip_bfloat16 Asl[128][32];
  __shared__ __align__(16) __hip_bfloat16 Bsl[128][32];
  int nf = xcd_flat(gridDim.x * gridDim.y);
  int bX = nf % gridDim.x, bY = nf / gridDim.x;
  int tid = threadIdx.x;
  int lane = tid & 63;
  int w = tid >> 6;
  int wr = w >> 1, wc = w & 1;
  int fr = lane & 15, fq = lane >> 4;
  int rowBase = bY * 128, colBase = bX * 128;
  const __hip_bfloat16* BTb = BT + (size_t)(rowBase >> BSHIFT) * btBatchStride;

  int r1 = tid >> 2, kc1 = tid & 3;
  int r2 = (tid + 256) >> 2;

  char* aB1 = (char*)Asl + (size_t)(w * 64) * 16;
  char* aB2 = (char*)Asl + (size_t)(256 + w * 64) * 16;
  char* bB1 = (char*)Bsl + (size_t)(w * 64) * 16;
  char* bB2 = (char*)Bsl + (size_t)(256 + w * 64) * 16;

  const __hip_bfloat16* a1 = A + (size_t)(rowBase + r1) * K + kc1 * 8;
  const __hip_bfloat16* a2 = A + (size_t)(rowBase + r2) * K + kc1 * 8;
  const __hip_bfloat16* b1 = BTb + (size_t)(colBase + r1) * K + kc1 * 8;
  const __hip_bfloat16* b2 = BTb + (size_t)(colBase + r2) * K + kc1 * 8;

  f32x4 acc[4][4] = {};

  for (int kk = 0; kk < K; kk += 32) {
    gload16(a1 + kk, aB1);
    gload16(a2 + kk, aB2);
    gload16(b1 + kk, bB1);
    gload16(b2 + kk, bB2);
    __syncthreads();
    bf16x8 af[4], bfv[4];
#pragma unroll
    for (int m = 0; m < 4; m++) af[m] = *(const bf16x8*)&Asl[wr * 64 + m * 16 + fr][fq * 8];
#pragma unroll
    for (int n = 0; n < 4; n++) bfv[n] = *(const bf16x8*)&Bsl[wc * 64 + n * 16 + fr][fq * 8];
#pragma unroll
    for (int m = 0; m < 4; m++)
#pragma unroll
      for (int n = 0; n < 4; n++)
        acc[m][n] = __builtin_amdgcn_mfma_f32_16x16x32_bf16(af[m], bfv[n], acc[m][n], 0, 0, 0);
    __syncthreads();
  }

#pragma unroll
  for (int m = 0; m < 4; m++) {
    int row0 = rowBase + wr * 64 + m * 16 + fq * 4;
#pragma unroll
    for (int n = 0; n < 4; n++) {
      int col = colBase + wc * 64 + n * 16 + fr;
      f32x4 v = acc[m][n];
#pragma unroll
      for (int r = 0; r < 4; r++) out[(size_t)(row0 + r) * Ncols + col] = cvt_from_f<OT>(v[r]);
    }
  }
}

// ---------------------------------------------------------------------------
// gemm_vlog: one pass over xb computes BOTH (XCD-swizzled grid (4,512))
//   x<3 : vT[b][c][n]  = sal·(xb @ wv)          (transposed bf16)
//   x==3: lgT[b*128+hm][n] = sal·(xb @ Wl^T)    (transposed bf16)
// ---------------------------------------------------------------------------
__global__ __launch_bounds__(256) void gemm_vlog(const __hip_bfloat16* __restrict__ A,
                                                 const __hip_bfloat16* __restrict__ BT,
                                                 __hip_bfloat16* __restrict__ vT,
                                                 __hip_bfloat16* __restrict__ lgT,
                                                 const float* __restrict__ rowScale) {
  constexpr int K = 384;
  __shared__ __align__(16) __hip_bfloat16 Asl[128][32];
  __shared__ __align__(16) __hip_bfloat16 Bsl[128][32];
  int nf = xcd_flat(2048);
  int bX = nf & 3, bY = nf >> 2;
  int tid = threadIdx.x;
  int lane = tid & 63;
  int w = tid >> 6;
  int wr = w >> 1, wc = w & 1;
  int fr = lane & 15, fq = lane >> 4;
  int rowBase = bY * 128, colBase = bX * 128;

  int r1 = tid >> 2, kc1 = tid & 3;
  int r2 = (tid + 256) >> 2;

  char* aB1 = (char*)Asl + (size_t)(w * 64) * 16;
  char* aB2 = (char*)Asl + (size_t)(256 + w * 64) * 16;
  char* bB1 = (char*)Bsl + (size_t)(w * 64) * 16;
  char* bB2 = (char*)Bsl + (size_t)(256 + w * 64) * 16;

  const __hip_bfloat16* a1 = A + (size_t)(rowBase + r1) * K + kc1 * 8;
  const __hip_bfloat16* a2 = A + (size_t)(rowBase + r2) * K + kc1 * 8;
  const __hip_bfloat16* b1 = BT + (size_t)(colBase + r1) * K + kc1 * 8;
  const __hip_bfloat16* b2 = BT + (size_t)(colBase + r2) * K + kc1 * 8;

  f32x4 acc[4][4] = {};

  for (int kk = 0; kk < K; kk += 32) {
    gload16(a1 + kk, aB1);
    gload16(a2 + kk, aB2);
    gload16(b1 + kk, bB1);
    gload16(b2 + kk, bB2);
    __syncthreads();
    bf16x8 af[4], bfv[4];
#pragma unroll
    for (int m = 0; m < 4; m++) af[m] = *(const bf16x8*)&Asl[wr * 64 + m * 16 + fr][fq * 8];
#pragma unroll
    for (int n = 0; n < 4; n++) bfv[n] = *(const bf16x8*)&Bsl[wc * 64 + n * 16 + fr][fq * 8];
#pragma unroll
    for (int m = 0; m < 4; m++)
#pragma unroll
      for (int n = 0; n < 4; n++)
        acc[m][n] = __builtin_amdgcn_mfma_f32_16x16x32_bf16(af[m], bfv[n], acc[m][n], 0, 0, 0);
    __syncthreads();
  }

  float sv[4][4];
#pragma unroll
  for (int m = 0; m < 4; m++)
#pragma unroll
    for (int r = 0; r < 4; r++)
      sv[m][r] = rowScale[rowBase + wr * 64 + m * 16 + fq * 4 + r];

  if (bX < 3) {
    // v epilogue: transposed bf16 write
#pragma unroll
    for (int m = 0; m < 4; m++) {
      int row0 = rowBase + wr * 64 + m * 16 + fq * 4;
      int bb = row0 >> 12;
      int n0 = row0 & 4095;
#pragma unroll
      for (int n = 0; n < 4; n++) {
        int col = colBase + wc * 64 + n * 16 + fr;
        __hip_bfloat16 tb[4];
#pragma unroll
        for (int r = 0; r < 4; r++) tb[r] = __float2bfloat16(acc[m][n][r] * sv[m][r]);
        *(unsigned long long*)(vT + ((size_t)bb * 384 + col) * 4096 + n0) = *(unsigned long long*)tb;
      }
    }
  } else {
    // logits epilogue: transposed bf16 write
#pragma unroll
    for (int m = 0; m < 4; m++) {
      int row0 = rowBase + wr * 64 + m * 16 + fq * 4;
      int bb = row0 >> 12;
      int n0 = row0 & 4095;
#pragma unroll
      for (int n = 0; n < 4; n++) {
        int col = wc * 64 + n * 16 + fr;  // 0..127 = hm
        __hip_bfloat16 tb[4];
#pragma unroll
        for (int r = 0; r < 4; r++) tb[r] = __float2bfloat16(acc[m][n][r] * sv[m][r]);
        *(unsigned long long*)(lgT + ((size_t)bb * 128 + col) * 4096 + n0) = *(unsigned long long*)tb;
      }
    }
  }
}

// ---------------------------------------------------------------------------
// gemm_pv: split-K PV, XCD-swizzled. pbuf[z][g][c] = PT[g, zslice] @ vT_b^T.
// Grid (3, 16, 8).
// ---------------------------------------------------------------------------
__global__ __launch_bounds__(256) void gemm_pv(const __hip_bfloat16* __restrict__ PT,
                                               const __hip_bfloat16* __restrict__ vT,
                                               float* __restrict__ pbuf) {
  __shared__ __align__(16) __hip_bfloat16 Asl[128][32];
  __shared__ __align__(16) __hip_bfloat16 Bsl[128][32];
  int nf = xcd_flat(384);
  int bX = nf % 3, bY = (nf / 3) & 15, kz = nf / 48;
  int tid = threadIdx.x;
  int lane = tid & 63;
  int w = tid >> 6;
  int wr = w >> 1, wc = w & 1;
  int fr = lane & 15, fq = lane >> 4;
  int rowBase = bY * 128, colBase = bX * 128;
  const __hip_bfloat16* BTb = vT + (size_t)bY * 384 * 4096;

  int r1 = tid >> 2, kc1 = tid & 3;
  int r2 = (tid + 256) >> 2;

  char* aB1 = (char*)Asl + (size_t)(w * 64) * 16;
  char* aB2 = (char*)Asl + (size_t)(256 + w * 64) * 16;
  char* bB1 = (char*)Bsl + (size_t)(w * 64) * 16;
  char* bB2 = (char*)Bsl + (size_t)(256 + w * 64) * 16;

  const __hip_bfloat16* a1 = PT + (size_t)(rowBase + r1) * 4096 + kz * 512 + kc1 * 8;
  const __hip_bfloat16* a2 = PT + (size_t)(rowBase + r2) * 4096 + kz * 512 + kc1 * 8;
  const __hip_bfloat16* b1 = BTb + (size_t)(colBase + r1) * 4096 + kz * 512 + kc1 * 8;
  const __hip_bfloat16* b2 = BTb + (size_t)(colBase + r2) * 4096 + kz * 512 + kc1 * 8;

  f32x4 acc[4][4] = {};

  for (int kk = 0; kk < 512; kk += 32) {
    gload16(a1 + kk, aB1);
    gload16(a2 + kk, aB2);
    gload16(b1 + kk, bB1);
    gload16(b2 + kk, bB2);
    __syncthreads();
    bf16x8 af[4], bfv[4];
#pragma unroll
    for (int m = 0; m < 4; m++) af[m] = *(const bf16x8*)&Asl[wr * 64 + m * 16 + fr][fq * 8];
#pragma unroll
    for (int n = 0; n < 4; n++) bfv[n] = *(const bf16x8*)&Bsl[wc * 64 + n * 16 + fr][fq * 8];
#pragma unroll
    for (int m = 0; m < 4; m++)
#pragma unroll
      for (int n = 0; n < 4; n++)
        acc[m][n] = __builtin_amdgcn_mfma_f32_16x16x32_bf16(af[m], bfv[n], acc[m][n], 0, 0, 0);
    __syncthreads();
  }

  float* outz = pbuf + (size_t)kz * 786432;
#pragma unroll
  for (int m = 0; m < 4; m++) {
    int row0 = rowBase + wr * 64 + m * 16 + fq * 4;
#pragma unroll
    for (int n = 0; n < 4; n++) {
      int col = colBase + wc * 64 + n * 16 + fr;
      f32x4 v = acc[m][n];
#pragma unroll
      for (int r = 0; r < 4; r++) outz[(size_t)(row0 + r) * 384 + col] = v[r];
    }
  }
}

// ---------------------------------------------------------------------------
// anch_fix2: anch1[b][m][c] = seeds[m][c] + sum_z pbuf[z][b*128+h(c)*16+m][c].
// ---------------------------------------------------------------------------
__global__ void anch_fix2(const float* __restrict__ pbuf, const float* __restrict__ seeds,
                          float* __restrict__ anch1) {
  int idx = blockIdx.x * 256 + threadIdx.x;  // 98304
  int b = idx / 6144;
  int rem = idx - b * 6144;
  int m = rem / 384, c = rem - m * 384;
  int g = b * 128 + (c / 48) * 16 + m;
  const float* p = pbuf + (size_t)g * 384 + c;
  float s = 0.f;
#pragma unroll
  for (int z = 0; z < 8; z++) s += p[(size_t)z * 786432];
  anch1[idx] = seeds[rem] + s;
}

// ---------------------------------------------------------------------------
// softmax_rows: PT[g][n] = softmax_n(lgT[g][n]) (bf16 in/out). Block per row.
// ---------------------------------------------------------------------------
__global__ __launch_bounds__(256) void softmax_rows(const __hip_bfloat16* __restrict__ lgT,
                                                    __hip_bfloat16* __restrict__ PT) {
  int g = blockIdx.x;
  const __hip_bfloat16* row = lgT + (size_t)g * 4096;
  int tid = threadIdx.x, wv = tid >> 6, lane = tid & 63;
  __shared__ float redm[4], reds[4];
  float v[16];
  union { ulonglong2 u; __hip_bfloat16 h[8]; } L0, L1;
  L0.u = *(const ulonglong2*)(row + tid * 16);
  L1.u = *(const ulonglong2*)(row + tid * 16 + 8);
#pragma unroll
  for (int i = 0; i < 8; i++) {
    v[i] = __bfloat162float(L0.h[i]);
    v[8 + i] = __bfloat162float(L1.h[i]);
  }
  float mx = v[0];
#pragma unroll
  for (int i = 1; i < 16; i++) mx = fmaxf(mx, v[i]);
#pragma unroll
  for (int off = 1; off < 64; off <<= 1) mx = fmaxf(mx, __shfl_xor(mx, off));
  if (lane == 0) redm[wv] = mx;
  __syncthreads();
  mx = fmaxf(fmaxf(redm[0], redm[1]), fmaxf(redm[2], redm[3]));
  float s = 0.f;
#pragma unroll
  for (int i = 0; i < 16; i++) {
    v[i] = __expf(v[i] - mx);
    s += v[i];
  }
#pragma unroll
  for (int off = 1; off < 64; off <<= 1) s += __shfl_xor(s, off);
  if (lane == 0) reds[wv] = s;
  __syncthreads();
  s = (reds[0] + reds[1]) + (reds[2] + reds[3]);
  float inv = 1.f / s;
  __hip_bfloat16 tb[16];
#pragma unroll
  for (int i = 0; i < 16; i++) tb[i] = __float2bfloat16(v[i] * inv);
  __hip_bfloat16* op = PT + (size_t)g * 4096 + tid * 16;
  *(ulonglong2*)op = *(ulonglong2*)tb;
  *(ulonglong2*)(op + 8) = *(ulonglong2*)(tb + 8);
}

// ---------------------------------------------------------------------------
// fill_wl: wvlT[384+hm][ci] = sum_d w_kv_agg[ci][h*48+d] * qseed[m][h*48+d].
// ---------------------------------------------------------------------------
__global__ void fill_wl(const float* __restrict__ wkv, const float* __restrict__ qseed,
                        __hip_bfloat16* __restrict__ wvlT) {
  int idx = blockIdx.x * 256 + threadIdx.x;  // 49152
  int hm = idx / 384, ci = idx - hm * 384;
  int h = hm >> 4, m = hm & 15;
  const float* wp = wkv + (size_t)ci * 768 + h * 48;
  const float* qp = qseed + m * 384 + h * 48;
  float acc = 0.f;
#pragma unroll
  for (int d = 0; d < 48; d++) acc += wp[d] * qp[d];
  wvlT[384 * 384 + idx] = __float2bfloat16(acc);
}

// ---------------------------------------------------------------------------
// wtrans: bt2[b][cp][k2<384] = bf16(w_proj[k2][cp]) via LDS 64x64 transpose,
// replicated to all 16 batch slices. Grid (6, 6, 4).
// ---------------------------------------------------------------------------
__global__ __launch_bounds__(256) void wtrans(const float* __restrict__ wproj,
                                              __hip_bfloat16* __restrict__ bt2) {
  __shared__ float t[64][65];
  int kt = blockIdx.x * 64, ct = blockIdx.y * 64;
  int tid = threadIdx.x;
  int c = tid & 63, r4 = tid >> 6;
#pragma unroll
  for (int i = 0; i < 16; i++) {
    int r = i * 4 + r4;
    t[r][c] = wproj[(size_t)(kt + r) * 384 + ct + c];
  }
  __syncthreads();
  __hip_bfloat16 vals[16];
#pragma unroll
  for (int i = 0; i < 16; i++) vals[i] = __float2bfloat16(t[c][i * 4 + r4]);
  for (int b = blockIdx.z * 4; b < blockIdx.z * 4 + 4; b++) {
    __hip_bfloat16* dst = bt2 + (size_t)b * 196608;
#pragma unroll
    for (int i = 0; i < 16; i++) {
      int rr = i * 4 + r4;
      dst[(size_t)(ct + rr) * 512 + kt + c] = vals[i];
    }
  }
}

// ---------------------------------------------------------------------------
// fill_fold: merged per-batch folded-weight fills. Grid (16, 16):
//   x<8 : wpbT[b][h*16+m][k]   (h = x)
//   x>=8: bt2[b][cp][384+h*16+m]  (h = x-8)
// ---------------------------------------------------------------------------
__global__ __launch_bounds__(256) void fill_fold(const float* __restrict__ wq,
                                                 const float* __restrict__ wproj,
                                                 const float* __restrict__ kvb,
                                                 __hip_bfloat16* __restrict__ wpbT,
                                                 __hip_bfloat16* __restrict__ bt2) {
  int b = blockIdx.y;
  int tid = threadIdx.x;
  __shared__ float stage[16][48];
  __shared__ __hip_bfloat16 obuf[16][264];
  if (blockIdx.x < 8) {
    int h = blockIdx.x;
    for (int idx = tid; idx < 768; idx += 256) {
      int m = idx / 48, d = idx % 48;
      stage[m][d] = kvb[(size_t)(b * 16 + m) * 768 + h * 48 + d];  // SCALE pre-folded
    }
    __syncthreads();
    for (int kbase = 0; kbase < 384; kbase += 256) {
      int chunk = (kbase == 0) ? 256 : 128;
      if (tid < chunk) {
        int k = kbase + tid;
        const float4* wp = (const float4*)(wq + (size_t)k * 384 + h * 48);
        float acc[16] = {};
#pragma unroll
        for (int dq = 0; dq < 12; dq++) {
          float4 wv = wp[dq];
#pragma unroll
          for (int m = 0; m < 16; m++)
            acc[m] += stage[m][dq * 4] * wv.x + stage[m][dq * 4 + 1] * wv.y +
                      stage[m][dq * 4 + 2] * wv.z + stage[m][dq * 4 + 3] * wv.w;
        }
#pragma unroll
        for (int m = 0; m < 16; m++) obuf[m][tid] = __float2bfloat16(acc[m]);
      }
      __syncthreads();
      for (int widx = tid; widx < 16 * chunk; widx += 256) {
        int m = widx / chunk, kk = widx - m * chunk;
        wpbT[(size_t)b * 49152 + (size_t)(h * 16 + m) * 384 + kbase + kk] = obuf[m][kk];
      }
      __syncthreads();
    }
  } else {
    int h = blockIdx.x - 8;
    for (int idx = tid; idx < 768; idx += 256) {
      int m = idx / 48, d = idx % 48;
      stage[m][d] = kvb[(size_t)(b * 16 + m) * 768 + 384 + h * 48 + d];
    }
    __syncthreads();
    for (int cp = tid; cp < 384; cp += 256) {
      float acc[16] = {};
      for (int d = 0; d < 48; d++) {
        float wv = wproj[(size_t)(h * 48 + d) * 384 + cp];
#pragma unroll
        for (int m = 0; m < 16; m++) acc[m] += stage[m][d] * wv;
      }
      __hip_bfloat16 tb[16];
#pragma unroll
      for (int m = 0; m < 16; m++) tb[m] = __float2bfloat16(acc[m]);
      __hip_bfloat16* dst = bt2 + (size_t)b * 196608 + (size_t)cp * 512 + 384 + h * 16;
      *(ulonglong2*)dst = *(ulonglong2*)tb;
      *(ulonglong2*)(dst + 8) = *(ulonglong2*)(tb + 8);
    }
  }
}

// ---------------------------------------------------------------------------
// pgemm: P = softmax_per_head(xb @ W_pbT_b^T), written bf16 to A2[:,384+hm].
// Grid (1, 512).
// ---------------------------------------------------------------------------
__global__ __launch_bounds__(256) void pgemm(const __hip_bfloat16* __restrict__ A,
                                             const __hip_bfloat16* __restrict__ wpbT,
                                             __hip_bfloat16* __restrict__ A2) {
  constexpr int K = 384;
  __shared__ __align__(16) __hip_bfloat16 Asl[128][32];
  __shared__ __align__(16) __hip_bfloat16 Bsl[128][32];
  int tid = threadIdx.x;
  int lane = tid & 63;
  int w = tid >> 6;
  int wr = w >> 1, wc = w & 1;
  int fr = lane & 15, fq = lane >> 4;
  int rowBase = blockIdx.y * 128;
  const __hip_bfloat16* BTb = wpbT + (size_t)(rowBase >> 12) * (128 * 384);

  int r1 = tid >> 2, kc1 = tid & 3;
  int r2 = (tid + 256) >> 2;

  char* aB1 = (char*)Asl + (size_t)(w * 64) * 16;
  char* aB2 = (char*)Asl + (size_t)(256 + w * 64) * 16;
  char* bB1 = (char*)Bsl + (size_t)(w * 64) * 16;
  char* bB2 = (char*)Bsl + (size_t)(256 + w * 64) * 16;

  const __hip_bfloat16* a1 = A + (size_t)(rowBase + r1) * K + kc1 * 8;
  const __hip_bfloat16* a2 = A + (size_t)(rowBase + r2) * K + kc1 * 8;
  const __hip_bfloat16* b1 = BTb + (size_t)r1 * K + kc1 * 8;
  const __hip_bfloat16* b2 = BTb + (size_t)r2 * K + kc1 * 8;

  f32x4 acc[4][4] = {};

  for (int kk = 0; kk < K; kk += 32) {
    gload16(a1 + kk, aB1);
    gload16(a2 + kk, aB2);
    gload16(b1 + kk, bB1);
    gload16(b2 + kk, bB2);
    __syncthreads();
    bf16x8 af[4], bfv[4];
#pragma unroll
    for (int m = 0; m < 4; m++) af[m] = *(const bf16x8*)&Asl[wr * 64 + m * 16 + fr][fq * 8];
#pragma unroll
    for (int n = 0; n < 4; n++) bfv[n] = *(const bf16x8*)&Bsl[wc * 64 + n * 16 + fr][fq * 8];
#pragma unroll
    for (int m = 0; m < 4; m++)
#pragma unroll
      for (int n = 0; n < 4; n++)
        acc[m][n] = __builtin_amdgcn_mfma_f32_16x16x32_bf16(af[m], bfv[n], acc[m][n], 0, 0, 0);
    __syncthreads();
  }

  // epilogue: per (row, head) softmax over the 16-lane fr group -> A2[:,384+col]
#pragma unroll
  for (int m = 0; m < 4; m++) {
    int row0 = rowBase + wr * 64 + m * 16 + fq * 4;
#pragma unroll
    for (int n = 0; n < 4; n++) {
      int col = wc * 64 + n * 16 + fr;
      f32x4 v = acc[m][n];
      f32x4 mx = v;
#pragma unroll
      for (int off = 1; off < 16; off <<= 1)
#pragma unroll
        for (int r = 0; r < 4; r++) mx[r] = fmaxf(mx[r], __shfl_xor(mx[r], off));
      f32x4 e;
#pragma unroll
      for (int r = 0; r < 4; r++) e[r] = __expf(v[r] - mx[r]);
      f32x4 s = e;
#pragma unroll
      for (int off = 1; off < 16; off <<= 1)
#pragma unroll
        for (int r = 0; r < 4; r++) s[r] += __shfl_xor(s[r], off);
#pragma unroll
      for (int r = 0; r < 4; r++)
        A2[(size_t)(row0 + r) * 512 + 384 + col] = __float2bfloat16(e[r] / s[r]);
    }
  }
}

// ---------------------------------------------------------------------------
// dwconv3: depthwise 3x3 conv with x-walking register-rotated tap columns.
// Block = one y-row (grid (64, B)); wave w covers x in [w*16, w*16+16).
// Lane owns 6 contiguous channels. 3 loads/step instead of 9.
// ---------------------------------------------------------------------------
__global__ __launch_bounds__(256) void dwconv3(const __hip_bfloat16* __restrict__ xb,
                                               const float* __restrict__ dwk,
                                               __hip_bfloat16* __restrict__ A2) {
  int b = blockIdx.y;
  int y = blockIdx.x;  // 0..63
  int w = threadIdx.x >> 6, lane = threadIdx.x & 63;
  int c0 = lane * 6;
  int x0 = w * 16;
  float kw[9][6];
#pragma unroll
  for (int ki = 0; ki < 9; ki++)
#pragma unroll
    for (int i = 0; i < 6; i++) kw[ki][i] = dwk[(c0 + i) * 9 + ki];

  const __hip_bfloat16* base = xb + ((size_t)(b * 4096 + y * 64)) * 384 + c0;
  bool yv[3];
#pragma unroll
  for (int t = 0; t < 3; t++) {
    int yy = y + t - 1;
    yv[t] = (yy >= 0 && yy < 64);
  }

  float colL[3][6], colC[3][6], colR[3][6];
  // load column x into dst
  auto loadcol = [&](float (&dst)[3][6], int x) {
#pragma unroll
    for (int t = 0; t < 3; t++) {
      if (yv[t]) {
        const __hip_bfloat16* p = base + ((size_t)(t - 1) * 64 + x) * 384;
#pragma unroll
        for (int i = 0; i < 6; i++) dst[t][i] = __bfloat162float(p[i]);
      } else {
#pragma unroll
        for (int i = 0; i < 6; i++) dst[t][i] = 0.f;
      }
    }
  };

  if (x0 == 0) {
#pragma unroll
    for (int t = 0; t < 3; t++)
#pragma unroll
      for (int i = 0; i < 6; i++) colL[t][i] = 0.f;
  } else {
    loadcol(colL, x0 - 1);
  }
  loadcol(colC, x0);

  for (int step = 0; step < 16; step++) {
    int x = x0 + step;
    if (x + 1 < 64) {
      loadcol(colR, x + 1);
    } else {
#pragma unroll
      for (int t = 0; t < 3; t++)
#pragma unroll
        for (int i = 0; i < 6; i++) colR[t][i] = 0.f;
    }
    float acc[6];
#pragma unroll
    for (int i = 0; i < 6; i++) {
      float a = 0.f;
#pragma unroll
      for (int t = 0; t < 3; t++)
        a += colL[t][i] * kw[t * 3 + 0][i] + colC[t][i] * kw[t * 3 + 1][i] +
             colR[t][i] * kw[t * 3 + 2][i];
      acc[i] = a;
    }
    __hip_bfloat16 tb[6];
#pragma unroll
    for (int i = 0; i < 6; i++) tb[i] = __float2bfloat16(acc[i]);
    __hip_bfloat16* gp = A2 + ((size_t)(b * 4096 + y * 64 + x)) * 512 + c0;
    *(unsigned int*)(gp) = *(unsigned int*)(tb);
    *(unsigned int*)(gp + 2) = *(unsigned int*)(tb + 2);
    *(unsigned int*)(gp + 4) = *(unsigned int*)(tb + 4);
    // rotate columns
#pragma unroll
    for (int t = 0; t < 3; t++)
#pragma unroll
      for (int i = 0; i < 6; i++) {
        colL[t][i] = colC[t][i];
        colC[t][i] = colR[t][i];
      }
  }
}

// ---------------------------------------------------------------------------
// anchor_proj2: out[b,16,wstride] = A[b,16,384] @ W[384,wstride].
// ---------------------------------------------------------------------------
__global__ __launch_bounds__(256) void anchor_proj2(const float* __restrict__ A,
                                                    const float* __restrict__ W,
                                                    float* __restrict__ out, int wstride,
                                                    int scaleCols) {
  int cs = blockIdx.x * 16;
  int b = blockIdx.y;
  __shared__ float a1[16][385];
  int tid = threadIdx.x;
  for (int idx = tid; idx < 6144; idx += 256) a1[idx / 384][idx % 384] = A[b * 6144 + idx];
  __syncthreads();
  int m = tid >> 4, cc = tid & 15;
  int col = cs + cc;
  const float* wp = W + col;
  float acc0 = 0.f, acc1 = 0.f, acc2 = 0.f, acc3 = 0.f;
#pragma unroll 4
  for (int k = 0; k < 384; k += 4) {
    acc0 += a1[m][k] * wp[(size_t)k * wstride];
    acc1 += a1[m][k + 1] * wp[(size_t)(k + 1) * wstride];
    acc2 += a1[m][k + 2] * wp[(size_t)(k + 2) * wstride];
    acc3 += a1[m][k + 3] * wp[(size_t)(k + 3) * wstride];
  }
  float acc = (acc0 + acc1) + (acc2 + acc3);
  if (col < scaleCols) acc *= SCALE;
  out[((size_t)b * 16 + m) * wstride + col] = acc;
}

// ---------------------------------------------------------------------------
// anchor_proj_qkv: fused q_self (x<24) + kv_self (x>=24) projections.
// ---------------------------------------------------------------------------
__global__ __launch_bounds__(256) void anchor_proj_qkv(const float* __restrict__ A,
                                                       const float* __restrict__ Wq,
                                                       const float* __restrict__ Wkv,
                                                       float* __restrict__ q_out,
                                                       float* __restrict__ kv_out) {
  bool isQ = blockIdx.x < 24;
  int bx = isQ ? blockIdx.x : blockIdx.x - 24;
  const float* W = isQ ? Wq : Wkv;
  float* outp = isQ ? q_out : kv_out;
  int wstride = isQ ? 384 : 768;
  float scale = isQ ? SCALE : 1.f;
  int cs = bx * 16;
  int b = blockIdx.y;
  __shared__ float a1[16][385];
  int tid = threadIdx.x;
  for (int idx = tid; idx < 6144; idx += 256) a1[idx / 384][idx % 384] = A[b * 6144 + idx];
  __syncthreads();
  int m = tid >> 4, cc = tid & 15;
  int col = cs + cc;
  const float* wp = W + col;
  float acc0 = 0.f, acc1 = 0.f, acc2 = 0.f, acc3 = 0.f;
#pragma unroll 4
  for (int k = 0; k < 384; k += 4) {
    acc0 += a1[m][k] * wp[(size_t)k * wstride];
    acc1 += a1[m][k + 1] * wp[(size_t)(k + 1) * wstride];
    acc2 += a1[m][k + 2] * wp[(size_t)(k + 2) * wstride];
    acc3 += a1[m][k + 3] * wp[(size_t)(k + 3) * wstride];
  }
  float acc = ((acc0 + acc1) + (acc2 + acc3)) * scale;
  outp[((size_t)b * 16 + m) * wstride + col] = acc;
}

// ---------------------------------------------------------------------------
// Self attention on anchors (16x16, per (b,h)); anchors2 = anchors1 + out.
// ---------------------------------------------------------------------------
__global__ void self_attn(const float* __restrict__ qsf, const float* __restrict__ kvs,
                          const float* __restrict__ anch1, float* __restrict__ anch2) {
  int h = blockIdx.x & 7, b = blockIdx.x >> 3;
  __shared__ float qs[16][48], ks[16][48], vs[16][48], p[16][17];
  int tid = threadIdx.x;
  for (int idx = tid; idx < 768; idx += 256) {
    int m = idx / 48, d = idx % 48;
    qs[m][d] = qsf[(b * 16 + m) * 384 + h * 48 + d];
    ks[m][d] = kvs[(b * 16 + m) * 768 + h * 48 + d];
    vs[m][d] = kvs[(b * 16 + m) * 768 + 384 + h * 48 + d];
  }
  __syncthreads();
  {
    int mq = tid >> 4, mk = tid & 15;
    float acc = 0.f;
    for (int d = 0; d < 48; d++) acc += qs[mq][d] * ks[mk][d];
    p[mq][mk] = acc;
  }
  __syncthreads();
  if (tid < 16) {
    float mx = -1e30f;
    for (int mk = 0; mk < 16; mk++) mx = fmaxf(mx, p[tid][mk]);
    float sum = 0.f;
    for (int mk = 0; mk < 16; mk++) {
      float e = __expf(p[tid][mk] - mx);
      p[tid][mk] = e;
      sum += e;
    }
    float inv = 1.f / sum;
    for (int mk = 0; mk < 16; mk++) p[tid][mk] *= inv;
  }
  __syncthreads();
  for (int idx = tid; idx < 768; idx += 256) {
    int m = idx / 48, d = idx % 48;
    float acc = 0.f;
    for (int mk = 0; mk < 16; mk++) acc += p[m][mk] * vs[mk][d];
    int c = h * 48 + d;
    anch2[(b * 16 + m) * 384 + c] = anch1[(b * 16 + m) * 384 + c] + acc;
  }
}

// ---------------------------------------------------------------------------
extern "C" void kernel_launch(void* const* d_in, const int* in_sizes, int n_in,
                              void* d_out, int out_size, void* d_ws, size_t ws_size,
                              hipStream_t stream) {
  (void)in_sizes; (void)n_in; (void)out_size; (void)ws_size;
  const float* x = (const float*)d_in[0];
  const float* wsal = (const float*)d_in[3];
  const float* bsal = (const float*)d_in[4];
  const float* seeds = (const float*)d_in[5];
  const float* w_q_agg = (const float*)d_in[6];
  const float* w_kv_agg = (const float*)d_in[7];
  const float* w_q_self = (const float*)d_in[8];
  const float* w_kv_self = (const float*)d_in[9];
  const float* w_q_bcast = (const float*)d_in[10];
  const float* w_kv_bcast = (const float*)d_in[11];
  const float* dwk = (const float*)d_in[12];
  const float* w_proj = (const float*)d_in[13];
  float* out = (float*)d_out;

  char* ws = (char*)d_ws;
  size_t off = 0;
  auto take = [&](size_t bytes) -> void* {
    void* p = ws + off;
    off += (bytes + 255) & ~(size_t)255;
    return p;
  };
  __hip_bfloat16* xb = (__hip_bfloat16*)take(50331648);      // bf16(x)
  __hip_bfloat16* vT = (__hip_bfloat16*)take(50331648);      // [16][384][4096] bf16
  char* lgRegion = (char*)take(33554432);                    // bf16 logits (16MB) / pbuf f32 (25MB)
  __hip_bfloat16* PT = (__hip_bfloat16*)take(16777216);      // [2048][4096] bf16
  float* qseed = (float*)take(24576);
  float* sal = (float*)take(262144);
  float* anch1 = (float*)take(393216);
  float* anch2 = (float*)take(393216);
  float* q_self = (float*)take(393216);
  float* kv_self = (float*)take(786432);
  float* kv_b = (float*)take(786432);
  __hip_bfloat16* wvlT = (__hip_bfloat16*)take(393216);   // [512][384] bf16: v ++ Wl
  __hip_bfloat16* wpbT = (__hip_bfloat16*)take(1572864);  // [16][128][384] bf16
  __hip_bfloat16* bt2 = (__hip_bfloat16*)take(6291456);   // [16][384][512] bf16
  __hip_bfloat16* logitsT = (__hip_bfloat16*)lgRegion;    // [2048][4096] bf16
  float* pbuf = (float*)lgRegion;  // alias: logits dead after softmax_rows
  __hip_bfloat16* A2 = vT;         // alias: vT+pbuf dead after anch_fix2 (64 of 80 MB)

  // 1) xb + saliency
  prep<<<16384, 256, 0, stream>>>(x, wsal, bsal, xb, sal);
  // 2) build combined B: wvlT[0:384] = v-cols^T; wvlT[384:512] = Wl (needs qseed)
  anchor_proj2<<<dim3(24, 1), 256, 0, stream>>>(seeds, w_q_agg, qseed, 384, 384);
  wcast_tv<<<576, 256, 0, stream>>>(w_kv_agg, wvlT);
  fill_wl<<<192, 256, 0, stream>>>(w_kv_agg, qseed, wvlT);
  // 2b) bt2 upper half: w_proj^T replicated (batch-independent, LDS transpose)
  wtrans<<<dim3(6, 6, 4), 256, 0, stream>>>(w_proj, bt2);
  // 3) one pass over xb: vT (transposed V) + logitsT (transposed bf16 logits)
  gemm_vlog<<<dim3(4, 512), 256, 0, stream>>>(xb, wvlT, vT, logitsT, sal);
  // 4) softmax over keys; PV with split-K=8; reduce+seeds -> anchors1
  softmax_rows<<<2048, 256, 0, stream>>>(logitsT, PT);
  gemm_pv<<<dim3(3, 16, 8), 256, 0, stream>>>(PT, vT, pbuf);
  anch_fix2<<<384, 256, 0, stream>>>(pbuf, seeds, anch1);
  // 5) anchor self-attention -> anchors2 (q_self + kv_self fused)
  anchor_proj_qkv<<<dim3(72, 16), 256, 0, stream>>>(anch1, w_q_self, w_kv_self, q_self, kv_self);
  self_attn<<<128, 256, 0, stream>>>(q_self, kv_self, anch1, anch2);
  // 6) kv_bcast = anchors2 @ w_kv_bcast (SCALE on k half)
  anchor_proj2<<<dim3(48, 16), 256, 0, stream>>>(anch2, w_kv_bcast, kv_b, 768, 384);
  // 7) per-batch folded weights (wpbT + bt2 lower half in one launch)
  fill_fold<<<dim3(16, 16), 256, 0, stream>>>(w_q_bcast, w_proj, kv_b, wpbT, bt2);
  // 8) A2[:,384:512] = P = softmax(xb @ W_pbT_b)  (vT/pbuf dead -> A2)
  pgemm<<<dim3(1, 512), 256, 0, stream>>>(xb, wpbT, A2);
  // 9) A2[:,0:384] = dwconv(xb)  (x-walk register rotation)
  dwconv3<<<dim3(64, 16), 256, 0, stream>>>(xb, dwk, A2);
  // 10) out = A2 @ BT2_b   (K=512, f32 out)
  gemm_mfma<512, float, 12><<<dim3(3, 512), 256, 0, stream>>>(A2, bt2, out, 384, (size_t)384 * 512);
}